// Round 2
// 9654.108 us; speedup vs baseline: 9.7412x; 9.7412x over previous
//
#include <hip/hip_runtime.h>
#include <hip/hip_bf16.h>

#define BB 4
#define CC 192
#define LL 65536
#define WWW 256
#define HID 768
#define SXP (CC + 4)    // 196: 196%32=4 -> rows rotate 4 banks (break 192%32==0 conflicts)
#define SAP (HID + 4)   // 772: same rotation for fc2 reads

__device__ __forceinline__ float us2f(unsigned short u) { return __uint_as_float(((unsigned int)u) << 16); }
__device__ __forceinline__ unsigned short f2us(float f) {
    // round-to-nearest-even bf16 truncation
    unsigned int x = __float_as_uint(f);
    unsigned int r = (x + 0x7FFFu + ((x >> 16) & 1u)) >> 16;
    return (unsigned short)r;
}

__device__ __forceinline__ float gelu_exact(float x) {
    return 0.5f * x * (1.0f + erff(x * 0.70710678118654752440f));
}

__device__ __forceinline__ float dot8(const float4 a, const float4 b, const float4 wa, const float4 wb) {
    return a.x*wa.x + a.y*wa.y + a.z*wa.z + a.w*wa.w
         + b.x*wb.x + b.y*wb.y + b.z*wb.z + b.w*wb.w;
}

// ---------------- Kernel A: gather window + LN1 + QKV + attn + proj + residual ----------------
// (unchanged; ~6.4 ms of the 94 ms baseline)
__global__ __launch_bounds__(256) void kA(
    const float* __restrict__ x, const int* __restrict__ perm,
    const float* __restrict__ n1g, const float* __restrict__ n1b,
    const float* __restrict__ qkvw, const float* __restrict__ qkvb,
    const float* __restrict__ projw, const float* __restrict__ projb,
    float* __restrict__ xt2)
{
    __shared__ float s_h[16][CC];              // raw -> LN'd -> (reused) o
    __shared__ float s_qkv[16][3*CC];          // q|k|v per token
    __shared__ float s_attn[96][16];           // 6 heads * 16 rows
    __shared__ unsigned short s_stash[16][CC]; // bf16 copy of raw x for residual
    __shared__ float s_mu[16], s_rs[16];
    __shared__ int s_tok[16];

    const int tid = threadIdx.x;
    const int wid = blockIdx.x;
    const int b  = wid >> 12;        // 4096 windows per batch
    const int hb = (wid >> 6) & 63;
    const int wb = wid & 63;

    if (tid < 16) {
        int si = tid >> 2, sj = tid & 3;
        s_tok[tid] = perm[(hb * 4 + si) * WWW + wb * 4 + sj];
    }
    __syncthreads();

    // gather raw x (scattered: stride-L per channel)
    for (int idx = tid; idx < 16 * CC; idx += 256) {
        int n = idx / CC, c = idx - n * CC;
        float v = x[((size_t)b * CC + c) * LL + s_tok[n]];
        s_h[n][c] = v;
        s_stash[n][c] = f2us(v);
    }
    __syncthreads();

    // LN stats: 16 threads, one token each
    if (tid < 16) {
        float s = 0.f, q = 0.f;
        for (int c = 0; c < CC; c++) { float v = s_h[tid][c]; s += v; q += v * v; }
        float mu = s * (1.f / CC);
        float var = q * (1.f / CC) - mu * mu;
        s_mu[tid] = mu;
        s_rs[tid] = rsqrtf(var + 1e-5f);
    }
    __syncthreads();

    // normalize in place
    for (int idx = tid; idx < 16 * CC; idx += 256) {
        int n = idx / CC, c = idx - n * CC;
        s_h[n][c] = (s_h[n][c] - s_mu[n]) * s_rs[n] * n1g[c] + n1b[c];
    }
    __syncthreads();

    // qkv = h @ qkv_w^T + qkv_b
    for (int oc = tid; oc < 3 * CC; oc += 256) {
        float acc[16];
        for (int i = 0; i < 16; i++) acc[i] = 0.f;
        const float4* wr = (const float4*)(qkvw + (size_t)oc * CC);
        for (int k8 = 0; k8 < CC / 8; ++k8) {
            float4 wa = wr[k8 * 2], wb2 = wr[k8 * 2 + 1];
            for (int n = 0; n < 16; n++) {
                const float4* hp = (const float4*)(&s_h[n][k8 * 8]);
                acc[n] += dot8(hp[0], hp[1], wa, wb2);
            }
        }
        float bias = qkvb[oc];
        for (int n = 0; n < 16; n++) s_qkv[n][oc] = acc[n] + bias;
    }
    __syncthreads();

    // scores = SCALE * q @ k^T   (6 heads x 16 x 16)
    for (int idx = tid; idx < 1536; idx += 256) {
        int head = idx >> 8, r = (idx >> 4) & 15, col = idx & 15;
        float s = 0.f;
        for (int d = 0; d < 32; d++)
            s += s_qkv[r][head * 32 + d] * s_qkv[col][CC + head * 32 + d];
        s_attn[head * 16 + r][col] = s * 4.0f;
    }
    __syncthreads();

    // softmax over 16 keys
    if (tid < 96) {
        float mx = -1e30f;
        for (int i = 0; i < 16; i++) mx = fmaxf(mx, s_attn[tid][i]);
        float ss = 0.f;
        for (int i = 0; i < 16; i++) { float e = __expf(s_attn[tid][i] - mx); ss += e; s_attn[tid][i] = e; }
        float inv = 1.f / ss;
        for (int i = 0; i < 16; i++) s_attn[tid][i] *= inv;
    }
    __syncthreads();

    // o = attn @ v  (into s_h, reuse)
    for (int idx = tid; idx < 16 * CC; idx += 256) {
        int n = idx / CC, c = idx - n * CC;
        int head = c >> 5;
        float s = 0.f;
        for (int m = 0; m < 16; m++) s += s_attn[head * 16 + n][m] * s_qkv[m][2 * CC + c];
        s_h[n][c] = s;
    }
    __syncthreads();

    // proj + residual, scatter to (B,C,L)
    if (tid < CC) {
        const int c = tid;
        float acc[16];
        for (int i = 0; i < 16; i++) acc[i] = 0.f;
        const float4* wr = (const float4*)(projw + (size_t)c * CC);
        for (int k8 = 0; k8 < CC / 8; ++k8) {
            float4 wa = wr[k8 * 2], wb2 = wr[k8 * 2 + 1];
            for (int n = 0; n < 16; n++) {
                const float4* hp = (const float4*)(&s_h[n][k8 * 8]);
                acc[n] += dot8(hp[0], hp[1], wa, wb2);
            }
        }
        float bias = projb[c];
        for (int n = 0; n < 16; n++) {
            float res = us2f(s_stash[n][c]);
            xt2[((size_t)b * CC + c) * LL + s_tok[n]] = acc[n] + bias + res;
        }
    }
}

// ---------------- Kernel B v2: LN2 + MLP + residual ----------------
// Register-blocked 4oc x 4tok (fc1) / 3oc x 4tok (fc2) so accumulators stay in VGPRs
// (v1 spilled: 256 VGPR, 188 GB scratch HBM traffic, 87.6 ms).
__global__ __launch_bounds__(256, 2) void kB(
    float* __restrict__ xt2,
    const float* __restrict__ n2g, const float* __restrict__ n2b,
    const float* __restrict__ fc1w, const float* __restrict__ fc1b,
    const float* __restrict__ fc2w, const float* __restrict__ fc2b)
{
    __shared__ float s_x[16][SXP];     // LN'd input
    __shared__ float s_a[16][SAP];     // gelu(fc1) activations

    const int tid = threadIdx.x;
    const int t0 = blockIdx.x * 16;    // 16 consecutive tokens, same b
    const int b  = t0 >> 16;           // / LL
    const int l0 = t0 & (LL - 1);
    float* xbase = xt2 + (size_t)b * CC * LL + l0;

    // ---- load 16 tokens x 192 ch; float4 along token axis (contiguous) ----
    for (int idx = tid; idx < 4 * CC; idx += 256) {
        int c = idx >> 2, n4 = idx & 3;
        float4 v = *(const float4*)(xbase + (size_t)c * LL + n4 * 4);
        s_x[n4 * 4 + 0][c] = v.x;
        s_x[n4 * 4 + 1][c] = v.y;
        s_x[n4 * 4 + 2][c] = v.z;
        s_x[n4 * 4 + 3][c] = v.w;
    }
    __syncthreads();

    // ---- LN2: 16 lanes per token, shuffle reduce (all lanes of a token in one wave) ----
    {
        const int t = tid >> 4, s = tid & 15;
        float sum = 0.f, sq = 0.f;
        #pragma unroll
        for (int k = 0; k < 12; k++) {
            float v = s_x[t][s + 16 * k];
            sum += v; sq += v * v;
        }
        #pragma unroll
        for (int m = 1; m < 16; m <<= 1) {
            sum += __shfl_xor(sum, m);
            sq  += __shfl_xor(sq, m);
        }
        float mu = sum * (1.f / CC);
        float rs = rsqrtf(sq * (1.f / CC) - mu * mu + 1e-5f);
        #pragma unroll
        for (int k = 0; k < 12; k++) {
            int c = s + 16 * k;
            s_x[t][c] = (s_x[t][c] - mu) * rs * n2g[c] + n2b[c];
        }
    }
    __syncthreads();

    // ---- fc1 + exact gelu -> s_a.  768 oc: 192 oc-groups(4) x 4 tok-groups(4) = 3 passes ----
    const int tg = tid & 3;            // token group (invariant across passes)
    const int n0 = tg * 4;
    for (int it = 0; it < 3; it++) {
        const int og  = (it * 256 + tid) >> 2;   // 0..191
        const int oc0 = og * 4;
        const float* w0 = fc1w + (size_t)(oc0 + 0) * CC;
        const float* w1 = fc1w + (size_t)(oc0 + 1) * CC;
        const float* w2 = fc1w + (size_t)(oc0 + 2) * CC;
        const float* w3 = fc1w + (size_t)(oc0 + 3) * CC;
        float acc[4][4];
        #pragma unroll
        for (int o = 0; o < 4; o++)
            #pragma unroll
            for (int j = 0; j < 4; j++) acc[o][j] = 0.f;

        for (int k8 = 0; k8 < CC / 8; k8++) {
            const int kb = k8 * 8;
            float4 w0a = *(const float4*)(w0 + kb), w0b = *(const float4*)(w0 + kb + 4);
            float4 w1a = *(const float4*)(w1 + kb), w1b = *(const float4*)(w1 + kb + 4);
            float4 w2a = *(const float4*)(w2 + kb), w2b = *(const float4*)(w2 + kb + 4);
            float4 w3a = *(const float4*)(w3 + kb), w3b = *(const float4*)(w3 + kb + 4);
            float4 x0a = *(const float4*)(&s_x[n0 + 0][kb]), x0b = *(const float4*)(&s_x[n0 + 0][kb + 4]);
            float4 x1a = *(const float4*)(&s_x[n0 + 1][kb]), x1b = *(const float4*)(&s_x[n0 + 1][kb + 4]);
            float4 x2a = *(const float4*)(&s_x[n0 + 2][kb]), x2b = *(const float4*)(&s_x[n0 + 2][kb + 4]);
            float4 x3a = *(const float4*)(&s_x[n0 + 3][kb]), x3b = *(const float4*)(&s_x[n0 + 3][kb + 4]);
            acc[0][0] += dot8(x0a, x0b, w0a, w0b); acc[0][1] += dot8(x1a, x1b, w0a, w0b);
            acc[0][2] += dot8(x2a, x2b, w0a, w0b); acc[0][3] += dot8(x3a, x3b, w0a, w0b);
            acc[1][0] += dot8(x0a, x0b, w1a, w1b); acc[1][1] += dot8(x1a, x1b, w1a, w1b);
            acc[1][2] += dot8(x2a, x2b, w1a, w1b); acc[1][3] += dot8(x3a, x3b, w1a, w1b);
            acc[2][0] += dot8(x0a, x0b, w2a, w2b); acc[2][1] += dot8(x1a, x1b, w2a, w2b);
            acc[2][2] += dot8(x2a, x2b, w2a, w2b); acc[2][3] += dot8(x3a, x3b, w2a, w2b);
            acc[3][0] += dot8(x0a, x0b, w3a, w3b); acc[3][1] += dot8(x1a, x1b, w3a, w3b);
            acc[3][2] += dot8(x2a, x2b, w3a, w3b); acc[3][3] += dot8(x3a, x3b, w3a, w3b);
        }
        #pragma unroll
        for (int o = 0; o < 4; o++) {
            float bias = fc1b[oc0 + o];
            #pragma unroll
            for (int j = 0; j < 4; j++)
                s_a[n0 + j][oc0 + o] = gelu_exact(acc[o][j] + bias);
        }
    }
    __syncthreads();

    // ---- fc2 + residual.  192 oc: 64 oc-groups(3) x 4 tok-groups = 256 tasks, 1 pass ----
    {
        const int og  = tid >> 2;          // 0..63
        const int oc0 = og * 3;
        const float* w0 = fc2w + (size_t)(oc0 + 0) * HID;
        const float* w1 = fc2w + (size_t)(oc0 + 1) * HID;
        const float* w2 = fc2w + (size_t)(oc0 + 2) * HID;
        float acc[3][4];
        #pragma unroll
        for (int o = 0; o < 3; o++)
            #pragma unroll
            for (int j = 0; j < 4; j++) acc[o][j] = 0.f;

        for (int k8 = 0; k8 < HID / 8; k8++) {
            const int kb = k8 * 8;
            float4 w0a = *(const float4*)(w0 + kb), w0b = *(const float4*)(w0 + kb + 4);
            float4 w1a = *(const float4*)(w1 + kb), w1b = *(const float4*)(w1 + kb + 4);
            float4 w2a = *(const float4*)(w2 + kb), w2b = *(const float4*)(w2 + kb + 4);
            float4 a0a = *(const float4*)(&s_a[n0 + 0][kb]), a0b = *(const float4*)(&s_a[n0 + 0][kb + 4]);
            float4 a1a = *(const float4*)(&s_a[n0 + 1][kb]), a1b = *(const float4*)(&s_a[n0 + 1][kb + 4]);
            float4 a2a = *(const float4*)(&s_a[n0 + 2][kb]), a2b = *(const float4*)(&s_a[n0 + 2][kb + 4]);
            float4 a3a = *(const float4*)(&s_a[n0 + 3][kb]), a3b = *(const float4*)(&s_a[n0 + 3][kb + 4]);
            acc[0][0] += dot8(a0a, a0b, w0a, w0b); acc[0][1] += dot8(a1a, a1b, w0a, w0b);
            acc[0][2] += dot8(a2a, a2b, w0a, w0b); acc[0][3] += dot8(a3a, a3b, w0a, w0b);
            acc[1][0] += dot8(a0a, a0b, w1a, w1b); acc[1][1] += dot8(a1a, a1b, w1a, w1b);
            acc[1][2] += dot8(a2a, a2b, w1a, w1b); acc[1][3] += dot8(a3a, a3b, w1a, w1b);
            acc[2][0] += dot8(a0a, a0b, w2a, w2b); acc[2][1] += dot8(a1a, a1b, w2a, w2b);
            acc[2][2] += dot8(a2a, a2b, w2a, w2b); acc[2][3] += dot8(a3a, a3b, w2a, w2b);
        }
        #pragma unroll
        for (int o = 0; o < 3; o++) {
            const int c = oc0 + o;
            float bias = fc2b[c];
            float* p = xbase + (size_t)c * LL + n0;
            float4 r = *(const float4*)p;      // residual (only this thread writes these addrs)
            float4 outv;
            outv.x = acc[o][0] + bias + r.x;
            outv.y = acc[o][1] + bias + r.y;
            outv.z = acc[o][2] + bias + r.z;
            outv.w = acc[o][3] + bias + r.w;
            *(float4*)p = outv;
        }
    }
}

extern "C" void kernel_launch(void* const* d_in, const int* in_sizes, int n_in,
                              void* d_out, int out_size, void* d_ws, size_t ws_size,
                              hipStream_t stream) {
    const float* x     = (const float*)d_in[0];
    const int*   perm  = (const int*)d_in[1];
    const float* n1g   = (const float*)d_in[2];
    const float* n1b   = (const float*)d_in[3];
    const float* qkvw  = (const float*)d_in[4];
    const float* qkvb  = (const float*)d_in[5];
    const float* projw = (const float*)d_in[6];
    const float* projb = (const float*)d_in[7];
    const float* n2g   = (const float*)d_in[8];
    const float* n2b   = (const float*)d_in[9];
    const float* fc1w  = (const float*)d_in[10];
    const float* fc1b  = (const float*)d_in[11];
    const float* fc2w  = (const float*)d_in[12];
    const float* fc2b  = (const float*)d_in[13];

    float* out = (float*)d_out;   // (B,C,L) xt2 scratch, then final output (same layout)

    kA<<<16384, 256, 0, stream>>>(x, perm, n1g, n1b, qkvw, qkvb, projw, projb, out);
    kB<<<16384, 256, 0, stream>>>(out, n2g, n2b, fc1w, fc1b, fc2w, fc2b);
    (void)d_ws; (void)ws_size; (void)in_sizes; (void)n_in;
}

// Round 3
// 4903.259 us; speedup vs baseline: 19.1796x; 1.9689x over previous
//
#include <hip/hip_runtime.h>
#include <hip/hip_bf16.h>

#define BB 4
#define CC 192
#define LL 65536
#define WWW 256
#define HID 768
#define SXP (CC + 4)    // 196: row stride ≡ 4 mod 32
#define SQP (3*CC + 4)  // 580: row stride ≡ 4 mod 32 (fix 16-way conflict in QK^T)
#define SAP (HID + 4)   // 772

__device__ __forceinline__ float us2f(unsigned short u) { return __uint_as_float(((unsigned int)u) << 16); }
__device__ __forceinline__ unsigned short f2us(float f) {
    unsigned int x = __float_as_uint(f);
    unsigned int r = (x + 0x7FFFu + ((x >> 16) & 1u)) >> 16;
    return (unsigned short)r;
}

__device__ __forceinline__ float gelu_exact(float x) {
    return 0.5f * x * (1.0f + erff(x * 0.70710678118654752440f));
}

__device__ __forceinline__ float dot8(const float4 a, const float4 b, const float4 wa, const float4 wb) {
    return a.x*wa.x + a.y*wa.y + a.z*wa.z + a.w*wa.w
         + b.x*wb.x + b.y*wb.y + b.z*wb.z + b.w*wb.w;
}

// =================== FAST PATH (needs 402 MB workspace) ===================

// ---- kT: transpose x (B,C,L) f32 -> xT (B,L,C) f32, LDS-tiled, coalesced both sides ----
#define TLL 64
__global__ __launch_bounds__(256) void kT(const float* __restrict__ x, float* __restrict__ xT)
{
    __shared__ float s_t[TLL][SXP];    // [l][c], stride 196 (float4-aligned rows)
    const int tid = threadIdx.x;
    const int b  = blockIdx.x >> 10;          // 1024 l-tiles per batch
    const int l0 = (blockIdx.x & 1023) * TLL;

    // read: per c-row, 64 consecutive l as float4 (256 B per 16 lanes)
    #pragma unroll
    for (int p = 0; p < 12; p++) {
        int idx = tid + p * 256;              // 3072 float4
        int c = idx >> 4, l4 = idx & 15;
        float4 v = *(const float4*)(x + ((size_t)b * CC + c) * LL + l0 + l4 * 4);
        s_t[l4 * 4 + 0][c] = v.x;
        s_t[l4 * 4 + 1][c] = v.y;
        s_t[l4 * 4 + 2][c] = v.z;
        s_t[l4 * 4 + 3][c] = v.w;
    }
    __syncthreads();

    // write: per l-row, 192 consecutive c as float4 (768 B per 48 lanes)
    #pragma unroll
    for (int p = 0; p < 12; p++) {
        int idx = tid + p * 256;              // 3072 float4
        int l = idx / 48, c4 = idx % 48;
        float4 v = *(const float4*)(&s_t[l][c4 * 4]);
        *(float4*)(xT + ((size_t)b * LL + l0 + l) * CC + c4 * 4) = v;
    }
}

// ---- kA2: gather window rows from xT + LN1 + QKV + attn + proj + exact-f32 residual ----
// writes xt2 in (B,L,C) layout at original token positions.
__global__ __launch_bounds__(256) void kA2(
    const float* __restrict__ xT, const int* __restrict__ perm,
    const float* __restrict__ n1g, const float* __restrict__ n1b,
    const float* __restrict__ qkvw, const float* __restrict__ qkvb,
    const float* __restrict__ projw, const float* __restrict__ projb,
    float* __restrict__ xt2)
{
    __shared__ float s_h[16][SXP];     // raw -> LN'd -> (reused) o
    __shared__ float s_qkv[16][SQP];   // q|k|v per token (padded row)
    __shared__ float s_attn[96][17];   // padded to 17 (odd stride -> banks rotate)
    __shared__ int s_tok[16];

    const int tid = threadIdx.x;
    const int wid = blockIdx.x;
    const int b  = wid >> 12;
    const int hb = (wid >> 6) & 63;
    const int wb = wid & 63;

    if (tid < 16) {
        int si = tid >> 2, sj = tid & 3;
        s_tok[tid] = perm[(hb * 4 + si) * WWW + wb * 4 + sj];
    }
    __syncthreads();

    const float* xbT = xT + (size_t)b * LL * CC;

    // gather 16 token rows (768 B contiguous each)
    #pragma unroll
    for (int p = 0; p < 3; p++) {
        int idx = tid + p * 256;           // 768 float4
        int n = idx / 48, c4 = idx % 48;
        float4 v = *(const float4*)(xbT + (size_t)s_tok[n] * CC + c4 * 4);
        *(float4*)&s_h[n][c4 * 4] = v;
    }
    __syncthreads();

    // LN1: 16 lanes per token, shuffle reduce (wave-parallel)
    {
        const int t = tid >> 4, s = tid & 15;
        float sum = 0.f, sq = 0.f;
        #pragma unroll
        for (int k = 0; k < 12; k++) {
            float v = s_h[t][s + 16 * k];
            sum += v; sq += v * v;
        }
        #pragma unroll
        for (int m = 1; m < 16; m <<= 1) {
            sum += __shfl_xor(sum, m);
            sq  += __shfl_xor(sq, m);
        }
        float mu = sum * (1.f / CC);
        float rs = rsqrtf(sq * (1.f / CC) - mu * mu + 1e-5f);
        #pragma unroll
        for (int k = 0; k < 12; k++) {
            int c = s + 16 * k;
            s_h[t][c] = (s_h[t][c] - mu) * rs * n1g[c] + n1b[c];
        }
    }
    __syncthreads();

    // qkv: register-blocked 3oc x 4tok, 3 passes (576 oc = 192 og x 4 tg = 768 tasks)
    const int tg = tid & 3;
    const int n0 = tg * 4;
    for (int it = 0; it < 3; it++) {
        const int og  = (it * 256 + tid) >> 2;   // 0..191
        const int oc0 = og * 3;                  // 0..573
        const float* w0 = qkvw + (size_t)(oc0 + 0) * CC;
        const float* w1 = qkvw + (size_t)(oc0 + 1) * CC;
        const float* w2 = qkvw + (size_t)(oc0 + 2) * CC;
        float acc[3][4];
        #pragma unroll
        for (int o = 0; o < 3; o++)
            #pragma unroll
            for (int j = 0; j < 4; j++) acc[o][j] = 0.f;

        for (int k8 = 0; k8 < CC / 8; k8++) {
            const int kb = k8 * 8;
            float4 w0a = *(const float4*)(w0 + kb), w0b = *(const float4*)(w0 + kb + 4);
            float4 w1a = *(const float4*)(w1 + kb), w1b = *(const float4*)(w1 + kb + 4);
            float4 w2a = *(const float4*)(w2 + kb), w2b = *(const float4*)(w2 + kb + 4);
            float4 x0a = *(const float4*)(&s_h[n0 + 0][kb]), x0b = *(const float4*)(&s_h[n0 + 0][kb + 4]);
            float4 x1a = *(const float4*)(&s_h[n0 + 1][kb]), x1b = *(const float4*)(&s_h[n0 + 1][kb + 4]);
            float4 x2a = *(const float4*)(&s_h[n0 + 2][kb]), x2b = *(const float4*)(&s_h[n0 + 2][kb + 4]);
            float4 x3a = *(const float4*)(&s_h[n0 + 3][kb]), x3b = *(const float4*)(&s_h[n0 + 3][kb + 4]);
            acc[0][0] += dot8(x0a, x0b, w0a, w0b); acc[0][1] += dot8(x1a, x1b, w0a, w0b);
            acc[0][2] += dot8(x2a, x2b, w0a, w0b); acc[0][3] += dot8(x3a, x3b, w0a, w0b);
            acc[1][0] += dot8(x0a, x0b, w1a, w1b); acc[1][1] += dot8(x1a, x1b, w1a, w1b);
            acc[1][2] += dot8(x2a, x2b, w1a, w1b); acc[1][3] += dot8(x3a, x3b, w1a, w1b);
            acc[2][0] += dot8(x0a, x0b, w2a, w2b); acc[2][1] += dot8(x1a, x1b, w2a, w2b);
            acc[2][2] += dot8(x2a, x2b, w2a, w2b); acc[2][3] += dot8(x3a, x3b, w2a, w2b);
        }
        #pragma unroll
        for (int o = 0; o < 3; o++) {
            float bias = qkvb[oc0 + o];
            #pragma unroll
            for (int j = 0; j < 4; j++)
                s_qkv[n0 + j][oc0 + o] = acc[o][j] + bias;
        }
    }
    __syncthreads();

    // scores = SCALE * q @ k^T (6 heads x 16 x 16); s_qkv pad kills the 16-way conflict
    for (int idx = tid; idx < 1536; idx += 256) {
        int head = idx >> 8, r = (idx >> 4) & 15, col = idx & 15;
        float s = 0.f;
        for (int d = 0; d < 32; d++)
            s += s_qkv[r][head * 32 + d] * s_qkv[col][CC + head * 32 + d];
        s_attn[head * 16 + r][col] = s * 4.0f;
    }
    __syncthreads();

    // softmax over 16 keys
    if (tid < 96) {
        float mx = -1e30f;
        for (int i = 0; i < 16; i++) mx = fmaxf(mx, s_attn[tid][i]);
        float ss = 0.f;
        for (int i = 0; i < 16; i++) { float e = __expf(s_attn[tid][i] - mx); ss += e; s_attn[tid][i] = e; }
        float inv = 1.f / ss;
        for (int i = 0; i < 16; i++) s_attn[tid][i] *= inv;
    }
    __syncthreads();

    // o = attn @ v  (into s_h, reuse)
    for (int idx = tid; idx < 16 * CC; idx += 256) {
        int n = idx / CC, c = idx - n * CC;
        int head = c >> 5;
        float s = 0.f;
        for (int m = 0; m < 16; m++) s += s_attn[head * 16 + n][m] * s_qkv[m][2 * CC + c];
        s_h[n][c] = s;
    }
    __syncthreads();

    // proj: 3oc x 4tok, 1 pass; + exact f32 residual from xT; write xt2 (B,L,C) rows
    {
        const int og  = tid >> 2;          // 0..63
        const int oc0 = og * 3;
        const float* w0 = projw + (size_t)(oc0 + 0) * CC;
        const float* w1 = projw + (size_t)(oc0 + 1) * CC;
        const float* w2 = projw + (size_t)(oc0 + 2) * CC;
        float acc[3][4];
        #pragma unroll
        for (int o = 0; o < 3; o++)
            #pragma unroll
            for (int j = 0; j < 4; j++) acc[o][j] = 0.f;

        for (int k8 = 0; k8 < CC / 8; k8++) {
            const int kb = k8 * 8;
            float4 w0a = *(const float4*)(w0 + kb), w0b = *(const float4*)(w0 + kb + 4);
            float4 w1a = *(const float4*)(w1 + kb), w1b = *(const float4*)(w1 + kb + 4);
            float4 w2a = *(const float4*)(w2 + kb), w2b = *(const float4*)(w2 + kb + 4);
            float4 h0a = *(const float4*)(&s_h[n0 + 0][kb]), h0b = *(const float4*)(&s_h[n0 + 0][kb + 4]);
            float4 h1a = *(const float4*)(&s_h[n0 + 1][kb]), h1b = *(const float4*)(&s_h[n0 + 1][kb + 4]);
            float4 h2a = *(const float4*)(&s_h[n0 + 2][kb]), h2b = *(const float4*)(&s_h[n0 + 2][kb + 4]);
            float4 h3a = *(const float4*)(&s_h[n0 + 3][kb]), h3b = *(const float4*)(&s_h[n0 + 3][kb + 4]);
            acc[0][0] += dot8(h0a, h0b, w0a, w0b); acc[0][1] += dot8(h1a, h1b, w0a, w0b);
            acc[0][2] += dot8(h2a, h2b, w0a, w0b); acc[0][3] += dot8(h3a, h3b, w0a, w0b);
            acc[1][0] += dot8(h0a, h0b, w1a, w1b); acc[1][1] += dot8(h1a, h1b, w1a, w1b);
            acc[1][2] += dot8(h2a, h2b, w1a, w1b); acc[1][3] += dot8(h3a, h3b, w1a, w1b);
            acc[2][0] += dot8(h0a, h0b, w2a, w2b); acc[2][1] += dot8(h1a, h1b, w2a, w2b);
            acc[2][2] += dot8(h2a, h2b, w2a, w2b); acc[2][3] += dot8(h3a, h3b, w2a, w2b);
        }
        float* xo = xt2 + (size_t)b * LL * CC;
        #pragma unroll
        for (int o = 0; o < 3; o++) {
            const int c = oc0 + o;
            float bias = projb[c];
            #pragma unroll
            for (int j = 0; j < 4; j++) {
                const size_t row = (size_t)s_tok[n0 + j] * CC;
                float res = xbT[row + c];                    // exact f32 shortcut
                xo[row + c] = acc[o][j] + bias + res;
            }
        }
    }
}

// ---- kB2: LN2 + MLP + residual; reads xt2 (B,L,C) rows, writes final (B,C,L) ----
__global__ __launch_bounds__(256, 2) void kB2(
    const float* __restrict__ xt2,
    const float* __restrict__ n2g, const float* __restrict__ n2b,
    const float* __restrict__ fc1w, const float* __restrict__ fc1b,
    const float* __restrict__ fc2w, const float* __restrict__ fc2b,
    float* __restrict__ out)
{
    __shared__ float s_x[16][SXP];
    __shared__ float s_a[16][SAP];

    const int tid = threadIdx.x;
    const int t0 = blockIdx.x * 16;
    const int b  = t0 >> 16;
    const int l0 = t0 & (LL - 1);
    const float* xrow = xt2 + ((size_t)b * LL + l0) * CC;   // 16 rows, fully contiguous

    // fully-coalesced row load (12 KB contiguous per block)
    #pragma unroll
    for (int p = 0; p < 3; p++) {
        int idx = tid + p * 256;
        int n = idx / 48, c4 = idx % 48;
        float4 v = *(const float4*)(xrow + (size_t)n * CC + c4 * 4);
        *(float4*)&s_x[n][c4 * 4] = v;
    }
    __syncthreads();

    // LN2 shuffle reduce
    {
        const int t = tid >> 4, s = tid & 15;
        float sum = 0.f, sq = 0.f;
        #pragma unroll
        for (int k = 0; k < 12; k++) {
            float v = s_x[t][s + 16 * k];
            sum += v; sq += v * v;
        }
        #pragma unroll
        for (int m = 1; m < 16; m <<= 1) {
            sum += __shfl_xor(sum, m);
            sq  += __shfl_xor(sq, m);
        }
        float mu = sum * (1.f / CC);
        float rs = rsqrtf(sq * (1.f / CC) - mu * mu + 1e-5f);
        #pragma unroll
        for (int k = 0; k < 12; k++) {
            int c = s + 16 * k;
            s_x[t][c] = (s_x[t][c] - mu) * rs * n2g[c] + n2b[c];
        }
    }
    __syncthreads();

    // fc1 + exact gelu: 4oc x 4tok, 3 passes
    const int tg = tid & 3;
    const int n0 = tg * 4;
    for (int it = 0; it < 3; it++) {
        const int og  = (it * 256 + tid) >> 2;   // 0..191
        const int oc0 = og * 4;
        const float* w0 = fc1w + (size_t)(oc0 + 0) * CC;
        const float* w1 = fc1w + (size_t)(oc0 + 1) * CC;
        const float* w2 = fc1w + (size_t)(oc0 + 2) * CC;
        const float* w3 = fc1w + (size_t)(oc0 + 3) * CC;
        float acc[4][4];
        #pragma unroll
        for (int o = 0; o < 4; o++)
            #pragma unroll
            for (int j = 0; j < 4; j++) acc[o][j] = 0.f;

        for (int k8 = 0; k8 < CC / 8; k8++) {
            const int kb = k8 * 8;
            float4 w0a = *(const float4*)(w0 + kb), w0b = *(const float4*)(w0 + kb + 4);
            float4 w1a = *(const float4*)(w1 + kb), w1b = *(const float4*)(w1 + kb + 4);
            float4 w2a = *(const float4*)(w2 + kb), w2b = *(const float4*)(w2 + kb + 4);
            float4 w3a = *(const float4*)(w3 + kb), w3b = *(const float4*)(w3 + kb + 4);
            float4 x0a = *(const float4*)(&s_x[n0 + 0][kb]), x0b = *(const float4*)(&s_x[n0 + 0][kb + 4]);
            float4 x1a = *(const float4*)(&s_x[n0 + 1][kb]), x1b = *(const float4*)(&s_x[n0 + 1][kb + 4]);
            float4 x2a = *(const float4*)(&s_x[n0 + 2][kb]), x2b = *(const float4*)(&s_x[n0 + 2][kb + 4]);
            float4 x3a = *(const float4*)(&s_x[n0 + 3][kb]), x3b = *(const float4*)(&s_x[n0 + 3][kb + 4]);
            acc[0][0] += dot8(x0a, x0b, w0a, w0b); acc[0][1] += dot8(x1a, x1b, w0a, w0b);
            acc[0][2] += dot8(x2a, x2b, w0a, w0b); acc[0][3] += dot8(x3a, x3b, w0a, w0b);
            acc[1][0] += dot8(x0a, x0b, w1a, w1b); acc[1][1] += dot8(x1a, x1b, w1a, w1b);
            acc[1][2] += dot8(x2a, x2b, w1a, w1b); acc[1][3] += dot8(x3a, x3b, w1a, w1b);
            acc[2][0] += dot8(x0a, x0b, w2a, w2b); acc[2][1] += dot8(x1a, x1b, w2a, w2b);
            acc[2][2] += dot8(x2a, x2b, w2a, w2b); acc[2][3] += dot8(x3a, x3b, w2a, w2b);
            acc[3][0] += dot8(x0a, x0b, w3a, w3b); acc[3][1] += dot8(x1a, x1b, w3a, w3b);
            acc[3][2] += dot8(x2a, x2b, w3a, w3b); acc[3][3] += dot8(x3a, x3b, w3a, w3b);
        }
        #pragma unroll
        for (int o = 0; o < 4; o++) {
            float bias = fc1b[oc0 + o];
            #pragma unroll
            for (int j = 0; j < 4; j++)
                s_a[n0 + j][oc0 + o] = gelu_exact(acc[o][j] + bias);
        }
    }
    __syncthreads();

    // fc2 + residual; write final output in (B,C,L)
    {
        const int og  = tid >> 2;          // 0..63
        const int oc0 = og * 3;
        const float* w0 = fc2w + (size_t)(oc0 + 0) * HID;
        const float* w1 = fc2w + (size_t)(oc0 + 1) * HID;
        const float* w2 = fc2w + (size_t)(oc0 + 2) * HID;
        float acc[3][4];
        #pragma unroll
        for (int o = 0; o < 3; o++)
            #pragma unroll
            for (int j = 0; j < 4; j++) acc[o][j] = 0.f;

        for (int k8 = 0; k8 < HID / 8; k8++) {
            const int kb = k8 * 8;
            float4 w0a = *(const float4*)(w0 + kb), w0b = *(const float4*)(w0 + kb + 4);
            float4 w1a = *(const float4*)(w1 + kb), w1b = *(const float4*)(w1 + kb + 4);
            float4 w2a = *(const float4*)(w2 + kb), w2b = *(const float4*)(w2 + kb + 4);
            float4 a0a = *(const float4*)(&s_a[n0 + 0][kb]), a0b = *(const float4*)(&s_a[n0 + 0][kb + 4]);
            float4 a1a = *(const float4*)(&s_a[n0 + 1][kb]), a1b = *(const float4*)(&s_a[n0 + 1][kb + 4]);
            float4 a2a = *(const float4*)(&s_a[n0 + 2][kb]), a2b = *(const float4*)(&s_a[n0 + 2][kb + 4]);
            float4 a3a = *(const float4*)(&s_a[n0 + 3][kb]), a3b = *(const float4*)(&s_a[n0 + 3][kb + 4]);
            acc[0][0] += dot8(a0a, a0b, w0a, w0b); acc[0][1] += dot8(a1a, a1b, w0a, w0b);
            acc[0][2] += dot8(a2a, a2b, w0a, w0b); acc[0][3] += dot8(a3a, a3b, w0a, w0b);
            acc[1][0] += dot8(a0a, a0b, w1a, w1b); acc[1][1] += dot8(a1a, a1b, w1a, w1b);
            acc[1][2] += dot8(a2a, a2b, w1a, w1b); acc[1][3] += dot8(a3a, a3b, w1a, w1b);
            acc[2][0] += dot8(a0a, a0b, w2a, w2b); acc[2][1] += dot8(a1a, a1b, w2a, w2b);
            acc[2][2] += dot8(a2a, a2b, w2a, w2b); acc[2][3] += dot8(a3a, a3b, w2a, w2b);
        }
        #pragma unroll
        for (int o = 0; o < 3; o++) {
            const int c = oc0 + o;
            float bias = fc2b[c];
            float4 outv;
            float r0 = xrow[(size_t)(n0 + 0) * CC + c];   // L2-hot residual re-read (exact)
            float r1 = xrow[(size_t)(n0 + 1) * CC + c];
            float r2 = xrow[(size_t)(n0 + 2) * CC + c];
            float r3 = xrow[(size_t)(n0 + 3) * CC + c];
            outv.x = acc[o][0] + bias + r0;
            outv.y = acc[o][1] + bias + r1;
            outv.z = acc[o][2] + bias + r2;
            outv.w = acc[o][3] + bias + r3;
            *(float4*)(out + ((size_t)b * CC + c) * LL + l0 + n0) = outv;
        }
    }
}

// =================== FALLBACK PATH (no workspace): round-2 kernels, verbatim ===================

__global__ __launch_bounds__(256) void kA(
    const float* __restrict__ x, const int* __restrict__ perm,
    const float* __restrict__ n1g, const float* __restrict__ n1b,
    const float* __restrict__ qkvw, const float* __restrict__ qkvb,
    const float* __restrict__ projw, const float* __restrict__ projb,
    float* __restrict__ xt2)
{
    __shared__ float s_h[16][CC];
    __shared__ float s_qkv[16][3*CC];
    __shared__ float s_attn[96][16];
    __shared__ unsigned short s_stash[16][CC];
    __shared__ float s_mu[16], s_rs[16];
    __shared__ int s_tok[16];

    const int tid = threadIdx.x;
    const int wid = blockIdx.x;
    const int b  = wid >> 12;
    const int hb = (wid >> 6) & 63;
    const int wb = wid & 63;

    if (tid < 16) {
        int si = tid >> 2, sj = tid & 3;
        s_tok[tid] = perm[(hb * 4 + si) * WWW + wb * 4 + sj];
    }
    __syncthreads();

    for (int idx = tid; idx < 16 * CC; idx += 256) {
        int n = idx / CC, c = idx - n * CC;
        float v = x[((size_t)b * CC + c) * LL + s_tok[n]];
        s_h[n][c] = v;
        s_stash[n][c] = f2us(v);
    }
    __syncthreads();

    if (tid < 16) {
        float s = 0.f, q = 0.f;
        for (int c = 0; c < CC; c++) { float v = s_h[tid][c]; s += v; q += v * v; }
        float mu = s * (1.f / CC);
        float var = q * (1.f / CC) - mu * mu;
        s_mu[tid] = mu;
        s_rs[tid] = rsqrtf(var + 1e-5f);
    }
    __syncthreads();

    for (int idx = tid; idx < 16 * CC; idx += 256) {
        int n = idx / CC, c = idx - n * CC;
        s_h[n][c] = (s_h[n][c] - s_mu[n]) * s_rs[n] * n1g[c] + n1b[c];
    }
    __syncthreads();

    for (int oc = tid; oc < 3 * CC; oc += 256) {
        float acc[16];
        for (int i = 0; i < 16; i++) acc[i] = 0.f;
        const float4* wr = (const float4*)(qkvw + (size_t)oc * CC);
        for (int k8 = 0; k8 < CC / 8; ++k8) {
            float4 wa = wr[k8 * 2], wb2 = wr[k8 * 2 + 1];
            for (int n = 0; n < 16; n++) {
                const float4* hp = (const float4*)(&s_h[n][k8 * 8]);
                acc[n] += dot8(hp[0], hp[1], wa, wb2);
            }
        }
        float bias = qkvb[oc];
        for (int n = 0; n < 16; n++) s_qkv[n][oc] = acc[n] + bias;
    }
    __syncthreads();

    for (int idx = tid; idx < 1536; idx += 256) {
        int head = idx >> 8, r = (idx >> 4) & 15, col = idx & 15;
        float s = 0.f;
        for (int d = 0; d < 32; d++)
            s += s_qkv[r][head * 32 + d] * s_qkv[col][CC + head * 32 + d];
        s_attn[head * 16 + r][col] = s * 4.0f;
    }
    __syncthreads();

    if (tid < 96) {
        float mx = -1e30f;
        for (int i = 0; i < 16; i++) mx = fmaxf(mx, s_attn[tid][i]);
        float ss = 0.f;
        for (int i = 0; i < 16; i++) { float e = __expf(s_attn[tid][i] - mx); ss += e; s_attn[tid][i] = e; }
        float inv = 1.f / ss;
        for (int i = 0; i < 16; i++) s_attn[tid][i] *= inv;
    }
    __syncthreads();

    for (int idx = tid; idx < 16 * CC; idx += 256) {
        int n = idx / CC, c = idx - n * CC;
        int head = c >> 5;
        float s = 0.f;
        for (int m = 0; m < 16; m++) s += s_attn[head * 16 + n][m] * s_qkv[m][2 * CC + c];
        s_h[n][c] = s;
    }
    __syncthreads();

    if (tid < CC) {
        const int c = tid;
        float acc[16];
        for (int i = 0; i < 16; i++) acc[i] = 0.f;
        const float4* wr = (const float4*)(projw + (size_t)c * CC);
        for (int k8 = 0; k8 < CC / 8; ++k8) {
            float4 wa = wr[k8 * 2], wb2 = wr[k8 * 2 + 1];
            for (int n = 0; n < 16; n++) {
                const float4* hp = (const float4*)(&s_h[n][k8 * 8]);
                acc[n] += dot8(hp[0], hp[1], wa, wb2);
            }
        }
        float bias = projb[c];
        for (int n = 0; n < 16; n++) {
            float res = us2f(s_stash[n][c]);
            xt2[((size_t)b * CC + c) * LL + s_tok[n]] = acc[n] + bias + res;
        }
    }
}

__global__ __launch_bounds__(256, 2) void kB(
    float* __restrict__ xt2,
    const float* __restrict__ n2g, const float* __restrict__ n2b,
    const float* __restrict__ fc1w, const float* __restrict__ fc1b,
    const float* __restrict__ fc2w, const float* __restrict__ fc2b)
{
    __shared__ float s_x[16][SXP];
    __shared__ float s_a[16][SAP];

    const int tid = threadIdx.x;
    const int t0 = blockIdx.x * 16;
    const int b  = t0 >> 16;
    const int l0 = t0 & (LL - 1);
    float* xbase = xt2 + (size_t)b * CC * LL + l0;

    for (int idx = tid; idx < 4 * CC; idx += 256) {
        int c = idx >> 2, n4 = idx & 3;
        float4 v = *(const float4*)(xbase + (size_t)c * LL + n4 * 4);
        s_x[n4 * 4 + 0][c] = v.x;
        s_x[n4 * 4 + 1][c] = v.y;
        s_x[n4 * 4 + 2][c] = v.z;
        s_x[n4 * 4 + 3][c] = v.w;
    }
    __syncthreads();

    {
        const int t = tid >> 4, s = tid & 15;
        float sum = 0.f, sq = 0.f;
        #pragma unroll
        for (int k = 0; k < 12; k++) {
            float v = s_x[t][s + 16 * k];
            sum += v; sq += v * v;
        }
        #pragma unroll
        for (int m = 1; m < 16; m <<= 1) {
            sum += __shfl_xor(sum, m);
            sq  += __shfl_xor(sq, m);
        }
        float mu = sum * (1.f / CC);
        float rs = rsqrtf(sq * (1.f / CC) - mu * mu + 1e-5f);
        #pragma unroll
        for (int k = 0; k < 12; k++) {
            int c = s + 16 * k;
            s_x[t][c] = (s_x[t][c] - mu) * rs * n2g[c] + n2b[c];
        }
    }
    __syncthreads();

    const int tg = tid & 3;
    const int n0 = tg * 4;
    for (int it = 0; it < 3; it++) {
        const int og  = (it * 256 + tid) >> 2;
        const int oc0 = og * 4;
        const float* w0 = fc1w + (size_t)(oc0 + 0) * CC;
        const float* w1 = fc1w + (size_t)(oc0 + 1) * CC;
        const float* w2 = fc1w + (size_t)(oc0 + 2) * CC;
        const float* w3 = fc1w + (size_t)(oc0 + 3) * CC;
        float acc[4][4];
        #pragma unroll
        for (int o = 0; o < 4; o++)
            #pragma unroll
            for (int j = 0; j < 4; j++) acc[o][j] = 0.f;

        for (int k8 = 0; k8 < CC / 8; k8++) {
            const int kb = k8 * 8;
            float4 w0a = *(const float4*)(w0 + kb), w0b = *(const float4*)(w0 + kb + 4);
            float4 w1a = *(const float4*)(w1 + kb), w1b = *(const float4*)(w1 + kb + 4);
            float4 w2a = *(const float4*)(w2 + kb), w2b = *(const float4*)(w2 + kb + 4);
            float4 w3a = *(const float4*)(w3 + kb), w3b = *(const float4*)(w3 + kb + 4);
            float4 x0a = *(const float4*)(&s_x[n0 + 0][kb]), x0b = *(const float4*)(&s_x[n0 + 0][kb + 4]);
            float4 x1a = *(const float4*)(&s_x[n0 + 1][kb]), x1b = *(const float4*)(&s_x[n0 + 1][kb + 4]);
            float4 x2a = *(const float4*)(&s_x[n0 + 2][kb]), x2b = *(const float4*)(&s_x[n0 + 2][kb + 4]);
            float4 x3a = *(const float4*)(&s_x[n0 + 3][kb]), x3b = *(const float4*)(&s_x[n0 + 3][kb + 4]);
            acc[0][0] += dot8(x0a, x0b, w0a, w0b); acc[0][1] += dot8(x1a, x1b, w0a, w0b);
            acc[0][2] += dot8(x2a, x2b, w0a, w0b); acc[0][3] += dot8(x3a, x3b, w0a, w0b);
            acc[1][0] += dot8(x0a, x0b, w1a, w1b); acc[1][1] += dot8(x1a, x1b, w1a, w1b);
            acc[1][2] += dot8(x2a, x2b, w1a, w1b); acc[1][3] += dot8(x3a, x3b, w1a, w1b);
            acc[2][0] += dot8(x0a, x0b, w2a, w2b); acc[2][1] += dot8(x1a, x1b, w2a, w2b);
            acc[2][2] += dot8(x2a, x2b, w2a, w2b); acc[2][3] += dot8(x3a, x3b, w2a, w2b);
            acc[3][0] += dot8(x0a, x0b, w3a, w3b); acc[3][1] += dot8(x1a, x1b, w3a, w3b);
            acc[3][2] += dot8(x2a, x2b, w3a, w3b); acc[3][3] += dot8(x3a, x3b, w3a, w3b);
        }
        #pragma unroll
        for (int o = 0; o < 4; o++) {
            float bias = fc1b[oc0 + o];
            #pragma unroll
            for (int j = 0; j < 4; j++)
                s_a[n0 + j][oc0 + o] = gelu_exact(acc[o][j] + bias);
        }
    }
    __syncthreads();

    {
        const int og  = tid >> 2;
        const int oc0 = og * 3;
        const float* w0 = fc2w + (size_t)(oc0 + 0) * HID;
        const float* w1 = fc2w + (size_t)(oc0 + 1) * HID;
        const float* w2 = fc2w + (size_t)(oc0 + 2) * HID;
        float acc[3][4];
        #pragma unroll
        for (int o = 0; o < 3; o++)
            #pragma unroll
            for (int j = 0; j < 4; j++) acc[o][j] = 0.f;

        for (int k8 = 0; k8 < HID / 8; k8++) {
            const int kb = k8 * 8;
            float4 w0a = *(const float4*)(w0 + kb), w0b = *(const float4*)(w0 + kb + 4);
            float4 w1a = *(const float4*)(w1 + kb), w1b = *(const float4*)(w1 + kb + 4);
            float4 w2a = *(const float4*)(w2 + kb), w2b = *(const float4*)(w2 + kb + 4);
            float4 a0a = *(const float4*)(&s_a[n0 + 0][kb]), a0b = *(const float4*)(&s_a[n0 + 0][kb + 4]);
            float4 a1a = *(const float4*)(&s_a[n0 + 1][kb]), a1b = *(const float4*)(&s_a[n0 + 1][kb + 4]);
            float4 a2a = *(const float4*)(&s_a[n0 + 2][kb]), a2b = *(const float4*)(&s_a[n0 + 2][kb + 4]);
            float4 a3a = *(const float4*)(&s_a[n0 + 3][kb]), a3b = *(const float4*)(&s_a[n0 + 3][kb + 4]);
            acc[0][0] += dot8(a0a, a0b, w0a, w0b); acc[0][1] += dot8(a1a, a1b, w0a, w0b);
            acc[0][2] += dot8(a2a, a2b, w0a, w0b); acc[0][3] += dot8(a3a, a3b, w0a, w0b);
            acc[1][0] += dot8(a0a, a0b, w1a, w1b); acc[1][1] += dot8(a1a, a1b, w1a, w1b);
            acc[1][2] += dot8(a2a, a2b, w1a, w1b); acc[1][3] += dot8(a3a, a3b, w1a, w1b);
            acc[2][0] += dot8(a0a, a0b, w2a, w2b); acc[2][1] += dot8(a1a, a1b, w2a, w2b);
            acc[2][2] += dot8(a2a, a2b, w2a, w2b); acc[2][3] += dot8(a3a, a3b, w2a, w2b);
        }
        #pragma unroll
        for (int o = 0; o < 3; o++) {
            const int c = oc0 + o;
            float bias = fc2b[c];
            float* p = xbase + (size_t)c * LL + n0;
            float4 r = *(const float4*)p;
            float4 outv;
            outv.x = acc[o][0] + bias + r.x;
            outv.y = acc[o][1] + bias + r.y;
            outv.z = acc[o][2] + bias + r.z;
            outv.w = acc[o][3] + bias + r.w;
            *(float4*)p = outv;
        }
    }
}

extern "C" void kernel_launch(void* const* d_in, const int* in_sizes, int n_in,
                              void* d_out, int out_size, void* d_ws, size_t ws_size,
                              hipStream_t stream) {
    const float* x     = (const float*)d_in[0];
    const int*   perm  = (const int*)d_in[1];
    const float* n1g   = (const float*)d_in[2];
    const float* n1b   = (const float*)d_in[3];
    const float* qkvw  = (const float*)d_in[4];
    const float* qkvb  = (const float*)d_in[5];
    const float* projw = (const float*)d_in[6];
    const float* projb = (const float*)d_in[7];
    const float* n2g   = (const float*)d_in[8];
    const float* n2b   = (const float*)d_in[9];
    const float* fc1w  = (const float*)d_in[10];
    const float* fc1b  = (const float*)d_in[11];
    const float* fc2w  = (const float*)d_in[12];
    const float* fc2b  = (const float*)d_in[13];

    const size_t NTOK = (size_t)BB * LL * CC;            // 50,331,648 floats
    const size_t WS_NEED = 2 * NTOK * sizeof(float);     // xT + xt2 (B,L,C)

    if (d_ws != nullptr && ws_size >= WS_NEED) {
        float* xT   = (float*)d_ws;          // (B,L,C) transposed input
        float* xt2w = xT + NTOK;             // (B,L,C) attn residual stream
        kT <<<BB * (LL / TLL), 256, 0, stream>>>(x, xT);
        kA2<<<16384, 256, 0, stream>>>(xT, perm, n1g, n1b, qkvw, qkvb, projw, projb, xt2w);
        kB2<<<16384, 256, 0, stream>>>(xt2w, n2g, n2b, fc1w, fc1b, fc2w, fc2b, (float*)d_out);
    } else {
        float* out = (float*)d_out;
        kA<<<16384, 256, 0, stream>>>(x, perm, n1g, n1b, qkvw, qkvb, projw, projb, out);
        kB<<<16384, 256, 0, stream>>>(out, n2g, n2b, fc1w, fc1b, fc2w, fc2b);
    }
    (void)in_sizes; (void)n_in; (void)out_size;
}

// Round 4
// 3109.827 us; speedup vs baseline: 30.2404x; 1.5767x over previous
//
#include <hip/hip_runtime.h>
#include <hip/hip_bf16.h>

#define BB 4
#define CC 192
#define LL 65536
#define WWW 256
#define HID 768
#define SXP (CC + 4)    // 196 f32: row stride ≡ 4 mod 32
#define SQP (3*CC + 4)  // 580
#define SAP (HID + 4)   // 772
#define SXBP 200        // bf16 row stride (400 B): (m+g)%8 uniform for b128 frag reads
#define SABP 776        // bf16 row stride (1552 B): same property

typedef short bf16x8 __attribute__((ext_vector_type(8)));
typedef float f32x4  __attribute__((ext_vector_type(4)));

__device__ __forceinline__ float us2f(unsigned short u) { return __uint_as_float(((unsigned int)u) << 16); }
__device__ __forceinline__ unsigned short f2us(float f) {
    unsigned int x = __float_as_uint(f);
    unsigned int r = (x + 0x7FFFu + ((x >> 16) & 1u)) >> 16;
    return (unsigned short)r;
}

__device__ __forceinline__ float gelu_exact(float x) {
    return 0.5f * x * (1.0f + erff(x * 0.70710678118654752440f));
}

__device__ __forceinline__ float dot8(const float4 a, const float4 b, const float4 wa, const float4 wb) {
    return a.x*wa.x + a.y*wa.y + a.z*wa.z + a.w*wa.w
         + b.x*wb.x + b.y*wb.y + b.z*wb.z + b.w*wb.w;
}

// =================== FAST PATH ===================

// ---- kW: convert fc1w/fc2w f32 -> bf16 (147456 elements each) ----
__global__ __launch_bounds__(256) void kW(
    const float* __restrict__ fc1w, const float* __restrict__ fc2w,
    unsigned short* __restrict__ fc1wb, unsigned short* __restrict__ fc2wb)
{
    int i = blockIdx.x * 256 + threadIdx.x;
    if (i < HID * CC) {
        fc1wb[i] = f2us(fc1w[i]);
        fc2wb[i] = f2us(fc2w[i]);
    }
}

// ---- kT: transpose x (B,C,L) f32 -> xT (B,L,C) f32 ----
#define TLL 64
__global__ __launch_bounds__(256) void kT(const float* __restrict__ x, float* __restrict__ xT)
{
    __shared__ float s_t[TLL][SXP];
    const int tid = threadIdx.x;
    const int b  = blockIdx.x >> 10;
    const int l0 = (blockIdx.x & 1023) * TLL;

    #pragma unroll
    for (int p = 0; p < 12; p++) {
        int idx = tid + p * 256;
        int c = idx >> 4, l4 = idx & 15;
        float4 v = *(const float4*)(x + ((size_t)b * CC + c) * LL + l0 + l4 * 4);
        s_t[l4 * 4 + 0][c] = v.x;
        s_t[l4 * 4 + 1][c] = v.y;
        s_t[l4 * 4 + 2][c] = v.z;
        s_t[l4 * 4 + 3][c] = v.w;
    }
    __syncthreads();

    #pragma unroll
    for (int p = 0; p < 12; p++) {
        int idx = tid + p * 256;
        int l = idx / 48, c4 = idx % 48;
        float4 v = *(const float4*)(&s_t[l][c4 * 4]);
        *(float4*)(xT + ((size_t)b * LL + l0 + l) * CC + c4 * 4) = v;
    }
}

// ---- kA2: gather window rows + LN1 + QKV + attn + proj + exact residual ----
__global__ __launch_bounds__(256) void kA2(
    const float* __restrict__ xT, const int* __restrict__ perm,
    const float* __restrict__ n1g, const float* __restrict__ n1b,
    const float* __restrict__ qkvw, const float* __restrict__ qkvb,
    const float* __restrict__ projw, const float* __restrict__ projb,
    float* __restrict__ xt2)
{
    __shared__ float s_h[16][SXP];
    __shared__ float s_qkv[16][SQP];
    __shared__ float s_attn[96][17];
    __shared__ int s_tok[16];

    const int tid = threadIdx.x;
    const int wid = blockIdx.x;
    const int b  = wid >> 12;
    const int hb = (wid >> 6) & 63;
    const int wb = wid & 63;

    if (tid < 16) {
        int si = tid >> 2, sj = tid & 3;
        s_tok[tid] = perm[(hb * 4 + si) * WWW + wb * 4 + sj];
    }
    __syncthreads();

    const float* xbT = xT + (size_t)b * LL * CC;

    #pragma unroll
    for (int p = 0; p < 3; p++) {
        int idx = tid + p * 256;
        int n = idx / 48, c4 = idx % 48;
        float4 v = *(const float4*)(xbT + (size_t)s_tok[n] * CC + c4 * 4);
        *(float4*)&s_h[n][c4 * 4] = v;
    }
    __syncthreads();

    {
        const int t = tid >> 4, s = tid & 15;
        float sum = 0.f, sq = 0.f;
        #pragma unroll
        for (int k = 0; k < 12; k++) {
            float v = s_h[t][s + 16 * k];
            sum += v; sq += v * v;
        }
        #pragma unroll
        for (int m = 1; m < 16; m <<= 1) {
            sum += __shfl_xor(sum, m);
            sq  += __shfl_xor(sq, m);
        }
        float mu = sum * (1.f / CC);
        float rs = rsqrtf(sq * (1.f / CC) - mu * mu + 1e-5f);
        #pragma unroll
        for (int k = 0; k < 12; k++) {
            int c = s + 16 * k;
            s_h[t][c] = (s_h[t][c] - mu) * rs * n1g[c] + n1b[c];
        }
    }
    __syncthreads();

    const int tg = tid & 3;
    const int n0 = tg * 4;
    for (int it = 0; it < 3; it++) {
        const int og  = (it * 256 + tid) >> 2;
        const int oc0 = og * 3;
        const float* w0 = qkvw + (size_t)(oc0 + 0) * CC;
        const float* w1 = qkvw + (size_t)(oc0 + 1) * CC;
        const float* w2 = qkvw + (size_t)(oc0 + 2) * CC;
        float acc[3][4];
        #pragma unroll
        for (int o = 0; o < 3; o++)
            #pragma unroll
            for (int j = 0; j < 4; j++) acc[o][j] = 0.f;

        for (int k8 = 0; k8 < CC / 8; k8++) {
            const int kb = k8 * 8;
            float4 w0a = *(const float4*)(w0 + kb), w0b = *(const float4*)(w0 + kb + 4);
            float4 w1a = *(const float4*)(w1 + kb), w1b = *(const float4*)(w1 + kb + 4);
            float4 w2a = *(const float4*)(w2 + kb), w2b = *(const float4*)(w2 + kb + 4);
            float4 x0a = *(const float4*)(&s_h[n0 + 0][kb]), x0b = *(const float4*)(&s_h[n0 + 0][kb + 4]);
            float4 x1a = *(const float4*)(&s_h[n0 + 1][kb]), x1b = *(const float4*)(&s_h[n0 + 1][kb + 4]);
            float4 x2a = *(const float4*)(&s_h[n0 + 2][kb]), x2b = *(const float4*)(&s_h[n0 + 2][kb + 4]);
            float4 x3a = *(const float4*)(&s_h[n0 + 3][kb]), x3b = *(const float4*)(&s_h[n0 + 3][kb + 4]);
            acc[0][0] += dot8(x0a, x0b, w0a, w0b); acc[0][1] += dot8(x1a, x1b, w0a, w0b);
            acc[0][2] += dot8(x2a, x2b, w0a, w0b); acc[0][3] += dot8(x3a, x3b, w0a, w0b);
            acc[1][0] += dot8(x0a, x0b, w1a, w1b); acc[1][1] += dot8(x1a, x1b, w1a, w1b);
            acc[1][2] += dot8(x2a, x2b, w1a, w1b); acc[1][3] += dot8(x3a, x3b, w1a, w1b);
            acc[2][0] += dot8(x0a, x0b, w2a, w2b); acc[2][1] += dot8(x1a, x1b, w2a, w2b);
            acc[2][2] += dot8(x2a, x2b, w2a, w2b); acc[2][3] += dot8(x3a, x3b, w2a, w2b);
        }
        #pragma unroll
        for (int o = 0; o < 3; o++) {
            float bias = qkvb[oc0 + o];
            #pragma unroll
            for (int j = 0; j < 4; j++)
                s_qkv[n0 + j][oc0 + o] = acc[o][j] + bias;
        }
    }
    __syncthreads();

    for (int idx = tid; idx < 1536; idx += 256) {
        int head = idx >> 8, r = (idx >> 4) & 15, col = idx & 15;
        float s = 0.f;
        for (int d = 0; d < 32; d++)
            s += s_qkv[r][head * 32 + d] * s_qkv[col][CC + head * 32 + d];
        s_attn[head * 16 + r][col] = s * 4.0f;
    }
    __syncthreads();

    if (tid < 96) {
        float mx = -1e30f;
        for (int i = 0; i < 16; i++) mx = fmaxf(mx, s_attn[tid][i]);
        float ss = 0.f;
        for (int i = 0; i < 16; i++) { float e = __expf(s_attn[tid][i] - mx); ss += e; s_attn[tid][i] = e; }
        float inv = 1.f / ss;
        for (int i = 0; i < 16; i++) s_attn[tid][i] *= inv;
    }
    __syncthreads();

    for (int idx = tid; idx < 16 * CC; idx += 256) {
        int n = idx / CC, c = idx - n * CC;
        int head = c >> 5;
        float s = 0.f;
        for (int m = 0; m < 16; m++) s += s_attn[head * 16 + n][m] * s_qkv[m][2 * CC + c];
        s_h[n][c] = s;
    }
    __syncthreads();

    {
        const int og  = tid >> 2;
        const int oc0 = og * 3;
        const float* w0 = projw + (size_t)(oc0 + 0) * CC;
        const float* w1 = projw + (size_t)(oc0 + 1) * CC;
        const float* w2 = projw + (size_t)(oc0 + 2) * CC;
        float acc[3][4];
        #pragma unroll
        for (int o = 0; o < 3; o++)
            #pragma unroll
            for (int j = 0; j < 4; j++) acc[o][j] = 0.f;

        for (int k8 = 0; k8 < CC / 8; k8++) {
            const int kb = k8 * 8;
            float4 w0a = *(const float4*)(w0 + kb), w0b = *(const float4*)(w0 + kb + 4);
            float4 w1a = *(const float4*)(w1 + kb), w1b = *(const float4*)(w1 + kb + 4);
            float4 w2a = *(const float4*)(w2 + kb), w2b = *(const float4*)(w2 + kb + 4);
            float4 h0a = *(const float4*)(&s_h[n0 + 0][kb]), h0b = *(const float4*)(&s_h[n0 + 0][kb + 4]);
            float4 h1a = *(const float4*)(&s_h[n0 + 1][kb]), h1b = *(const float4*)(&s_h[n0 + 1][kb + 4]);
            float4 h2a = *(const float4*)(&s_h[n0 + 2][kb]), h2b = *(const float4*)(&s_h[n0 + 2][kb + 4]);
            float4 h3a = *(const float4*)(&s_h[n0 + 3][kb]), h3b = *(const float4*)(&s_h[n0 + 3][kb + 4]);
            acc[0][0] += dot8(h0a, h0b, w0a, w0b); acc[0][1] += dot8(h1a, h1b, w0a, w0b);
            acc[0][2] += dot8(h2a, h2b, w0a, w0b); acc[0][3] += dot8(h3a, h3b, w0a, w0b);
            acc[1][0] += dot8(h0a, h0b, w1a, w1b); acc[1][1] += dot8(h1a, h1b, w1a, w1b);
            acc[1][2] += dot8(h2a, h2b, w1a, w1b); acc[1][3] += dot8(h3a, h3b, w1a, w1b);
            acc[2][0] += dot8(h0a, h0b, w2a, w2b); acc[2][1] += dot8(h1a, h1b, w2a, w2b);
            acc[2][2] += dot8(h2a, h2b, w2a, w2b); acc[2][3] += dot8(h3a, h3b, w2a, w2b);
        }
        float* xo = xt2 + (size_t)b * LL * CC;
        #pragma unroll
        for (int o = 0; o < 3; o++) {
            const int c = oc0 + o;
            float bias = projb[c];
            #pragma unroll
            for (int j = 0; j < 4; j++) {
                const size_t row = (size_t)s_tok[n0 + j] * CC;
                float res = xbT[row + c];
                xo[row + c] = acc[o][j] + bias + res;
            }
        }
    }
}

// ---- kB3: LN2 + MLP via bf16 MFMA + residual; reads xt2 (B,L,C), writes (B,C,L) ----
// A-frag (M=token): lane&15 = row, 8 contiguous k at (lane>>4)*8.  B-frag (N=out ch):
// lane&15 = n, source row-major [N][K] -> 16-B contiguous load.  D: col=lane&15,
// row=(lane>>4)*4+reg (m89-verified).
__global__ __launch_bounds__(256) void kB3(
    const float* __restrict__ xt2,
    const float* __restrict__ n2g, const float* __restrict__ n2b,
    const unsigned short* __restrict__ fc1wb, const float* __restrict__ fc1b,
    const unsigned short* __restrict__ fc2wb, const float* __restrict__ fc2b,
    float* __restrict__ out)
{
    // s_x f32[16][196] (12544 B) lives in the head of the s_a region (24832 B):
    // s_x is dead after LN writes s_xb; single __syncthreads separates the lifetimes.
    __shared__ char smem[16 * SABP * 2];
    __shared__ unsigned short s_xb[16][SXBP];
    float (*s_x)[SXP] = (float(*)[SXP])smem;
    unsigned short (*s_a)[SABP] = (unsigned short(*)[SABP])smem;

    const int tid = threadIdx.x;
    const int t0 = blockIdx.x * 16;
    const int b  = t0 >> 16;
    const int l0 = t0 & (LL - 1);
    const float* xrow = xt2 + ((size_t)b * LL + l0) * CC;

    #pragma unroll
    for (int p = 0; p < 3; p++) {
        int idx = tid + p * 256;
        int n = idx / 48, c4 = idx % 48;
        float4 v = *(const float4*)(xrow + (size_t)n * CC + c4 * 4);
        *(float4*)&s_x[n][c4 * 4] = v;
    }
    __syncthreads();

    // LN2 -> bf16 into s_xb (s_x becomes dead)
    {
        const int t = tid >> 4, s = tid & 15;
        float vals[12];
        float sum = 0.f, sq = 0.f;
        #pragma unroll
        for (int k = 0; k < 12; k++) {
            float v = s_x[t][s + 16 * k];
            vals[k] = v; sum += v; sq += v * v;
        }
        #pragma unroll
        for (int m = 1; m < 16; m <<= 1) {
            sum += __shfl_xor(sum, m);
            sq  += __shfl_xor(sq, m);
        }
        float mu = sum * (1.f / CC);
        float rs = rsqrtf(sq * (1.f / CC) - mu * mu + 1e-5f);
        #pragma unroll
        for (int k = 0; k < 12; k++) {
            int c = s + 16 * k;
            s_xb[t][c] = f2us((vals[k] - mu) * rs * n2g[c] + n2b[c]);
        }
    }
    __syncthreads();

    const int lane = tid & 63;
    const int w    = tid >> 6;       // wave id 0..3
    const int m16  = lane & 15;      // A row / B-N / D col
    const int g    = lane >> 4;      // k-group 0..3

    // ---- fc1: wave w owns ntiles w*12 .. w*12+11 (N=768 = 48 tiles of 16) ----
    bf16x8 afrag[6];
    #pragma unroll
    for (int k = 0; k < 6; k++)
        afrag[k] = *(const bf16x8*)&s_xb[m16][k * 32 + g * 8];

    #pragma unroll
    for (int pp = 0; pp < 6; pp++) {
        const int nt0 = w * 12 + pp * 2;
        f32x4 acc0 = {0.f, 0.f, 0.f, 0.f};
        f32x4 acc1 = {0.f, 0.f, 0.f, 0.f};
        const unsigned short* wr0 = fc1wb + (size_t)(nt0 * 16 + m16) * CC + g * 8;
        const unsigned short* wr1 = wr0 + 16 * CC;
        #pragma unroll
        for (int k = 0; k < 6; k++) {
            bf16x8 b0 = *(const bf16x8*)(wr0 + k * 32);
            bf16x8 b1 = *(const bf16x8*)(wr1 + k * 32);
            acc0 = __builtin_amdgcn_mfma_f32_16x16x32_bf16(afrag[k], b0, acc0, 0, 0, 0);
            acc1 = __builtin_amdgcn_mfma_f32_16x16x32_bf16(afrag[k], b1, acc1, 0, 0, 0);
        }
        float bias0 = fc1b[nt0 * 16 + m16];
        float bias1 = fc1b[(nt0 + 1) * 16 + m16];
        #pragma unroll
        for (int t = 0; t < 4; t++) {
            s_a[g * 4 + t][nt0 * 16 + m16]       = f2us(gelu_exact(acc0[t] + bias0));
            s_a[g * 4 + t][(nt0 + 1) * 16 + m16] = f2us(gelu_exact(acc1[t] + bias1));
        }
    }
    __syncthreads();

    // ---- fc2: wave w owns ntiles w*3 .. w*3+2 (N=192 = 12 tiles); K=768 = 24 steps ----
    {
        const int nt0 = w * 3;
        f32x4 acc0 = {0.f, 0.f, 0.f, 0.f};
        f32x4 acc1 = {0.f, 0.f, 0.f, 0.f};
        f32x4 acc2 = {0.f, 0.f, 0.f, 0.f};
        const unsigned short* wr0 = fc2wb + (size_t)(nt0 * 16 + m16) * HID + g * 8;
        const unsigned short* wr1 = wr0 + 16 * HID;
        const unsigned short* wr2 = wr1 + 16 * HID;
        #pragma unroll 8
        for (int k = 0; k < 24; k++) {
            bf16x8 a  = *(const bf16x8*)&s_a[m16][k * 32 + g * 8];
            bf16x8 b0 = *(const bf16x8*)(wr0 + k * 32);
            bf16x8 b1 = *(const bf16x8*)(wr1 + k * 32);
            bf16x8 b2 = *(const bf16x8*)(wr2 + k * 32);
            acc0 = __builtin_amdgcn_mfma_f32_16x16x32_bf16(a, b0, acc0, 0, 0, 0);
            acc1 = __builtin_amdgcn_mfma_f32_16x16x32_bf16(a, b1, acc1, 0, 0, 0);
            acc2 = __builtin_amdgcn_mfma_f32_16x16x32_bf16(a, b2, acc2, 0, 0, 0);
        }
        float* outb = out + (size_t)b * CC * LL + l0;
        const int n0 = g * 4;
        #pragma unroll
        for (int i = 0; i < 3; i++) {
            const int c = (nt0 + i) * 16 + m16;
            const float bias = fc2b[c];
            const f32x4 av = (i == 0) ? acc0 : (i == 1) ? acc1 : acc2;
            float4 ov;
            ov.x = av[0] + bias + xrow[(size_t)(n0 + 0) * CC + c];
            ov.y = av[1] + bias + xrow[(size_t)(n0 + 1) * CC + c];
            ov.z = av[2] + bias + xrow[(size_t)(n0 + 2) * CC + c];
            ov.w = av[3] + bias + xrow[(size_t)(n0 + 3) * CC + c];
            *(float4*)(outb + (size_t)c * LL + n0) = ov;
        }
    }
}

// ---- kB2 (round-3 mid-tier fallback): LN2 + MLP f32, reads (B,L,C), writes (B,C,L) ----
__global__ __launch_bounds__(256, 2) void kB2(
    const float* __restrict__ xt2,
    const float* __restrict__ n2g, const float* __restrict__ n2b,
    const float* __restrict__ fc1w, const float* __restrict__ fc1b,
    const float* __restrict__ fc2w, const float* __restrict__ fc2b,
    float* __restrict__ out)
{
    __shared__ float s_x[16][SXP];
    __shared__ float s_a[16][SAP];

    const int tid = threadIdx.x;
    const int t0 = blockIdx.x * 16;
    const int b  = t0 >> 16;
    const int l0 = t0 & (LL - 1);
    const float* xrow = xt2 + ((size_t)b * LL + l0) * CC;

    #pragma unroll
    for (int p = 0; p < 3; p++) {
        int idx = tid + p * 256;
        int n = idx / 48, c4 = idx % 48;
        float4 v = *(const float4*)(xrow + (size_t)n * CC + c4 * 4);
        *(float4*)&s_x[n][c4 * 4] = v;
    }
    __syncthreads();

    {
        const int t = tid >> 4, s = tid & 15;
        float sum = 0.f, sq = 0.f;
        #pragma unroll
        for (int k = 0; k < 12; k++) {
            float v = s_x[t][s + 16 * k];
            sum += v; sq += v * v;
        }
        #pragma unroll
        for (int m = 1; m < 16; m <<= 1) {
            sum += __shfl_xor(sum, m);
            sq  += __shfl_xor(sq, m);
        }
        float mu = sum * (1.f / CC);
        float rs = rsqrtf(sq * (1.f / CC) - mu * mu + 1e-5f);
        #pragma unroll
        for (int k = 0; k < 12; k++) {
            int c = s + 16 * k;
            s_x[t][c] = (s_x[t][c] - mu) * rs * n2g[c] + n2b[c];
        }
    }
    __syncthreads();

    const int tg = tid & 3;
    const int n0 = tg * 4;
    for (int it = 0; it < 3; it++) {
        const int og  = (it * 256 + tid) >> 2;
        const int oc0 = og * 4;
        const float* w0 = fc1w + (size_t)(oc0 + 0) * CC;
        const float* w1 = fc1w + (size_t)(oc0 + 1) * CC;
        const float* w2 = fc1w + (size_t)(oc0 + 2) * CC;
        const float* w3 = fc1w + (size_t)(oc0 + 3) * CC;
        float acc[4][4];
        #pragma unroll
        for (int o = 0; o < 4; o++)
            #pragma unroll
            for (int j = 0; j < 4; j++) acc[o][j] = 0.f;

        for (int k8 = 0; k8 < CC / 8; k8++) {
            const int kb = k8 * 8;
            float4 w0a = *(const float4*)(w0 + kb), w0b = *(const float4*)(w0 + kb + 4);
            float4 w1a = *(const float4*)(w1 + kb), w1b = *(const float4*)(w1 + kb + 4);
            float4 w2a = *(const float4*)(w2 + kb), w2b = *(const float4*)(w2 + kb + 4);
            float4 w3a = *(const float4*)(w3 + kb), w3b = *(const float4*)(w3 + kb + 4);
            float4 x0a = *(const float4*)(&s_x[n0 + 0][kb]), x0b = *(const float4*)(&s_x[n0 + 0][kb + 4]);
            float4 x1a = *(const float4*)(&s_x[n0 + 1][kb]), x1b = *(const float4*)(&s_x[n0 + 1][kb + 4]);
            float4 x2a = *(const float4*)(&s_x[n0 + 2][kb]), x2b = *(const float4*)(&s_x[n0 + 2][kb + 4]);
            float4 x3a = *(const float4*)(&s_x[n0 + 3][kb]), x3b = *(const float4*)(&s_x[n0 + 3][kb + 4]);
            acc[0][0] += dot8(x0a, x0b, w0a, w0b); acc[0][1] += dot8(x1a, x1b, w0a, w0b);
            acc[0][2] += dot8(x2a, x2b, w0a, w0b); acc[0][3] += dot8(x3a, x3b, w0a, w0b);
            acc[1][0] += dot8(x0a, x0b, w1a, w1b); acc[1][1] += dot8(x1a, x1b, w1a, w1b);
            acc[1][2] += dot8(x2a, x2b, w1a, w1b); acc[1][3] += dot8(x3a, x3b, w1a, w1b);
            acc[2][0] += dot8(x0a, x0b, w2a, w2b); acc[2][1] += dot8(x1a, x1b, w2a, w2b);
            acc[2][2] += dot8(x2a, x2b, w2a, w2b); acc[2][3] += dot8(x3a, x3b, w2a, w2b);
            acc[3][0] += dot8(x0a, x0b, w3a, w3b); acc[3][1] += dot8(x1a, x1b, w3a, w3b);
            acc[3][2] += dot8(x2a, x2b, w3a, w3b); acc[3][3] += dot8(x3a, x3b, w3a, w3b);
        }
        #pragma unroll
        for (int o = 0; o < 4; o++) {
            float bias = fc1b[oc0 + o];
            #pragma unroll
            for (int j = 0; j < 4; j++)
                s_a[n0 + j][oc0 + o] = gelu_exact(acc[o][j] + bias);
        }
    }
    __syncthreads();

    {
        const int og  = tid >> 2;
        const int oc0 = og * 3;
        const float* w0 = fc2w + (size_t)(oc0 + 0) * HID;
        const float* w1 = fc2w + (size_t)(oc0 + 1) * HID;
        const float* w2 = fc2w + (size_t)(oc0 + 2) * HID;
        float acc[3][4];
        #pragma unroll
        for (int o = 0; o < 3; o++)
            #pragma unroll
            for (int j = 0; j < 4; j++) acc[o][j] = 0.f;

        for (int k8 = 0; k8 < HID / 8; k8++) {
            const int kb = k8 * 8;
            float4 w0a = *(const float4*)(w0 + kb), w0b = *(const float4*)(w0 + kb + 4);
            float4 w1a = *(const float4*)(w1 + kb), w1b = *(const float4*)(w1 + kb + 4);
            float4 w2a = *(const float4*)(w2 + kb), w2b = *(const float4*)(w2 + kb + 4);
            float4 a0a = *(const float4*)(&s_a[n0 + 0][kb]), a0b = *(const float4*)(&s_a[n0 + 0][kb + 4]);
            float4 a1a = *(const float4*)(&s_a[n0 + 1][kb]), a1b = *(const float4*)(&s_a[n0 + 1][kb + 4]);
            float4 a2a = *(const float4*)(&s_a[n0 + 2][kb]), a2b = *(const float4*)(&s_a[n0 + 2][kb + 4]);
            float4 a3a = *(const float4*)(&s_a[n0 + 3][kb]), a3b = *(const float4*)(&s_a[n0 + 3][kb + 4]);
            acc[0][0] += dot8(a0a, a0b, w0a, w0b); acc[0][1] += dot8(a1a, a1b, w0a, w0b);
            acc[0][2] += dot8(a2a, a2b, w0a, w0b); acc[0][3] += dot8(a3a, a3b, w0a, w0b);
            acc[1][0] += dot8(a0a, a0b, w1a, w1b); acc[1][1] += dot8(a1a, a1b, w1a, w1b);
            acc[1][2] += dot8(a2a, a2b, w1a, w1b); acc[1][3] += dot8(a3a, a3b, w1a, w1b);
            acc[2][0] += dot8(a0a, a0b, w2a, w2b); acc[2][1] += dot8(a1a, a1b, w2a, w2b);
            acc[2][2] += dot8(a2a, a2b, w2a, w2b); acc[2][3] += dot8(a3a, a3b, w2a, w2b);
        }
        #pragma unroll
        for (int o = 0; o < 3; o++) {
            const int c = oc0 + o;
            float bias = fc2b[c];
            float4 outv;
            float r0 = xrow[(size_t)(n0 + 0) * CC + c];
            float r1 = xrow[(size_t)(n0 + 1) * CC + c];
            float r2 = xrow[(size_t)(n0 + 2) * CC + c];
            float r3 = xrow[(size_t)(n0 + 3) * CC + c];
            outv.x = acc[o][0] + bias + r0;
            outv.y = acc[o][1] + bias + r1;
            outv.z = acc[o][2] + bias + r2;
            outv.w = acc[o][3] + bias + r3;
            *(float4*)(out + ((size_t)b * CC + c) * LL + l0 + n0) = outv;
        }
    }
}

// =================== NO-WORKSPACE FALLBACK (round-2 kernels) ===================

__global__ __launch_bounds__(256) void kA(
    const float* __restrict__ x, const int* __restrict__ perm,
    const float* __restrict__ n1g, const float* __restrict__ n1b,
    const float* __restrict__ qkvw, const float* __restrict__ qkvb,
    const float* __restrict__ projw, const float* __restrict__ projb,
    float* __restrict__ xt2)
{
    __shared__ float s_h[16][CC];
    __shared__ float s_qkv[16][3*CC];
    __shared__ float s_attn[96][16];
    __shared__ unsigned short s_stash[16][CC];
    __shared__ float s_mu[16], s_rs[16];
    __shared__ int s_tok[16];

    const int tid = threadIdx.x;
    const int wid = blockIdx.x;
    const int b  = wid >> 12;
    const int hb = (wid >> 6) & 63;
    const int wb = wid & 63;

    if (tid < 16) {
        int si = tid >> 2, sj = tid & 3;
        s_tok[tid] = perm[(hb * 4 + si) * WWW + wb * 4 + sj];
    }
    __syncthreads();

    for (int idx = tid; idx < 16 * CC; idx += 256) {
        int n = idx / CC, c = idx - n * CC;
        float v = x[((size_t)b * CC + c) * LL + s_tok[n]];
        s_h[n][c] = v;
        s_stash[n][c] = f2us(v);
    }
    __syncthreads();

    if (tid < 16) {
        float s = 0.f, q = 0.f;
        for (int c = 0; c < CC; c++) { float v = s_h[tid][c]; s += v; q += v * v; }
        float mu = s * (1.f / CC);
        float var = q * (1.f / CC) - mu * mu;
        s_mu[tid] = mu;
        s_rs[tid] = rsqrtf(var + 1e-5f);
    }
    __syncthreads();

    for (int idx = tid; idx < 16 * CC; idx += 256) {
        int n = idx / CC, c = idx - n * CC;
        s_h[n][c] = (s_h[n][c] - s_mu[n]) * s_rs[n] * n1g[c] + n1b[c];
    }
    __syncthreads();

    for (int oc = tid; oc < 3 * CC; oc += 256) {
        float acc[16];
        for (int i = 0; i < 16; i++) acc[i] = 0.f;
        const float4* wr = (const float4*)(qkvw + (size_t)oc * CC);
        for (int k8 = 0; k8 < CC / 8; ++k8) {
            float4 wa = wr[k8 * 2], wb2 = wr[k8 * 2 + 1];
            for (int n = 0; n < 16; n++) {
                const float4* hp = (const float4*)(&s_h[n][k8 * 8]);
                acc[n] += dot8(hp[0], hp[1], wa, wb2);
            }
        }
        float bias = qkvb[oc];
        for (int n = 0; n < 16; n++) s_qkv[n][oc] = acc[n] + bias;
    }
    __syncthreads();

    for (int idx = tid; idx < 1536; idx += 256) {
        int head = idx >> 8, r = (idx >> 4) & 15, col = idx & 15;
        float s = 0.f;
        for (int d = 0; d < 32; d++)
            s += s_qkv[r][head * 32 + d] * s_qkv[col][CC + head * 32 + d];
        s_attn[head * 16 + r][col] = s * 4.0f;
    }
    __syncthreads();

    if (tid < 96) {
        float mx = -1e30f;
        for (int i = 0; i < 16; i++) mx = fmaxf(mx, s_attn[tid][i]);
        float ss = 0.f;
        for (int i = 0; i < 16; i++) { float e = __expf(s_attn[tid][i] - mx); ss += e; s_attn[tid][i] = e; }
        float inv = 1.f / ss;
        for (int i = 0; i < 16; i++) s_attn[tid][i] *= inv;
    }
    __syncthreads();

    for (int idx = tid; idx < 16 * CC; idx += 256) {
        int n = idx / CC, c = idx - n * CC;
        int head = c >> 5;
        float s = 0.f;
        for (int m = 0; m < 16; m++) s += s_attn[head * 16 + n][m] * s_qkv[m][2 * CC + c];
        s_h[n][c] = s;
    }
    __syncthreads();

    if (tid < CC) {
        const int c = tid;
        float acc[16];
        for (int i = 0; i < 16; i++) acc[i] = 0.f;
        const float4* wr = (const float4*)(projw + (size_t)c * CC);
        for (int k8 = 0; k8 < CC / 8; ++k8) {
            float4 wa = wr[k8 * 2], wb2 = wr[k8 * 2 + 1];
            for (int n = 0; n < 16; n++) {
                const float4* hp = (const float4*)(&s_h[n][k8 * 8]);
                acc[n] += dot8(hp[0], hp[1], wa, wb2);
            }
        }
        float bias = projb[c];
        for (int n = 0; n < 16; n++) {
            float res = us2f(s_stash[n][c]);
            xt2[((size_t)b * CC + c) * LL + s_tok[n]] = acc[n] + bias + res;
        }
    }
}

__global__ __launch_bounds__(256, 2) void kB(
    float* __restrict__ xt2,
    const float* __restrict__ n2g, const float* __restrict__ n2b,
    const float* __restrict__ fc1w, const float* __restrict__ fc1b,
    const float* __restrict__ fc2w, const float* __restrict__ fc2b)
{
    __shared__ float s_x[16][SXP];
    __shared__ float s_a[16][SAP];

    const int tid = threadIdx.x;
    const int t0 = blockIdx.x * 16;
    const int b  = t0 >> 16;
    const int l0 = t0 & (LL - 1);
    float* xbase = xt2 + (size_t)b * CC * LL + l0;

    for (int idx = tid; idx < 4 * CC; idx += 256) {
        int c = idx >> 2, n4 = idx & 3;
        float4 v = *(const float4*)(xbase + (size_t)c * LL + n4 * 4);
        s_x[n4 * 4 + 0][c] = v.x;
        s_x[n4 * 4 + 1][c] = v.y;
        s_x[n4 * 4 + 2][c] = v.z;
        s_x[n4 * 4 + 3][c] = v.w;
    }
    __syncthreads();

    {
        const int t = tid >> 4, s = tid & 15;
        float sum = 0.f, sq = 0.f;
        #pragma unroll
        for (int k = 0; k < 12; k++) {
            float v = s_x[t][s + 16 * k];
            sum += v; sq += v * v;
        }
        #pragma unroll
        for (int m = 1; m < 16; m <<= 1) {
            sum += __shfl_xor(sum, m);
            sq  += __shfl_xor(sq, m);
        }
        float mu = sum * (1.f / CC);
        float rs = rsqrtf(sq * (1.f / CC) - mu * mu + 1e-5f);
        #pragma unroll
        for (int k = 0; k < 12; k++) {
            int c = s + 16 * k;
            s_x[t][c] = (s_x[t][c] - mu) * rs * n2g[c] + n2b[c];
        }
    }
    __syncthreads();

    const int tg = tid & 3;
    const int n0 = tg * 4;
    for (int it = 0; it < 3; it++) {
        const int og  = (it * 256 + tid) >> 2;
        const int oc0 = og * 4;
        const float* w0 = fc1w + (size_t)(oc0 + 0) * CC;
        const float* w1 = fc1w + (size_t)(oc0 + 1) * CC;
        const float* w2 = fc1w + (size_t)(oc0 + 2) * CC;
        const float* w3 = fc1w + (size_t)(oc0 + 3) * CC;
        float acc[4][4];
        #pragma unroll
        for (int o = 0; o < 4; o++)
            #pragma unroll
            for (int j = 0; j < 4; j++) acc[o][j] = 0.f;

        for (int k8 = 0; k8 < CC / 8; k8++) {
            const int kb = k8 * 8;
            float4 w0a = *(const float4*)(w0 + kb), w0b = *(const float4*)(w0 + kb + 4);
            float4 w1a = *(const float4*)(w1 + kb), w1b = *(const float4*)(w1 + kb + 4);
            float4 w2a = *(const float4*)(w2 + kb), w2b = *(const float4*)(w2 + kb + 4);
            float4 w3a = *(const float4*)(w3 + kb), w3b = *(const float4*)(w3 + kb + 4);
            float4 x0a = *(const float4*)(&s_x[n0 + 0][kb]), x0b = *(const float4*)(&s_x[n0 + 0][kb + 4]);
            float4 x1a = *(const float4*)(&s_x[n0 + 1][kb]), x1b = *(const float4*)(&s_x[n0 + 1][kb + 4]);
            float4 x2a = *(const float4*)(&s_x[n0 + 2][kb]), x2b = *(const float4*)(&s_x[n0 + 2][kb + 4]);
            float4 x3a = *(const float4*)(&s_x[n0 + 3][kb]), x3b = *(const float4*)(&s_x[n0 + 3][kb + 4]);
            acc[0][0] += dot8(x0a, x0b, w0a, w0b); acc[0][1] += dot8(x1a, x1b, w0a, w0b);
            acc[0][2] += dot8(x2a, x2b, w0a, w0b); acc[0][3] += dot8(x3a, x3b, w0a, w0b);
            acc[1][0] += dot8(x0a, x0b, w1a, w1b); acc[1][1] += dot8(x1a, x1b, w1a, w1b);
            acc[1][2] += dot8(x2a, x2b, w1a, w1b); acc[1][3] += dot8(x3a, x3b, w1a, w1b);
            acc[2][0] += dot8(x0a, x0b, w2a, w2b); acc[2][1] += dot8(x1a, x1b, w2a, w2b);
            acc[2][2] += dot8(x2a, x2b, w2a, w2b); acc[2][3] += dot8(x3a, x3b, w2a, w2b);
            acc[3][0] += dot8(x0a, x0b, w3a, w3b); acc[3][1] += dot8(x1a, x1b, w3a, w3b);
            acc[3][2] += dot8(x2a, x2b, w3a, w3b); acc[3][3] += dot8(x3a, x3b, w3a, w3b);
        }
        #pragma unroll
        for (int o = 0; o < 4; o++) {
            float bias = fc1b[oc0 + o];
            #pragma unroll
            for (int j = 0; j < 4; j++)
                s_a[n0 + j][oc0 + o] = gelu_exact(acc[o][j] + bias);
        }
    }
    __syncthreads();

    {
        const int og  = tid >> 2;
        const int oc0 = og * 3;
        const float* w0 = fc2w + (size_t)(oc0 + 0) * HID;
        const float* w1 = fc2w + (size_t)(oc0 + 1) * HID;
        const float* w2 = fc2w + (size_t)(oc0 + 2) * HID;
        float acc[3][4];
        #pragma unroll
        for (int o = 0; o < 3; o++)
            #pragma unroll
            for (int j = 0; j < 4; j++) acc[o][j] = 0.f;

        for (int k8 = 0; k8 < HID / 8; k8++) {
            const int kb = k8 * 8;
            float4 w0a = *(const float4*)(w0 + kb), w0b = *(const float4*)(w0 + kb + 4);
            float4 w1a = *(const float4*)(w1 + kb), w1b = *(const float4*)(w1 + kb + 4);
            float4 w2a = *(const float4*)(w2 + kb), w2b = *(const float4*)(w2 + kb + 4);
            float4 a0a = *(const float4*)(&s_a[n0 + 0][kb]), a0b = *(const float4*)(&s_a[n0 + 0][kb + 4]);
            float4 a1a = *(const float4*)(&s_a[n0 + 1][kb]), a1b = *(const float4*)(&s_a[n0 + 1][kb + 4]);
            float4 a2a = *(const float4*)(&s_a[n0 + 2][kb]), a2b = *(const float4*)(&s_a[n0 + 2][kb + 4]);
            float4 a3a = *(const float4*)(&s_a[n0 + 3][kb]), a3b = *(const float4*)(&s_a[n0 + 3][kb + 4]);
            acc[0][0] += dot8(a0a, a0b, w0a, w0b); acc[0][1] += dot8(a1a, a1b, w0a, w0b);
            acc[0][2] += dot8(a2a, a2b, w0a, w0b); acc[0][3] += dot8(a3a, a3b, w0a, w0b);
            acc[1][0] += dot8(a0a, a0b, w1a, w1b); acc[1][1] += dot8(a1a, a1b, w1a, w1b);
            acc[1][2] += dot8(a2a, a2b, w1a, w1b); acc[1][3] += dot8(a3a, a3b, w1a, w1b);
            acc[2][0] += dot8(a0a, a0b, w2a, w2b); acc[2][1] += dot8(a1a, a1b, w2a, w2b);
            acc[2][2] += dot8(a2a, a2b, w2a, w2b); acc[2][3] += dot8(a3a, a3b, w2a, w2b);
        }
        #pragma unroll
        for (int o = 0; o < 3; o++) {
            const int c = oc0 + o;
            float bias = fc2b[c];
            float* p = xbase + (size_t)c * LL + n0;
            float4 r = *(const float4*)p;
            float4 outv;
            outv.x = acc[o][0] + bias + r.x;
            outv.y = acc[o][1] + bias + r.y;
            outv.z = acc[o][2] + bias + r.z;
            outv.w = acc[o][3] + bias + r.w;
            *(float4*)p = outv;
        }
    }
}

extern "C" void kernel_launch(void* const* d_in, const int* in_sizes, int n_in,
                              void* d_out, int out_size, void* d_ws, size_t ws_size,
                              hipStream_t stream) {
    const float* x     = (const float*)d_in[0];
    const int*   perm  = (const int*)d_in[1];
    const float* n1g   = (const float*)d_in[2];
    const float* n1b   = (const float*)d_in[3];
    const float* qkvw  = (const float*)d_in[4];
    const float* qkvb  = (const float*)d_in[5];
    const float* projw = (const float*)d_in[6];
    const float* projb = (const float*)d_in[7];
    const float* n2g   = (const float*)d_in[8];
    const float* n2b   = (const float*)d_in[9];
    const float* fc1w  = (const float*)d_in[10];
    const float* fc1b  = (const float*)d_in[11];
    const float* fc2w  = (const float*)d_in[12];
    const float* fc2b  = (const float*)d_in[13];

    const size_t NTOK    = (size_t)BB * LL * CC;            // 50,331,648 floats
    const size_t WS_MID  = 2 * NTOK * sizeof(float);        // xT + xt2 (B,L,C)
    const size_t WS_FULL = WS_MID + 2 * (size_t)HID * CC * sizeof(unsigned short); // + bf16 weights

    if (d_ws != nullptr && ws_size >= WS_FULL) {
        float* xT   = (float*)d_ws;
        float* xt2w = xT + NTOK;
        unsigned short* fc1wb = (unsigned short*)(xt2w + NTOK);
        unsigned short* fc2wb = fc1wb + (size_t)HID * CC;
        kW <<<(HID * CC + 255) / 256, 256, 0, stream>>>(fc1w, fc2w, fc1wb, fc2wb);
        kT <<<BB * (LL / TLL), 256, 0, stream>>>(x, xT);
        kA2<<<16384, 256, 0, stream>>>(xT, perm, n1g, n1b, qkvw, qkvb, projw, projb, xt2w);
        kB3<<<16384, 256, 0, stream>>>(xt2w, n2g, n2b, fc1wb, fc1b, fc2wb, fc2b, (float*)d_out);
    } else if (d_ws != nullptr && ws_size >= WS_MID) {
        float* xT   = (float*)d_ws;
        float* xt2w = xT + NTOK;
        kT <<<BB * (LL / TLL), 256, 0, stream>>>(x, xT);
        kA2<<<16384, 256, 0, stream>>>(xT, perm, n1g, n1b, qkvw, qkvb, projw, projb, xt2w);
        kB2<<<16384, 256, 0, stream>>>(xt2w, n2g, n2b, fc1w, fc1b, fc2w, fc2b, (float*)d_out);
    } else {
        float* out = (float*)d_out;
        kA<<<16384, 256, 0, stream>>>(x, perm, n1g, n1b, qkvw, qkvb, projw, projb, out);
        kB<<<16384, 256, 0, stream>>>(out, n2g, n2b, fc1w, fc1b, fc2w, fc2b);
    }
    (void)in_sizes; (void)n_in; (void)out_size;
}

// Round 5
// 2055.924 us; speedup vs baseline: 45.7421x; 1.5126x over previous
//
#include <hip/hip_runtime.h>
#include <hip/hip_bf16.h>

#define BB 4
#define CC 192
#define LL 65536
#define WWW 256
#define HID 768
#define SXP (CC + 4)    // 196 f32
#define SQP (3*CC + 4)  // 580 f32
#define SAP (HID + 4)   // 772 f32
#define SXBP 200        // bf16 row stride (400 B): (m+g)%8 uniform for b128 frag reads
#define SABP 776        // bf16 row stride (1552 B)

typedef short bf16x8 __attribute__((ext_vector_type(8)));
typedef float f32x4  __attribute__((ext_vector_type(4)));

__device__ __forceinline__ float us2f(unsigned short u) { return __uint_as_float(((unsigned int)u) << 16); }
__device__ __forceinline__ unsigned short f2us(float f) {
    unsigned int x = __float_as_uint(f);
    unsigned int r = (x + 0x7FFFu + ((x >> 16) & 1u)) >> 16;
    return (unsigned short)r;
}

__device__ __forceinline__ float gelu_exact(float x) {
    return 0.5f * x * (1.0f + erff(x * 0.70710678118654752440f));
}

__device__ __forceinline__ float dot8(const float4 a, const float4 b, const float4 wa, const float4 wb) {
    return a.x*wa.x + a.y*wa.y + a.z*wa.z + a.w*wa.w
         + b.x*wb.x + b.y*wb.y + b.z*wb.z + b.w*wb.w;
}

// =================== FAST PATH ===================

// ---- kW2: convert all four GEMM weights f32 -> bf16 ----
__global__ __launch_bounds__(256) void kW2(
    const float* __restrict__ fc1w, const float* __restrict__ fc2w,
    const float* __restrict__ qkvw, const float* __restrict__ projw,
    unsigned short* __restrict__ fc1wb, unsigned short* __restrict__ fc2wb,
    unsigned short* __restrict__ qkvwb, unsigned short* __restrict__ projwb)
{
    int i = blockIdx.x * 256 + threadIdx.x;
    if (i < HID * CC) { fc1wb[i] = f2us(fc1w[i]); fc2wb[i] = f2us(fc2w[i]); }
    if (i < 3 * CC * CC) qkvwb[i] = f2us(qkvw[i]);
    if (i < CC * CC)     projwb[i] = f2us(projw[i]);
}

// ---- kW: convert fc1w/fc2w only (round-4 tier) ----
__global__ __launch_bounds__(256) void kW(
    const float* __restrict__ fc1w, const float* __restrict__ fc2w,
    unsigned short* __restrict__ fc1wb, unsigned short* __restrict__ fc2wb)
{
    int i = blockIdx.x * 256 + threadIdx.x;
    if (i < HID * CC) {
        fc1wb[i] = f2us(fc1w[i]);
        fc2wb[i] = f2us(fc2w[i]);
    }
}

// ---- kT: transpose x (B,C,L) f32 -> xT (B,L,C) f32 ----
#define TLL 64
__global__ __launch_bounds__(256) void kT(const float* __restrict__ x, float* __restrict__ xT)
{
    __shared__ float s_t[TLL][SXP];
    const int tid = threadIdx.x;
    const int b  = blockIdx.x >> 10;
    const int l0 = (blockIdx.x & 1023) * TLL;

    #pragma unroll
    for (int p = 0; p < 12; p++) {
        int idx = tid + p * 256;
        int c = idx >> 4, l4 = idx & 15;
        float4 v = *(const float4*)(x + ((size_t)b * CC + c) * LL + l0 + l4 * 4);
        s_t[l4 * 4 + 0][c] = v.x;
        s_t[l4 * 4 + 1][c] = v.y;
        s_t[l4 * 4 + 2][c] = v.z;
        s_t[l4 * 4 + 3][c] = v.w;
    }
    __syncthreads();

    #pragma unroll
    for (int p = 0; p < 12; p++) {
        int idx = tid + p * 256;
        int l = idx / 48, c4 = idx % 48;
        float4 v = *(const float4*)(&s_t[l][c4 * 4]);
        *(float4*)(xT + ((size_t)b * LL + l0 + l) * CC + c4 * 4) = v;
    }
}

// ---- kA3: gather + LN1 + MFMA QKV + f32 attn + MFMA proj + exact residual ----
// Fragment recipe identical to kB3 (numerically verified in round 4).
__global__ __launch_bounds__(256) void kA3(
    const float* __restrict__ xT, const int* __restrict__ perm,
    const float* __restrict__ n1g, const float* __restrict__ n1b,
    const unsigned short* __restrict__ qkvwb, const float* __restrict__ qkvb,
    const unsigned short* __restrict__ projwb, const float* __restrict__ projb,
    float* __restrict__ xt2)
{
    // s_h f32[16][196] (raw->LN read) overlays head of s_qkv f32[16][580]:
    // s_h dead after LN writes s_hb; __syncthreads separates lifetimes.
    __shared__ __align__(16) float smemA[16 * SQP];
    float (*s_h)[SXP]   = (float(*)[SXP])smemA;
    float (*s_qkv)[SQP] = (float(*)[SQP])smemA;
    __shared__ __align__(16) unsigned short s_hb[16][SXBP];   // LN1 out, bf16 (QKV A)
    __shared__ __align__(16) unsigned short s_ob[16][SXBP];   // attn out, bf16 (proj A)
    __shared__ float s_attn[96][17];
    __shared__ int s_tok[16];

    const int tid = threadIdx.x;
    const int wid = blockIdx.x;
    const int b  = wid >> 12;
    const int hb = (wid >> 6) & 63;
    const int wb = wid & 63;

    if (tid < 16) {
        int si = tid >> 2, sj = tid & 3;
        s_tok[tid] = perm[(hb * 4 + si) * WWW + wb * 4 + sj];
    }
    __syncthreads();

    const float* xbT = xT + (size_t)b * LL * CC;

    // gather 16 token rows (768 B contiguous each)
    #pragma unroll
    for (int p = 0; p < 3; p++) {
        int idx = tid + p * 256;
        int n = idx / 48, c4 = idx % 48;
        float4 v = *(const float4*)(xbT + (size_t)s_tok[n] * CC + c4 * 4);
        *(float4*)&s_h[n][c4 * 4] = v;
    }
    __syncthreads();

    // LN1 -> bf16 s_hb (16 lanes/token, shuffle reduce)
    {
        const int t = tid >> 4, s = tid & 15;
        float vals[12];
        float sum = 0.f, sq = 0.f;
        #pragma unroll
        for (int k = 0; k < 12; k++) {
            float v = s_h[t][s + 16 * k];
            vals[k] = v; sum += v; sq += v * v;
        }
        #pragma unroll
        for (int m = 1; m < 16; m <<= 1) {
            sum += __shfl_xor(sum, m);
            sq  += __shfl_xor(sq, m);
        }
        float mu = sum * (1.f / CC);
        float rs = rsqrtf(sq * (1.f / CC) - mu * mu + 1e-5f);
        #pragma unroll
        for (int k = 0; k < 12; k++) {
            int c = s + 16 * k;
            s_hb[t][c] = f2us((vals[k] - mu) * rs * n1g[c] + n1b[c]);
        }
    }
    __syncthreads();   // s_h dead; s_qkv region free for MFMA output

    const int lane = tid & 63;
    const int w    = tid >> 6;       // wave 0..3
    const int m16  = lane & 15;      // A row / B-N / D col
    const int g    = lane >> 4;      // k-group 0..3

    // ---- QKV: 36 N-tiles (q 0..11 | k 12..23 | v 24..35); wave owns 9, triple-acc ----
    {
        bf16x8 afrag[6];
        #pragma unroll
        for (int k = 0; k < 6; k++)
            afrag[k] = *(const bf16x8*)&s_hb[m16][k * 32 + g * 8];

        #pragma unroll
        for (int ii = 0; ii < 3; ii++) {
            const int nt0 = w * 9 + ii * 3;
            f32x4 a0 = {0.f,0.f,0.f,0.f}, a1 = {0.f,0.f,0.f,0.f}, a2 = {0.f,0.f,0.f,0.f};
            const unsigned short* w0 = qkvwb + (size_t)((nt0 + 0) * 16 + m16) * CC + g * 8;
            const unsigned short* w1 = qkvwb + (size_t)((nt0 + 1) * 16 + m16) * CC + g * 8;
            const unsigned short* w2 = qkvwb + (size_t)((nt0 + 2) * 16 + m16) * CC + g * 8;
            #pragma unroll
            for (int k = 0; k < 6; k++) {
                a0 = __builtin_amdgcn_mfma_f32_16x16x32_bf16(afrag[k], *(const bf16x8*)(w0 + k * 32), a0, 0, 0, 0);
                a1 = __builtin_amdgcn_mfma_f32_16x16x32_bf16(afrag[k], *(const bf16x8*)(w1 + k * 32), a1, 0, 0, 0);
                a2 = __builtin_amdgcn_mfma_f32_16x16x32_bf16(afrag[k], *(const bf16x8*)(w2 + k * 32), a2, 0, 0, 0);
            }
            const int c0 = (nt0 + 0) * 16 + m16;
            const int c1 = (nt0 + 1) * 16 + m16;
            const int c2 = (nt0 + 2) * 16 + m16;
            const float b0 = qkvb[c0], b1 = qkvb[c1], b2 = qkvb[c2];
            #pragma unroll
            for (int t = 0; t < 4; t++) {
                s_qkv[g * 4 + t][c0] = a0[t] + b0;
                s_qkv[g * 4 + t][c1] = a1[t] + b1;
                s_qkv[g * 4 + t][c2] = a2[t] + b2;
            }
        }
    }
    __syncthreads();

    // ---- scores = SCALE * q @ k^T (f32 VALU; 4% of FLOP, keep exact-ish) ----
    for (int idx = tid; idx < 1536; idx += 256) {
        int head = idx >> 8, r = (idx >> 4) & 15, col = idx & 15;
        float s = 0.f;
        for (int d = 0; d < 32; d++)
            s += s_qkv[r][head * 32 + d] * s_qkv[col][CC + head * 32 + d];
        s_attn[head * 16 + r][col] = s * 4.0f;
    }
    __syncthreads();

    if (tid < 96) {
        float mx = -1e30f;
        for (int i = 0; i < 16; i++) mx = fmaxf(mx, s_attn[tid][i]);
        float ss = 0.f;
        for (int i = 0; i < 16; i++) { float e = __expf(s_attn[tid][i] - mx); ss += e; s_attn[tid][i] = e; }
        float inv = 1.f / ss;
        for (int i = 0; i < 16; i++) s_attn[tid][i] *= inv;
    }
    __syncthreads();

    // o = attn @ v -> bf16 s_ob (proj A operand)
    for (int idx = tid; idx < 16 * CC; idx += 256) {
        int n = idx / CC, c = idx - n * CC;
        int head = c >> 5;
        float s = 0.f;
        for (int m = 0; m < 16; m++) s += s_attn[head * 16 + n][m] * s_qkv[m][2 * CC + c];
        s_ob[n][c] = f2us(s);
    }
    __syncthreads();

    // ---- proj: 12 N-tiles, wave owns 3; + exact f32 residual; write xt2 (B,L,C) ----
    {
        bf16x8 pa[6];
        #pragma unroll
        for (int k = 0; k < 6; k++)
            pa[k] = *(const bf16x8*)&s_ob[m16][k * 32 + g * 8];

        const int nt0 = w * 3;
        f32x4 a0 = {0.f,0.f,0.f,0.f}, a1 = {0.f,0.f,0.f,0.f}, a2 = {0.f,0.f,0.f,0.f};
        const unsigned short* w0 = projwb + (size_t)((nt0 + 0) * 16 + m16) * CC + g * 8;
        const unsigned short* w1 = projwb + (size_t)((nt0 + 1) * 16 + m16) * CC + g * 8;
        const unsigned short* w2 = projwb + (size_t)((nt0 + 2) * 16 + m16) * CC + g * 8;
        #pragma unroll
        for (int k = 0; k < 6; k++) {
            a0 = __builtin_amdgcn_mfma_f32_16x16x32_bf16(pa[k], *(const bf16x8*)(w0 + k * 32), a0, 0, 0, 0);
            a1 = __builtin_amdgcn_mfma_f32_16x16x32_bf16(pa[k], *(const bf16x8*)(w1 + k * 32), a1, 0, 0, 0);
            a2 = __builtin_amdgcn_mfma_f32_16x16x32_bf16(pa[k], *(const bf16x8*)(w2 + k * 32), a2, 0, 0, 0);
        }
        float* xo = xt2 + (size_t)b * LL * CC;
        #pragma unroll
        for (int i = 0; i < 3; i++) {
            const int c = (nt0 + i) * 16 + m16;
            const float bias = projb[c];
            const f32x4 av = (i == 0) ? a0 : (i == 1) ? a1 : a2;
            #pragma unroll
            for (int t = 0; t < 4; t++) {
                const size_t row = (size_t)s_tok[g * 4 + t] * CC;
                xo[row + c] = av[t] + bias + xbT[row + c];   // exact f32 shortcut
            }
        }
    }
}

// ---- kA2 (round-3/4 tier): f32 VALU attention block ----
__global__ __launch_bounds__(256) void kA2(
    const float* __restrict__ xT, const int* __restrict__ perm,
    const float* __restrict__ n1g, const float* __restrict__ n1b,
    const float* __restrict__ qkvw, const float* __restrict__ qkvb,
    const float* __restrict__ projw, const float* __restrict__ projb,
    float* __restrict__ xt2)
{
    __shared__ float s_h[16][SXP];
    __shared__ float s_qkv[16][SQP];
    __shared__ float s_attn[96][17];
    __shared__ int s_tok[16];

    const int tid = threadIdx.x;
    const int wid = blockIdx.x;
    const int b  = wid >> 12;
    const int hb = (wid >> 6) & 63;
    const int wb = wid & 63;

    if (tid < 16) {
        int si = tid >> 2, sj = tid & 3;
        s_tok[tid] = perm[(hb * 4 + si) * WWW + wb * 4 + sj];
    }
    __syncthreads();

    const float* xbT = xT + (size_t)b * LL * CC;

    #pragma unroll
    for (int p = 0; p < 3; p++) {
        int idx = tid + p * 256;
        int n = idx / 48, c4 = idx % 48;
        float4 v = *(const float4*)(xbT + (size_t)s_tok[n] * CC + c4 * 4);
        *(float4*)&s_h[n][c4 * 4] = v;
    }
    __syncthreads();

    {
        const int t = tid >> 4, s = tid & 15;
        float sum = 0.f, sq = 0.f;
        #pragma unroll
        for (int k = 0; k < 12; k++) {
            float v = s_h[t][s + 16 * k];
            sum += v; sq += v * v;
        }
        #pragma unroll
        for (int m = 1; m < 16; m <<= 1) {
            sum += __shfl_xor(sum, m);
            sq  += __shfl_xor(sq, m);
        }
        float mu = sum * (1.f / CC);
        float rs = rsqrtf(sq * (1.f / CC) - mu * mu + 1e-5f);
        #pragma unroll
        for (int k = 0; k < 12; k++) {
            int c = s + 16 * k;
            s_h[t][c] = (s_h[t][c] - mu) * rs * n1g[c] + n1b[c];
        }
    }
    __syncthreads();

    const int tg = tid & 3;
    const int n0 = tg * 4;
    for (int it = 0; it < 3; it++) {
        const int og  = (it * 256 + tid) >> 2;
        const int oc0 = og * 3;
        const float* w0 = qkvw + (size_t)(oc0 + 0) * CC;
        const float* w1 = qkvw + (size_t)(oc0 + 1) * CC;
        const float* w2 = qkvw + (size_t)(oc0 + 2) * CC;
        float acc[3][4];
        #pragma unroll
        for (int o = 0; o < 3; o++)
            #pragma unroll
            for (int j = 0; j < 4; j++) acc[o][j] = 0.f;

        for (int k8 = 0; k8 < CC / 8; k8++) {
            const int kb = k8 * 8;
            float4 w0a = *(const float4*)(w0 + kb), w0b = *(const float4*)(w0 + kb + 4);
            float4 w1a = *(const float4*)(w1 + kb), w1b = *(const float4*)(w1 + kb + 4);
            float4 w2a = *(const float4*)(w2 + kb), w2b = *(const float4*)(w2 + kb + 4);
            float4 x0a = *(const float4*)(&s_h[n0 + 0][kb]), x0b = *(const float4*)(&s_h[n0 + 0][kb + 4]);
            float4 x1a = *(const float4*)(&s_h[n0 + 1][kb]), x1b = *(const float4*)(&s_h[n0 + 1][kb + 4]);
            float4 x2a = *(const float4*)(&s_h[n0 + 2][kb]), x2b = *(const float4*)(&s_h[n0 + 2][kb + 4]);
            float4 x3a = *(const float4*)(&s_h[n0 + 3][kb]), x3b = *(const float4*)(&s_h[n0 + 3][kb + 4]);
            acc[0][0] += dot8(x0a, x0b, w0a, w0b); acc[0][1] += dot8(x1a, x1b, w0a, w0b);
            acc[0][2] += dot8(x2a, x2b, w0a, w0b); acc[0][3] += dot8(x3a, x3b, w0a, w0b);
            acc[1][0] += dot8(x0a, x0b, w1a, w1b); acc[1][1] += dot8(x1a, x1b, w1a, w1b);
            acc[1][2] += dot8(x2a, x2b, w1a, w1b); acc[1][3] += dot8(x3a, x3b, w1a, w1b);
            acc[2][0] += dot8(x0a, x0b, w2a, w2b); acc[2][1] += dot8(x1a, x1b, w2a, w2b);
            acc[2][2] += dot8(x2a, x2b, w2a, w2b); acc[2][3] += dot8(x3a, x3b, w2a, w2b);
        }
        #pragma unroll
        for (int o = 0; o < 3; o++) {
            float bias = qkvb[oc0 + o];
            #pragma unroll
            for (int j = 0; j < 4; j++)
                s_qkv[n0 + j][oc0 + o] = acc[o][j] + bias;
        }
    }
    __syncthreads();

    for (int idx = tid; idx < 1536; idx += 256) {
        int head = idx >> 8, r = (idx >> 4) & 15, col = idx & 15;
        float s = 0.f;
        for (int d = 0; d < 32; d++)
            s += s_qkv[r][head * 32 + d] * s_qkv[col][CC + head * 32 + d];
        s_attn[head * 16 + r][col] = s * 4.0f;
    }
    __syncthreads();

    if (tid < 96) {
        float mx = -1e30f;
        for (int i = 0; i < 16; i++) mx = fmaxf(mx, s_attn[tid][i]);
        float ss = 0.f;
        for (int i = 0; i < 16; i++) { float e = __expf(s_attn[tid][i] - mx); ss += e; s_attn[tid][i] = e; }
        float inv = 1.f / ss;
        for (int i = 0; i < 16; i++) s_attn[tid][i] *= inv;
    }
    __syncthreads();

    for (int idx = tid; idx < 16 * CC; idx += 256) {
        int n = idx / CC, c = idx - n * CC;
        int head = c >> 5;
        float s = 0.f;
        for (int m = 0; m < 16; m++) s += s_attn[head * 16 + n][m] * s_qkv[m][2 * CC + c];
        s_h[n][c] = s;
    }
    __syncthreads();

    {
        const int og  = tid >> 2;
        const int oc0 = og * 3;
        const float* w0 = projw + (size_t)(oc0 + 0) * CC;
        const float* w1 = projw + (size_t)(oc0 + 1) * CC;
        const float* w2 = projw + (size_t)(oc0 + 2) * CC;
        float acc[3][4];
        #pragma unroll
        for (int o = 0; o < 3; o++)
            #pragma unroll
            for (int j = 0; j < 4; j++) acc[o][j] = 0.f;

        for (int k8 = 0; k8 < CC / 8; k8++) {
            const int kb = k8 * 8;
            float4 w0a = *(const float4*)(w0 + kb), w0b = *(const float4*)(w0 + kb + 4);
            float4 w1a = *(const float4*)(w1 + kb), w1b = *(const float4*)(w1 + kb + 4);
            float4 w2a = *(const float4*)(w2 + kb), w2b = *(const float4*)(w2 + kb + 4);
            float4 h0a = *(const float4*)(&s_h[n0 + 0][kb]), h0b = *(const float4*)(&s_h[n0 + 0][kb + 4]);
            float4 h1a = *(const float4*)(&s_h[n0 + 1][kb]), h1b = *(const float4*)(&s_h[n0 + 1][kb + 4]);
            float4 h2a = *(const float4*)(&s_h[n0 + 2][kb]), h2b = *(const float4*)(&s_h[n0 + 2][kb + 4]);
            float4 h3a = *(const float4*)(&s_h[n0 + 3][kb]), h3b = *(const float4*)(&s_h[n0 + 3][kb + 4]);
            acc[0][0] += dot8(h0a, h0b, w0a, w0b); acc[0][1] += dot8(h1a, h1b, w0a, w0b);
            acc[0][2] += dot8(h2a, h2b, w0a, w0b); acc[0][3] += dot8(h3a, h3b, w0a, w0b);
            acc[1][0] += dot8(h0a, h0b, w1a, w1b); acc[1][1] += dot8(h1a, h1b, w1a, w1b);
            acc[1][2] += dot8(h2a, h2b, w1a, w1b); acc[1][3] += dot8(h3a, h3b, w1a, w1b);
            acc[2][0] += dot8(h0a, h0b, w2a, w2b); acc[2][1] += dot8(h1a, h1b, w2a, w2b);
            acc[2][2] += dot8(h2a, h2b, w2a, w2b); acc[2][3] += dot8(h3a, h3b, w2a, w2b);
        }
        float* xo = xt2 + (size_t)b * LL * CC;
        #pragma unroll
        for (int o = 0; o < 3; o++) {
            const int c = oc0 + o;
            float bias = projb[c];
            #pragma unroll
            for (int j = 0; j < 4; j++) {
                const size_t row = (size_t)s_tok[n0 + j] * CC;
                float res = xbT[row + c];
                xo[row + c] = acc[o][j] + bias + res;
            }
        }
    }
}

// ---- kB3: LN2 + MLP via bf16 MFMA + residual (verified round 4) ----
__global__ __launch_bounds__(256) void kB3(
    const float* __restrict__ xt2,
    const float* __restrict__ n2g, const float* __restrict__ n2b,
    const unsigned short* __restrict__ fc1wb, const float* __restrict__ fc1b,
    const unsigned short* __restrict__ fc2wb, const float* __restrict__ fc2b,
    float* __restrict__ out)
{
    __shared__ __align__(16) char smem[16 * SABP * 2];
    __shared__ __align__(16) unsigned short s_xb[16][SXBP];
    float (*s_x)[SXP] = (float(*)[SXP])smem;
    unsigned short (*s_a)[SABP] = (unsigned short(*)[SABP])smem;

    const int tid = threadIdx.x;
    const int t0 = blockIdx.x * 16;
    const int b  = t0 >> 16;
    const int l0 = t0 & (LL - 1);
    const float* xrow = xt2 + ((size_t)b * LL + l0) * CC;

    #pragma unroll
    for (int p = 0; p < 3; p++) {
        int idx = tid + p * 256;
        int n = idx / 48, c4 = idx % 48;
        float4 v = *(const float4*)(xrow + (size_t)n * CC + c4 * 4);
        *(float4*)&s_x[n][c4 * 4] = v;
    }
    __syncthreads();

    {
        const int t = tid >> 4, s = tid & 15;
        float vals[12];
        float sum = 0.f, sq = 0.f;
        #pragma unroll
        for (int k = 0; k < 12; k++) {
            float v = s_x[t][s + 16 * k];
            vals[k] = v; sum += v; sq += v * v;
        }
        #pragma unroll
        for (int m = 1; m < 16; m <<= 1) {
            sum += __shfl_xor(sum, m);
            sq  += __shfl_xor(sq, m);
        }
        float mu = sum * (1.f / CC);
        float rs = rsqrtf(sq * (1.f / CC) - mu * mu + 1e-5f);
        #pragma unroll
        for (int k = 0; k < 12; k++) {
            int c = s + 16 * k;
            s_xb[t][c] = f2us((vals[k] - mu) * rs * n2g[c] + n2b[c]);
        }
    }
    __syncthreads();

    const int lane = tid & 63;
    const int w    = tid >> 6;
    const int m16  = lane & 15;
    const int g    = lane >> 4;

    bf16x8 afrag[6];
    #pragma unroll
    for (int k = 0; k < 6; k++)
        afrag[k] = *(const bf16x8*)&s_xb[m16][k * 32 + g * 8];

    #pragma unroll
    for (int pp = 0; pp < 6; pp++) {
        const int nt0 = w * 12 + pp * 2;
        f32x4 acc0 = {0.f, 0.f, 0.f, 0.f};
        f32x4 acc1 = {0.f, 0.f, 0.f, 0.f};
        const unsigned short* wr0 = fc1wb + (size_t)(nt0 * 16 + m16) * CC + g * 8;
        const unsigned short* wr1 = wr0 + 16 * CC;
        #pragma unroll
        for (int k = 0; k < 6; k++) {
            bf16x8 b0 = *(const bf16x8*)(wr0 + k * 32);
            bf16x8 b1 = *(const bf16x8*)(wr1 + k * 32);
            acc0 = __builtin_amdgcn_mfma_f32_16x16x32_bf16(afrag[k], b0, acc0, 0, 0, 0);
            acc1 = __builtin_amdgcn_mfma_f32_16x16x32_bf16(afrag[k], b1, acc1, 0, 0, 0);
        }
        float bias0 = fc1b[nt0 * 16 + m16];
        float bias1 = fc1b[(nt0 + 1) * 16 + m16];
        #pragma unroll
        for (int t = 0; t < 4; t++) {
            s_a[g * 4 + t][nt0 * 16 + m16]       = f2us(gelu_exact(acc0[t] + bias0));
            s_a[g * 4 + t][(nt0 + 1) * 16 + m16] = f2us(gelu_exact(acc1[t] + bias1));
        }
    }
    __syncthreads();

    {
        const int nt0 = w * 3;
        f32x4 acc0 = {0.f, 0.f, 0.f, 0.f};
        f32x4 acc1 = {0.f, 0.f, 0.f, 0.f};
        f32x4 acc2 = {0.f, 0.f, 0.f, 0.f};
        const unsigned short* wr0 = fc2wb + (size_t)(nt0 * 16 + m16) * HID + g * 8;
        const unsigned short* wr1 = wr0 + 16 * HID;
        const unsigned short* wr2 = wr1 + 16 * HID;
        #pragma unroll 8
        for (int k = 0; k < 24; k++) {
            bf16x8 a  = *(const bf16x8*)&s_a[m16][k * 32 + g * 8];
            bf16x8 b0 = *(const bf16x8*)(wr0 + k * 32);
            bf16x8 b1 = *(const bf16x8*)(wr1 + k * 32);
            bf16x8 b2 = *(const bf16x8*)(wr2 + k * 32);
            acc0 = __builtin_amdgcn_mfma_f32_16x16x32_bf16(a, b0, acc0, 0, 0, 0);
            acc1 = __builtin_amdgcn_mfma_f32_16x16x32_bf16(a, b1, acc1, 0, 0, 0);
            acc2 = __builtin_amdgcn_mfma_f32_16x16x32_bf16(a, b2, acc2, 0, 0, 0);
        }
        float* outb = out + (size_t)b * CC * LL + l0;
        const int n0 = g * 4;
        #pragma unroll
        for (int i = 0; i < 3; i++) {
            const int c = (nt0 + i) * 16 + m16;
            const float bias = fc2b[c];
            const f32x4 av = (i == 0) ? acc0 : (i == 1) ? acc1 : acc2;
            float4 ov;
            ov.x = av[0] + bias + xrow[(size_t)(n0 + 0) * CC + c];
            ov.y = av[1] + bias + xrow[(size_t)(n0 + 1) * CC + c];
            ov.z = av[2] + bias + xrow[(size_t)(n0 + 2) * CC + c];
            ov.w = av[3] + bias + xrow[(size_t)(n0 + 3) * CC + c];
            *(float4*)(outb + (size_t)c * LL + n0) = ov;
        }
    }
}

// ---- kB2 (round-3 tier): LN2 + MLP f32 ----
__global__ __launch_bounds__(256, 2) void kB2(
    const float* __restrict__ xt2,
    const float* __restrict__ n2g, const float* __restrict__ n2b,
    const float* __restrict__ fc1w, const float* __restrict__ fc1b,
    const float* __restrict__ fc2w, const float* __restrict__ fc2b,
    float* __restrict__ out)
{
    __shared__ float s_x[16][SXP];
    __shared__ float s_a[16][SAP];

    const int tid = threadIdx.x;
    const int t0 = blockIdx.x * 16;
    const int b  = t0 >> 16;
    const int l0 = t0 & (LL - 1);
    const float* xrow = xt2 + ((size_t)b * LL + l0) * CC;

    #pragma unroll
    for (int p = 0; p < 3; p++) {
        int idx = tid + p * 256;
        int n = idx / 48, c4 = idx % 48;
        float4 v = *(const float4*)(xrow + (size_t)n * CC + c4 * 4);
        *(float4*)&s_x[n][c4 * 4] = v;
    }
    __syncthreads();

    {
        const int t = tid >> 4, s = tid & 15;
        float sum = 0.f, sq = 0.f;
        #pragma unroll
        for (int k = 0; k < 12; k++) {
            float v = s_x[t][s + 16 * k];
            sum += v; sq += v * v;
        }
        #pragma unroll
        for (int m = 1; m < 16; m <<= 1) {
            sum += __shfl_xor(sum, m);
            sq  += __shfl_xor(sq, m);
        }
        float mu = sum * (1.f / CC);
        float rs = rsqrtf(sq * (1.f / CC) - mu * mu + 1e-5f);
        #pragma unroll
        for (int k = 0; k < 12; k++) {
            int c = s + 16 * k;
            s_x[t][c] = (s_x[t][c] - mu) * rs * n2g[c] + n2b[c];
        }
    }
    __syncthreads();

    const int tg = tid & 3;
    const int n0 = tg * 4;
    for (int it = 0; it < 3; it++) {
        const int og  = (it * 256 + tid) >> 2;
        const int oc0 = og * 4;
        const float* w0 = fc1w + (size_t)(oc0 + 0) * CC;
        const float* w1 = fc1w + (size_t)(oc0 + 1) * CC;
        const float* w2 = fc1w + (size_t)(oc0 + 2) * CC;
        const float* w3 = fc1w + (size_t)(oc0 + 3) * CC;
        float acc[4][4];
        #pragma unroll
        for (int o = 0; o < 4; o++)
            #pragma unroll
            for (int j = 0; j < 4; j++) acc[o][j] = 0.f;

        for (int k8 = 0; k8 < CC / 8; k8++) {
            const int kb = k8 * 8;
            float4 w0a = *(const float4*)(w0 + kb), w0b = *(const float4*)(w0 + kb + 4);
            float4 w1a = *(const float4*)(w1 + kb), w1b = *(const float4*)(w1 + kb + 4);
            float4 w2a = *(const float4*)(w2 + kb), w2b = *(const float4*)(w2 + kb + 4);
            float4 w3a = *(const float4*)(w3 + kb), w3b = *(const float4*)(w3 + kb + 4);
            float4 x0a = *(const float4*)(&s_x[n0 + 0][kb]), x0b = *(const float4*)(&s_x[n0 + 0][kb + 4]);
            float4 x1a = *(const float4*)(&s_x[n0 + 1][kb]), x1b = *(const float4*)(&s_x[n0 + 1][kb + 4]);
            float4 x2a = *(const float4*)(&s_x[n0 + 2][kb]), x2b = *(const float4*)(&s_x[n0 + 2][kb + 4]);
            float4 x3a = *(const float4*)(&s_x[n0 + 3][kb]), x3b = *(const float4*)(&s_x[n0 + 3][kb + 4]);
            acc[0][0] += dot8(x0a, x0b, w0a, w0b); acc[0][1] += dot8(x1a, x1b, w0a, w0b);
            acc[0][2] += dot8(x2a, x2b, w0a, w0b); acc[0][3] += dot8(x3a, x3b, w0a, w0b);
            acc[1][0] += dot8(x0a, x0b, w1a, w1b); acc[1][1] += dot8(x1a, x1b, w1a, w1b);
            acc[1][2] += dot8(x2a, x2b, w1a, w1b); acc[1][3] += dot8(x3a, x3b, w1a, w1b);
            acc[2][0] += dot8(x0a, x0b, w2a, w2b); acc[2][1] += dot8(x1a, x1b, w2a, w2b);
            acc[2][2] += dot8(x2a, x2b, w2a, w2b); acc[2][3] += dot8(x3a, x3b, w2a, w2b);
            acc[3][0] += dot8(x0a, x0b, w3a, w3b); acc[3][1] += dot8(x1a, x1b, w3a, w3b);
            acc[3][2] += dot8(x2a, x2b, w3a, w3b); acc[3][3] += dot8(x3a, x3b, w3a, w3b);
        }
        #pragma unroll
        for (int o = 0; o < 4; o++) {
            float bias = fc1b[oc0 + o];
            #pragma unroll
            for (int j = 0; j < 4; j++)
                s_a[n0 + j][oc0 + o] = gelu_exact(acc[o][j] + bias);
        }
    }
    __syncthreads();

    {
        const int og  = tid >> 2;
        const int oc0 = og * 3;
        const float* w0 = fc2w + (size_t)(oc0 + 0) * HID;
        const float* w1 = fc2w + (size_t)(oc0 + 1) * HID;
        const float* w2 = fc2w + (size_t)(oc0 + 2) * HID;
        float acc[3][4];
        #pragma unroll
        for (int o = 0; o < 3; o++)
            #pragma unroll
            for (int j = 0; j < 4; j++) acc[o][j] = 0.f;

        for (int k8 = 0; k8 < HID / 8; k8++) {
            const int kb = k8 * 8;
            float4 w0a = *(const float4*)(w0 + kb), w0b = *(const float4*)(w0 + kb + 4);
            float4 w1a = *(const float4*)(w1 + kb), w1b = *(const float4*)(w1 + kb + 4);
            float4 w2a = *(const float4*)(w2 + kb), w2b = *(const float4*)(w2 + kb + 4);
            float4 a0a = *(const float4*)(&s_a[n0 + 0][kb]), a0b = *(const float4*)(&s_a[n0 + 0][kb + 4]);
            float4 a1a = *(const float4*)(&s_a[n0 + 1][kb]), a1b = *(const float4*)(&s_a[n0 + 1][kb + 4]);
            float4 a2a = *(const float4*)(&s_a[n0 + 2][kb]), a2b = *(const float4*)(&s_a[n0 + 2][kb + 4]);
            float4 a3a = *(const float4*)(&s_a[n0 + 3][kb]), a3b = *(const float4*)(&s_a[n0 + 3][kb + 4]);
            acc[0][0] += dot8(a0a, a0b, w0a, w0b); acc[0][1] += dot8(a1a, a1b, w0a, w0b);
            acc[0][2] += dot8(a2a, a2b, w0a, w0b); acc[0][3] += dot8(a3a, a3b, w0a, w0b);
            acc[1][0] += dot8(a0a, a0b, w1a, w1b); acc[1][1] += dot8(a1a, a1b, w1a, w1b);
            acc[1][2] += dot8(a2a, a2b, w1a, w1b); acc[1][3] += dot8(a3a, a3b, w1a, w1b);
            acc[2][0] += dot8(a0a, a0b, w2a, w2b); acc[2][1] += dot8(a1a, a1b, w2a, w2b);
            acc[2][2] += dot8(a2a, a2b, w2a, w2b); acc[2][3] += dot8(a3a, a3b, w2a, w2b);
        }
        #pragma unroll
        for (int o = 0; o < 3; o++) {
            const int c = oc0 + o;
            float bias = fc2b[c];
            float4 outv;
            float r0 = xrow[(size_t)(n0 + 0) * CC + c];
            float r1 = xrow[(size_t)(n0 + 1) * CC + c];
            float r2 = xrow[(size_t)(n0 + 2) * CC + c];
            float r3 = xrow[(size_t)(n0 + 3) * CC + c];
            outv.x = acc[o][0] + bias + r0;
            outv.y = acc[o][1] + bias + r1;
            outv.z = acc[o][2] + bias + r2;
            outv.w = acc[o][3] + bias + r3;
            *(float4*)(out + ((size_t)b * CC + c) * LL + l0 + n0) = outv;
        }
    }
}

// =================== NO-WORKSPACE FALLBACK (round-2 kernels) ===================

__global__ __launch_bounds__(256) void kA(
    const float* __restrict__ x, const int* __restrict__ perm,
    const float* __restrict__ n1g, const float* __restrict__ n1b,
    const float* __restrict__ qkvw, const float* __restrict__ qkvb,
    const float* __restrict__ projw, const float* __restrict__ projb,
    float* __restrict__ xt2)
{
    __shared__ float s_h[16][CC];
    __shared__ float s_qkv[16][3*CC];
    __shared__ float s_attn[96][16];
    __shared__ unsigned short s_stash[16][CC];
    __shared__ float s_mu[16], s_rs[16];
    __shared__ int s_tok[16];

    const int tid = threadIdx.x;
    const int wid = blockIdx.x;
    const int b  = wid >> 12;
    const int hb = (wid >> 6) & 63;
    const int wb = wid & 63;

    if (tid < 16) {
        int si = tid >> 2, sj = tid & 3;
        s_tok[tid] = perm[(hb * 4 + si) * WWW + wb * 4 + sj];
    }
    __syncthreads();

    for (int idx = tid; idx < 16 * CC; idx += 256) {
        int n = idx / CC, c = idx - n * CC;
        float v = x[((size_t)b * CC + c) * LL + s_tok[n]];
        s_h[n][c] = v;
        s_stash[n][c] = f2us(v);
    }
    __syncthreads();

    if (tid < 16) {
        float s = 0.f, q = 0.f;
        for (int c = 0; c < CC; c++) { float v = s_h[tid][c]; s += v; q += v * v; }
        float mu = s * (1.f / CC);
        float var = q * (1.f / CC) - mu * mu;
        s_mu[tid] = mu;
        s_rs[tid] = rsqrtf(var + 1e-5f);
    }
    __syncthreads();

    for (int idx = tid; idx < 16 * CC; idx += 256) {
        int n = idx / CC, c = idx - n * CC;
        s_h[n][c] = (s_h[n][c] - s_mu[n]) * s_rs[n] * n1g[c] + n1b[c];
    }
    __syncthreads();

    for (int oc = tid; oc < 3 * CC; oc += 256) {
        float acc[16];
        for (int i = 0; i < 16; i++) acc[i] = 0.f;
        const float4* wr = (const float4*)(qkvw + (size_t)oc * CC);
        for (int k8 = 0; k8 < CC / 8; ++k8) {
            float4 wa = wr[k8 * 2], wb2 = wr[k8 * 2 + 1];
            for (int n = 0; n < 16; n++) {
                const float4* hp = (const float4*)(&s_h[n][k8 * 8]);
                acc[n] += dot8(hp[0], hp[1], wa, wb2);
            }
        }
        float bias = qkvb[oc];
        for (int n = 0; n < 16; n++) s_qkv[n][oc] = acc[n] + bias;
    }
    __syncthreads();

    for (int idx = tid; idx < 1536; idx += 256) {
        int head = idx >> 8, r = (idx >> 4) & 15, col = idx & 15;
        float s = 0.f;
        for (int d = 0; d < 32; d++)
            s += s_qkv[r][head * 32 + d] * s_qkv[col][CC + head * 32 + d];
        s_attn[head * 16 + r][col] = s * 4.0f;
    }
    __syncthreads();

    if (tid < 96) {
        float mx = -1e30f;
        for (int i = 0; i < 16; i++) mx = fmaxf(mx, s_attn[tid][i]);
        float ss = 0.f;
        for (int i = 0; i < 16; i++) { float e = __expf(s_attn[tid][i] - mx); ss += e; s_attn[tid][i] = e; }
        float inv = 1.f / ss;
        for (int i = 0; i < 16; i++) s_attn[tid][i] *= inv;
    }
    __syncthreads();

    for (int idx = tid; idx < 16 * CC; idx += 256) {
        int n = idx / CC, c = idx - n * CC;
        int head = c >> 5;
        float s = 0.f;
        for (int m = 0; m < 16; m++) s += s_attn[head * 16 + n][m] * s_qkv[m][2 * CC + c];
        s_h[n][c] = s;
    }
    __syncthreads();

    if (tid < CC) {
        const int c = tid;
        float acc[16];
        for (int i = 0; i < 16; i++) acc[i] = 0.f;
        const float4* wr = (const float4*)(projw + (size_t)c * CC);
        for (int k8 = 0; k8 < CC / 8; ++k8) {
            float4 wa = wr[k8 * 2], wb2 = wr[k8 * 2 + 1];
            for (int n = 0; n < 16; n++) {
                const float4* hp = (const float4*)(&s_h[n][k8 * 8]);
                acc[n] += dot8(hp[0], hp[1], wa, wb2);
            }
        }
        float bias = projb[c];
        for (int n = 0; n < 16; n++) {
            float res = us2f(s_stash[n][c]);
            xt2[((size_t)b * CC + c) * LL + s_tok[n]] = acc[n] + bias + res;
        }
    }
}

__global__ __launch_bounds__(256, 2) void kB(
    float* __restrict__ xt2,
    const float* __restrict__ n2g, const float* __restrict__ n2b,
    const float* __restrict__ fc1w, const float* __restrict__ fc1b,
    const float* __restrict__ fc2w, const float* __restrict__ fc2b)
{
    __shared__ float s_x[16][SXP];
    __shared__ float s_a[16][SAP];

    const int tid = threadIdx.x;
    const int t0 = blockIdx.x * 16;
    const int b  = t0 >> 16;
    const int l0 = t0 & (LL - 1);
    float* xbase = xt2 + (size_t)b * CC * LL + l0;

    for (int idx = tid; idx < 4 * CC; idx += 256) {
        int c = idx >> 2, n4 = idx & 3;
        float4 v = *(const float4*)(xbase + (size_t)c * LL + n4 * 4);
        s_x[n4 * 4 + 0][c] = v.x;
        s_x[n4 * 4 + 1][c] = v.y;
        s_x[n4 * 4 + 2][c] = v.z;
        s_x[n4 * 4 + 3][c] = v.w;
    }
    __syncthreads();

    {
        const int t = tid >> 4, s = tid & 15;
        float sum = 0.f, sq = 0.f;
        #pragma unroll
        for (int k = 0; k < 12; k++) {
            float v = s_x[t][s + 16 * k];
            sum += v; sq += v * v;
        }
        #pragma unroll
        for (int m = 1; m < 16; m <<= 1) {
            sum += __shfl_xor(sum, m);
            sq  += __shfl_xor(sq, m);
        }
        float mu = sum * (1.f / CC);
        float rs = rsqrtf(sq * (1.f / CC) - mu * mu + 1e-5f);
        #pragma unroll
        for (int k = 0; k < 12; k++) {
            int c = s + 16 * k;
            s_x[t][c] = (s_x[t][c] - mu) * rs * n2g[c] + n2b[c];
        }
    }
    __syncthreads();

    const int tg = tid & 3;
    const int n0 = tg * 4;
    for (int it = 0; it < 3; it++) {
        const int og  = (it * 256 + tid) >> 2;
        const int oc0 = og * 4;
        const float* w0 = fc1w + (size_t)(oc0 + 0) * CC;
        const float* w1 = fc1w + (size_t)(oc0 + 1) * CC;
        const float* w2 = fc1w + (size_t)(oc0 + 2) * CC;
        const float* w3 = fc1w + (size_t)(oc0 + 3) * CC;
        float acc[4][4];
        #pragma unroll
        for (int o = 0; o < 4; o++)
            #pragma unroll
            for (int j = 0; j < 4; j++) acc[o][j] = 0.f;

        for (int k8 = 0; k8 < CC / 8; k8++) {
            const int kb = k8 * 8;
            float4 w0a = *(const float4*)(w0 + kb), w0b = *(const float4*)(w0 + kb + 4);
            float4 w1a = *(const float4*)(w1 + kb), w1b = *(const float4*)(w1 + kb + 4);
            float4 w2a = *(const float4*)(w2 + kb), w2b = *(const float4*)(w2 + kb + 4);
            float4 w3a = *(const float4*)(w3 + kb), w3b = *(const float4*)(w3 + kb + 4);
            float4 x0a = *(const float4*)(&s_x[n0 + 0][kb]), x0b = *(const float4*)(&s_x[n0 + 0][kb + 4]);
            float4 x1a = *(const float4*)(&s_x[n0 + 1][kb]), x1b = *(const float4*)(&s_x[n0 + 1][kb + 4]);
            float4 x2a = *(const float4*)(&s_x[n0 + 2][kb]), x2b = *(const float4*)(&s_x[n0 + 2][kb + 4]);
            float4 x3a = *(const float4*)(&s_x[n0 + 3][kb]), x3b = *(const float4*)(&s_x[n0 + 3][kb + 4]);
            acc[0][0] += dot8(x0a, x0b, w0a, w0b); acc[0][1] += dot8(x1a, x1b, w0a, w0b);
            acc[0][2] += dot8(x2a, x2b, w0a, w0b); acc[0][3] += dot8(x3a, x3b, w0a, w0b);
            acc[1][0] += dot8(x0a, x0b, w1a, w1b); acc[1][1] += dot8(x1a, x1b, w1a, w1b);
            acc[1][2] += dot8(x2a, x2b, w1a, w1b); acc[1][3] += dot8(x3a, x3b, w1a, w1b);
            acc[2][0] += dot8(x0a, x0b, w2a, w2b); acc[2][1] += dot8(x1a, x1b, w2a, w2b);
            acc[2][2] += dot8(x2a, x2b, w2a, w2b); acc[2][3] += dot8(x3a, x3b, w2a, w2b);
            acc[3][0] += dot8(x0a, x0b, w3a, w3b); acc[3][1] += dot8(x1a, x1b, w3a, w3b);
            acc[3][2] += dot8(x2a, x2b, w3a, w3b); acc[3][3] += dot8(x3a, x3b, w3a, w3b);
        }
        #pragma unroll
        for (int o = 0; o < 4; o++) {
            float bias = fc1b[oc0 + o];
            #pragma unroll
            for (int j = 0; j < 4; j++)
                s_a[n0 + j][oc0 + o] = gelu_exact(acc[o][j] + bias);
        }
    }
    __syncthreads();

    {
        const int og  = tid >> 2;
        const int oc0 = og * 3;
        const float* w0 = fc2w + (size_t)(oc0 + 0) * HID;
        const float* w1 = fc2w + (size_t)(oc0 + 1) * HID;
        const float* w2 = fc2w + (size_t)(oc0 + 2) * HID;
        float acc[3][4];
        #pragma unroll
        for (int o = 0; o < 3; o++)
            #pragma unroll
            for (int j = 0; j < 4; j++) acc[o][j] = 0.f;

        for (int k8 = 0; k8 < HID / 8; k8++) {
            const int kb = k8 * 8;
            float4 w0a = *(const float4*)(w0 + kb), w0b = *(const float4*)(w0 + kb + 4);
            float4 w1a = *(const float4*)(w1 + kb), w1b = *(const float4*)(w1 + kb + 4);
            float4 w2a = *(const float4*)(w2 + kb), w2b = *(const float4*)(w2 + kb + 4);
            float4 a0a = *(const float4*)(&s_a[n0 + 0][kb]), a0b = *(const float4*)(&s_a[n0 + 0][kb + 4]);
            float4 a1a = *(const float4*)(&s_a[n0 + 1][kb]), a1b = *(const float4*)(&s_a[n0 + 1][kb + 4]);
            float4 a2a = *(const float4*)(&s_a[n0 + 2][kb]), a2b = *(const float4*)(&s_a[n0 + 2][kb + 4]);
            float4 a3a = *(const float4*)(&s_a[n0 + 3][kb]), a3b = *(const float4*)(&s_a[n0 + 3][kb + 4]);
            acc[0][0] += dot8(a0a, a0b, w0a, w0b); acc[0][1] += dot8(a1a, a1b, w0a, w0b);
            acc[0][2] += dot8(a2a, a2b, w0a, w0b); acc[0][3] += dot8(a3a, a3b, w0a, w0b);
            acc[1][0] += dot8(a0a, a0b, w1a, w1b); acc[1][1] += dot8(a1a, a1b, w1a, w1b);
            acc[1][2] += dot8(a2a, a2b, w1a, w1b); acc[1][3] += dot8(a3a, a3b, w1a, w1b);
            acc[2][0] += dot8(a0a, a0b, w2a, w2b); acc[2][1] += dot8(a1a, a1b, w2a, w2b);
            acc[2][2] += dot8(a2a, a2b, w2a, w2b); acc[2][3] += dot8(a3a, a3b, w2a, w2b);
        }
        #pragma unroll
        for (int o = 0; o < 3; o++) {
            const int c = oc0 + o;
            float bias = fc2b[c];
            float* p = xbase + (size_t)c * LL + n0;
            float4 r = *(const float4*)p;
            float4 outv;
            outv.x = acc[o][0] + bias + r.x;
            outv.y = acc[o][1] + bias + r.y;
            outv.z = acc[o][2] + bias + r.z;
            outv.w = acc[o][3] + bias + r.w;
            *(float4*)p = outv;
        }
    }
}

extern "C" void kernel_launch(void* const* d_in, const int* in_sizes, int n_in,
                              void* d_out, int out_size, void* d_ws, size_t ws_size,
                              hipStream_t stream) {
    const float* x     = (const float*)d_in[0];
    const int*   perm  = (const int*)d_in[1];
    const float* n1g   = (const float*)d_in[2];
    const float* n1b   = (const float*)d_in[3];
    const float* qkvw  = (const float*)d_in[4];
    const float* qkvb  = (const float*)d_in[5];
    const float* projw = (const float*)d_in[6];
    const float* projb = (const float*)d_in[7];
    const float* n2g   = (const float*)d_in[8];
    const float* n2b   = (const float*)d_in[9];
    const float* fc1w  = (const float*)d_in[10];
    const float* fc1b  = (const float*)d_in[11];
    const float* fc2w  = (const float*)d_in[12];
    const float* fc2b  = (const float*)d_in[13];

    const size_t NTOK  = (size_t)BB * LL * CC;
    const size_t WS_MID  = 2 * NTOK * sizeof(float);                               // xT + xt2
    const size_t WS_T1   = WS_MID + 2 * (size_t)HID * CC * sizeof(unsigned short); // + fc bf16
    const size_t WS_T2   = WS_T1 + (size_t)(3*CC*CC + CC*CC) * sizeof(unsigned short); // + qkv/proj bf16

    if (d_ws != nullptr && ws_size >= WS_T2) {
        float* xT   = (float*)d_ws;
        float* xt2w = xT + NTOK;
        unsigned short* fc1wb  = (unsigned short*)(xt2w + NTOK);
        unsigned short* fc2wb  = fc1wb + (size_t)HID * CC;
        unsigned short* qkvwb  = fc2wb + (size_t)HID * CC;
        unsigned short* projwb = qkvwb + (size_t)3 * CC * CC;
        kW2<<<(HID * CC + 255) / 256, 256, 0, stream>>>(fc1w, fc2w, qkvw, projw, fc1wb, fc2wb, qkvwb, projwb);
        kT <<<BB * (LL / TLL), 256, 0, stream>>>(x, xT);
        kA3<<<16384, 256, 0, stream>>>(xT, perm, n1g, n1b, qkvwb, qkvb, projwb, projb, xt2w);
        kB3<<<16384, 256, 0, stream>>>(xt2w, n2g, n2b, fc1wb, fc1b, fc2wb, fc2b, (float*)d_out);
    } else if (d_ws != nullptr && ws_size >= WS_T1) {
        float* xT   = (float*)d_ws;
        float* xt2w = xT + NTOK;
        unsigned short* fc1wb = (unsigned short*)(xt2w + NTOK);
        unsigned short* fc2wb = fc1wb + (size_t)HID * CC;
        kW <<<(HID * CC + 255) / 256, 256, 0, stream>>>(fc1w, fc2w, fc1wb, fc2wb);
        kT <<<BB * (LL / TLL), 256, 0, stream>>>(x, xT);
        kA2<<<16384, 256, 0, stream>>>(xT, perm, n1g, n1b, qkvw, qkvb, projw, projb, xt2w);
        kB3<<<16384, 256, 0, stream>>>(xt2w, n2g, n2b, fc1wb, fc1b, fc2wb, fc2b, (float*)d_out);
    } else if (d_ws != nullptr && ws_size >= WS_MID) {
        float* xT   = (float*)d_ws;
        float* xt2w = xT + NTOK;
        kT <<<BB * (LL / TLL), 256, 0, stream>>>(x, xT);
        kA2<<<16384, 256, 0, stream>>>(xT, perm, n1g, n1b, qkvw, qkvb, projw, projb, xt2w);
        kB2<<<16384, 256, 0, stream>>>(xt2w, n2g, n2b, fc1w, fc1b, fc2w, fc2b, (float*)d_out);
    } else {
        float* out = (float*)d_out;
        kA<<<16384, 256, 0, stream>>>(x, perm, n1g, n1b, qkvw, qkvb, projw, projb, out);
        kB<<<16384, 256, 0, stream>>>(out, n2g, n2b, fc1w, fc1b, fc2w, fc2b);
    }
    (void)in_sizes; (void)n_in; (void)out_size;
}

// Round 6
// 1420.503 us; speedup vs baseline: 66.2035x; 1.4473x over previous
//
#include <hip/hip_runtime.h>
#include <hip/hip_bf16.h>

#define BB 4
#define CC 192
#define LL 65536
#define WWW 256
#define HID 768
#define SXP (CC + 4)    // 196 f32
#define SQP (3*CC + 4)  // 580 f32
#define SAP (HID + 4)   // 772 f32
#define SXBP 200        // bf16 row stride (400 B): 2-way-max bank aliasing on b128 frag reads
#define SABP 776        // bf16 row stride (1552 B)

typedef short bf16x8 __attribute__((ext_vector_type(8)));
typedef float f32x4  __attribute__((ext_vector_type(4)));

__device__ __forceinline__ float us2f(unsigned short u) { return __uint_as_float(((unsigned int)u) << 16); }
__device__ __forceinline__ unsigned short f2us(float f) {
    unsigned int x = __float_as_uint(f);
    unsigned int r = (x + 0x7FFFu + ((x >> 16) & 1u)) >> 16;
    return (unsigned short)r;
}

__device__ __forceinline__ float gelu_exact(float x) {
    return 0.5f * x * (1.0f + erff(x * 0.70710678118654752440f));
}

__device__ __forceinline__ float dot8(const float4 a, const float4 b, const float4 wa, const float4 wb) {
    return a.x*wa.x + a.y*wa.y + a.z*wa.z + a.w*wa.w
         + b.x*wb.x + b.y*wb.y + b.z*wb.z + b.w*wb.w;
}

// =================== FAST PATH ===================

// ---- kW2: convert all four GEMM weights f32 -> bf16 ----
__global__ __launch_bounds__(256) void kW2(
    const float* __restrict__ fc1w, const float* __restrict__ fc2w,
    const float* __restrict__ qkvw, const float* __restrict__ projw,
    unsigned short* __restrict__ fc1wb, unsigned short* __restrict__ fc2wb,
    unsigned short* __restrict__ qkvwb, unsigned short* __restrict__ projwb)
{
    int i = blockIdx.x * 256 + threadIdx.x;
    if (i < HID * CC) { fc1wb[i] = f2us(fc1w[i]); fc2wb[i] = f2us(fc2w[i]); }
    if (i < 3 * CC * CC) qkvwb[i] = f2us(qkvw[i]);
    if (i < CC * CC)     projwb[i] = f2us(projw[i]);
}

// ---- kW: convert fc1w/fc2w only (round-4 tier) ----
__global__ __launch_bounds__(256) void kW(
    const float* __restrict__ fc1w, const float* __restrict__ fc2w,
    unsigned short* __restrict__ fc1wb, unsigned short* __restrict__ fc2wb)
{
    int i = blockIdx.x * 256 + threadIdx.x;
    if (i < HID * CC) {
        fc1wb[i] = f2us(fc1w[i]);
        fc2wb[i] = f2us(fc2w[i]);
    }
}

// ---- kT: transpose x (B,C,L) f32 -> xT (B,L,C) f32 ----
#define TLL 64
__global__ __launch_bounds__(256) void kT(const float* __restrict__ x, float* __restrict__ xT)
{
    __shared__ float s_t[TLL][SXP];
    const int tid = threadIdx.x;
    const int b  = blockIdx.x >> 10;
    const int l0 = (blockIdx.x & 1023) * TLL;

    #pragma unroll
    for (int p = 0; p < 12; p++) {
        int idx = tid + p * 256;
        int c = idx >> 4, l4 = idx & 15;
        float4 v = *(const float4*)(x + ((size_t)b * CC + c) * LL + l0 + l4 * 4);
        s_t[l4 * 4 + 0][c] = v.x;
        s_t[l4 * 4 + 1][c] = v.y;
        s_t[l4 * 4 + 2][c] = v.z;
        s_t[l4 * 4 + 3][c] = v.w;
    }
    __syncthreads();

    #pragma unroll
    for (int p = 0; p < 12; p++) {
        int idx = tid + p * 256;
        int l = idx / 48, c4 = idx % 48;
        float4 v = *(const float4*)(&s_t[l][c4 * 4]);
        *(float4*)(xT + ((size_t)b * LL + l0 + l) * CC + c4 * 4) = v;
    }
}

// ---- kA3: gather + LN1 + MFMA QKV + f32 attn + MFMA proj + exact residual ----
__global__ __launch_bounds__(256) void kA3(
    const float* __restrict__ xT, const int* __restrict__ perm,
    const float* __restrict__ n1g, const float* __restrict__ n1b,
    const unsigned short* __restrict__ qkvwb, const float* __restrict__ qkvb,
    const unsigned short* __restrict__ projwb, const float* __restrict__ projb,
    float* __restrict__ xt2)
{
    __shared__ __align__(16) float smemA[16 * SQP];
    float (*s_h)[SXP]   = (float(*)[SXP])smemA;
    float (*s_qkv)[SQP] = (float(*)[SQP])smemA;
    __shared__ __align__(16) unsigned short s_hb[16][SXBP];
    __shared__ __align__(16) unsigned short s_ob[16][SXBP];
    __shared__ float s_attn[96][17];
    __shared__ int s_tok[16];

    const int tid = threadIdx.x;
    const int wid = blockIdx.x;
    const int b  = wid >> 12;
    const int hb = (wid >> 6) & 63;
    const int wb = wid & 63;

    if (tid < 16) {
        int si = tid >> 2, sj = tid & 3;
        s_tok[tid] = perm[(hb * 4 + si) * WWW + wb * 4 + sj];
    }
    __syncthreads();

    const float* xbT = xT + (size_t)b * LL * CC;

    #pragma unroll
    for (int p = 0; p < 3; p++) {
        int idx = tid + p * 256;
        int n = idx / 48, c4 = idx % 48;
        float4 v = *(const float4*)(xbT + (size_t)s_tok[n] * CC + c4 * 4);
        *(float4*)&s_h[n][c4 * 4] = v;
    }
    __syncthreads();

    {
        const int t = tid >> 4, s = tid & 15;
        float vals[12];
        float sum = 0.f, sq = 0.f;
        #pragma unroll
        for (int k = 0; k < 12; k++) {
            float v = s_h[t][s + 16 * k];
            vals[k] = v; sum += v; sq += v * v;
        }
        #pragma unroll
        for (int m = 1; m < 16; m <<= 1) {
            sum += __shfl_xor(sum, m);
            sq  += __shfl_xor(sq, m);
        }
        float mu = sum * (1.f / CC);
        float rs = rsqrtf(sq * (1.f / CC) - mu * mu + 1e-5f);
        #pragma unroll
        for (int k = 0; k < 12; k++) {
            int c = s + 16 * k;
            s_hb[t][c] = f2us((vals[k] - mu) * rs * n1g[c] + n1b[c]);
        }
    }
    __syncthreads();

    const int lane = tid & 63;
    const int w    = tid >> 6;
    const int m16  = lane & 15;
    const int g    = lane >> 4;

    {
        bf16x8 afrag[6];
        #pragma unroll
        for (int k = 0; k < 6; k++)
            afrag[k] = *(const bf16x8*)&s_hb[m16][k * 32 + g * 8];

        #pragma unroll
        for (int ii = 0; ii < 3; ii++) {
            const int nt0 = w * 9 + ii * 3;
            f32x4 a0 = {0.f,0.f,0.f,0.f}, a1 = {0.f,0.f,0.f,0.f}, a2 = {0.f,0.f,0.f,0.f};
            const unsigned short* w0 = qkvwb + (size_t)((nt0 + 0) * 16 + m16) * CC + g * 8;
            const unsigned short* w1 = qkvwb + (size_t)((nt0 + 1) * 16 + m16) * CC + g * 8;
            const unsigned short* w2 = qkvwb + (size_t)((nt0 + 2) * 16 + m16) * CC + g * 8;
            #pragma unroll
            for (int k = 0; k < 6; k++) {
                a0 = __builtin_amdgcn_mfma_f32_16x16x32_bf16(afrag[k], *(const bf16x8*)(w0 + k * 32), a0, 0, 0, 0);
                a1 = __builtin_amdgcn_mfma_f32_16x16x32_bf16(afrag[k], *(const bf16x8*)(w1 + k * 32), a1, 0, 0, 0);
                a2 = __builtin_amdgcn_mfma_f32_16x16x32_bf16(afrag[k], *(const bf16x8*)(w2 + k * 32), a2, 0, 0, 0);
            }
            const int c0 = (nt0 + 0) * 16 + m16;
            const int c1 = (nt0 + 1) * 16 + m16;
            const int c2 = (nt0 + 2) * 16 + m16;
            const float b0 = qkvb[c0], b1 = qkvb[c1], b2 = qkvb[c2];
            #pragma unroll
            for (int t = 0; t < 4; t++) {
                s_qkv[g * 4 + t][c0] = a0[t] + b0;
                s_qkv[g * 4 + t][c1] = a1[t] + b1;
                s_qkv[g * 4 + t][c2] = a2[t] + b2;
            }
        }
    }
    __syncthreads();

    for (int idx = tid; idx < 1536; idx += 256) {
        int head = idx >> 8, r = (idx >> 4) & 15, col = idx & 15;
        float s = 0.f;
        for (int d = 0; d < 32; d++)
            s += s_qkv[r][head * 32 + d] * s_qkv[col][CC + head * 32 + d];
        s_attn[head * 16 + r][col] = s * 4.0f;
    }
    __syncthreads();

    if (tid < 96) {
        float mx = -1e30f;
        for (int i = 0; i < 16; i++) mx = fmaxf(mx, s_attn[tid][i]);
        float ss = 0.f;
        for (int i = 0; i < 16; i++) { float e = __expf(s_attn[tid][i] - mx); ss += e; s_attn[tid][i] = e; }
        float inv = 1.f / ss;
        for (int i = 0; i < 16; i++) s_attn[tid][i] *= inv;
    }
    __syncthreads();

    for (int idx = tid; idx < 16 * CC; idx += 256) {
        int n = idx / CC, c = idx - n * CC;
        int head = c >> 5;
        float s = 0.f;
        for (int m = 0; m < 16; m++) s += s_attn[head * 16 + n][m] * s_qkv[m][2 * CC + c];
        s_ob[n][c] = f2us(s);
    }
    __syncthreads();

    {
        bf16x8 pa[6];
        #pragma unroll
        for (int k = 0; k < 6; k++)
            pa[k] = *(const bf16x8*)&s_ob[m16][k * 32 + g * 8];

        const int nt0 = w * 3;
        f32x4 a0 = {0.f,0.f,0.f,0.f}, a1 = {0.f,0.f,0.f,0.f}, a2 = {0.f,0.f,0.f,0.f};
        const unsigned short* w0 = projwb + (size_t)((nt0 + 0) * 16 + m16) * CC + g * 8;
        const unsigned short* w1 = projwb + (size_t)((nt0 + 1) * 16 + m16) * CC + g * 8;
        const unsigned short* w2 = projwb + (size_t)((nt0 + 2) * 16 + m16) * CC + g * 8;
        #pragma unroll
        for (int k = 0; k < 6; k++) {
            a0 = __builtin_amdgcn_mfma_f32_16x16x32_bf16(pa[k], *(const bf16x8*)(w0 + k * 32), a0, 0, 0, 0);
            a1 = __builtin_amdgcn_mfma_f32_16x16x32_bf16(pa[k], *(const bf16x8*)(w1 + k * 32), a1, 0, 0, 0);
            a2 = __builtin_amdgcn_mfma_f32_16x16x32_bf16(pa[k], *(const bf16x8*)(w2 + k * 32), a2, 0, 0, 0);
        }
        float* xo = xt2 + (size_t)b * LL * CC;
        #pragma unroll
        for (int i = 0; i < 3; i++) {
            const int c = (nt0 + i) * 16 + m16;
            const float bias = projb[c];
            const f32x4 av = (i == 0) ? a0 : (i == 1) ? a1 : a2;
            #pragma unroll
            for (int t = 0; t < 4; t++) {
                const size_t row = (size_t)s_tok[g * 4 + t] * CC;
                xo[row + c] = av[t] + bias + xbT[row + c];
            }
        }
    }
}

// ---- kA2 (mid tier): f32 VALU attention block ----
__global__ __launch_bounds__(256) void kA2(
    const float* __restrict__ xT, const int* __restrict__ perm,
    const float* __restrict__ n1g, const float* __restrict__ n1b,
    const float* __restrict__ qkvw, const float* __restrict__ qkvb,
    const float* __restrict__ projw, const float* __restrict__ projb,
    float* __restrict__ xt2)
{
    __shared__ float s_h[16][SXP];
    __shared__ float s_qkv[16][SQP];
    __shared__ float s_attn[96][17];
    __shared__ int s_tok[16];

    const int tid = threadIdx.x;
    const int wid = blockIdx.x;
    const int b  = wid >> 12;
    const int hb = (wid >> 6) & 63;
    const int wb = wid & 63;

    if (tid < 16) {
        int si = tid >> 2, sj = tid & 3;
        s_tok[tid] = perm[(hb * 4 + si) * WWW + wb * 4 + sj];
    }
    __syncthreads();

    const float* xbT = xT + (size_t)b * LL * CC;

    #pragma unroll
    for (int p = 0; p < 3; p++) {
        int idx = tid + p * 256;
        int n = idx / 48, c4 = idx % 48;
        float4 v = *(const float4*)(xbT + (size_t)s_tok[n] * CC + c4 * 4);
        *(float4*)&s_h[n][c4 * 4] = v;
    }
    __syncthreads();

    {
        const int t = tid >> 4, s = tid & 15;
        float sum = 0.f, sq = 0.f;
        #pragma unroll
        for (int k = 0; k < 12; k++) {
            float v = s_h[t][s + 16 * k];
            sum += v; sq += v * v;
        }
        #pragma unroll
        for (int m = 1; m < 16; m <<= 1) {
            sum += __shfl_xor(sum, m);
            sq  += __shfl_xor(sq, m);
        }
        float mu = sum * (1.f / CC);
        float rs = rsqrtf(sq * (1.f / CC) - mu * mu + 1e-5f);
        #pragma unroll
        for (int k = 0; k < 12; k++) {
            int c = s + 16 * k;
            s_h[t][c] = (s_h[t][c] - mu) * rs * n1g[c] + n1b[c];
        }
    }
    __syncthreads();

    const int tg = tid & 3;
    const int n0 = tg * 4;
    for (int it = 0; it < 3; it++) {
        const int og  = (it * 256 + tid) >> 2;
        const int oc0 = og * 3;
        const float* w0 = qkvw + (size_t)(oc0 + 0) * CC;
        const float* w1 = qkvw + (size_t)(oc0 + 1) * CC;
        const float* w2 = qkvw + (size_t)(oc0 + 2) * CC;
        float acc[3][4];
        #pragma unroll
        for (int o = 0; o < 3; o++)
            #pragma unroll
            for (int j = 0; j < 4; j++) acc[o][j] = 0.f;

        for (int k8 = 0; k8 < CC / 8; k8++) {
            const int kb = k8 * 8;
            float4 w0a = *(const float4*)(w0 + kb), w0b = *(const float4*)(w0 + kb + 4);
            float4 w1a = *(const float4*)(w1 + kb), w1b = *(const float4*)(w1 + kb + 4);
            float4 w2a = *(const float4*)(w2 + kb), w2b = *(const float4*)(w2 + kb + 4);
            float4 x0a = *(const float4*)(&s_h[n0 + 0][kb]), x0b = *(const float4*)(&s_h[n0 + 0][kb + 4]);
            float4 x1a = *(const float4*)(&s_h[n0 + 1][kb]), x1b = *(const float4*)(&s_h[n0 + 1][kb + 4]);
            float4 x2a = *(const float4*)(&s_h[n0 + 2][kb]), x2b = *(const float4*)(&s_h[n0 + 2][kb + 4]);
            float4 x3a = *(const float4*)(&s_h[n0 + 3][kb]), x3b = *(const float4*)(&s_h[n0 + 3][kb + 4]);
            acc[0][0] += dot8(x0a, x0b, w0a, w0b); acc[0][1] += dot8(x1a, x1b, w0a, w0b);
            acc[0][2] += dot8(x2a, x2b, w0a, w0b); acc[0][3] += dot8(x3a, x3b, w0a, w0b);
            acc[1][0] += dot8(x0a, x0b, w1a, w1b); acc[1][1] += dot8(x1a, x1b, w1a, w1b);
            acc[1][2] += dot8(x2a, x2b, w1a, w1b); acc[1][3] += dot8(x3a, x3b, w1a, w1b);
            acc[2][0] += dot8(x0a, x0b, w2a, w2b); acc[2][1] += dot8(x1a, x1b, w2a, w2b);
            acc[2][2] += dot8(x2a, x2b, w2a, w2b); acc[2][3] += dot8(x3a, x3b, w2a, w2b);
        }
        #pragma unroll
        for (int o = 0; o < 3; o++) {
            float bias = qkvb[oc0 + o];
            #pragma unroll
            for (int j = 0; j < 4; j++)
                s_qkv[n0 + j][oc0 + o] = acc[o][j] + bias;
        }
    }
    __syncthreads();

    for (int idx = tid; idx < 1536; idx += 256) {
        int head = idx >> 8, r = (idx >> 4) & 15, col = idx & 15;
        float s = 0.f;
        for (int d = 0; d < 32; d++)
            s += s_qkv[r][head * 32 + d] * s_qkv[col][CC + head * 32 + d];
        s_attn[head * 16 + r][col] = s * 4.0f;
    }
    __syncthreads();

    if (tid < 96) {
        float mx = -1e30f;
        for (int i = 0; i < 16; i++) mx = fmaxf(mx, s_attn[tid][i]);
        float ss = 0.f;
        for (int i = 0; i < 16; i++) { float e = __expf(s_attn[tid][i] - mx); ss += e; s_attn[tid][i] = e; }
        float inv = 1.f / ss;
        for (int i = 0; i < 16; i++) s_attn[tid][i] *= inv;
    }
    __syncthreads();

    for (int idx = tid; idx < 16 * CC; idx += 256) {
        int n = idx / CC, c = idx - n * CC;
        int head = c >> 5;
        float s = 0.f;
        for (int m = 0; m < 16; m++) s += s_attn[head * 16 + n][m] * s_qkv[m][2 * CC + c];
        s_h[n][c] = s;
    }
    __syncthreads();

    {
        const int og  = tid >> 2;
        const int oc0 = og * 3;
        const float* w0 = projw + (size_t)(oc0 + 0) * CC;
        const float* w1 = projw + (size_t)(oc0 + 1) * CC;
        const float* w2 = projw + (size_t)(oc0 + 2) * CC;
        float acc[3][4];
        #pragma unroll
        for (int o = 0; o < 3; o++)
            #pragma unroll
            for (int j = 0; j < 4; j++) acc[o][j] = 0.f;

        for (int k8 = 0; k8 < CC / 8; k8++) {
            const int kb = k8 * 8;
            float4 w0a = *(const float4*)(w0 + kb), w0b = *(const float4*)(w0 + kb + 4);
            float4 w1a = *(const float4*)(w1 + kb), w1b = *(const float4*)(w1 + kb + 4);
            float4 w2a = *(const float4*)(w2 + kb), w2b = *(const float4*)(w2 + kb + 4);
            float4 h0a = *(const float4*)(&s_h[n0 + 0][kb]), h0b = *(const float4*)(&s_h[n0 + 0][kb + 4]);
            float4 h1a = *(const float4*)(&s_h[n0 + 1][kb]), h1b = *(const float4*)(&s_h[n0 + 1][kb + 4]);
            float4 h2a = *(const float4*)(&s_h[n0 + 2][kb]), h2b = *(const float4*)(&s_h[n0 + 2][kb + 4]);
            float4 h3a = *(const float4*)(&s_h[n0 + 3][kb]), h3b = *(const float4*)(&s_h[n0 + 3][kb + 4]);
            acc[0][0] += dot8(h0a, h0b, w0a, w0b); acc[0][1] += dot8(h1a, h1b, w0a, w0b);
            acc[0][2] += dot8(h2a, h2b, w0a, w0b); acc[0][3] += dot8(h3a, h3b, w0a, w0b);
            acc[1][0] += dot8(h0a, h0b, w1a, w1b); acc[1][1] += dot8(h1a, h1b, w1a, w1b);
            acc[1][2] += dot8(h2a, h2b, w1a, w1b); acc[1][3] += dot8(h3a, h3b, w1a, w1b);
            acc[2][0] += dot8(h0a, h0b, w2a, w2b); acc[2][1] += dot8(h1a, h1b, w2a, w2b);
            acc[2][2] += dot8(h2a, h2b, w2a, w2b); acc[2][3] += dot8(h3a, h3b, w2a, w2b);
        }
        float* xo = xt2 + (size_t)b * LL * CC;
        #pragma unroll
        for (int o = 0; o < 3; o++) {
            const int c = oc0 + o;
            float bias = projb[c];
            #pragma unroll
            for (int j = 0; j < 4; j++) {
                const size_t row = (size_t)s_tok[n0 + j] * CC;
                float res = xbT[row + c];
                xo[row + c] = acc[o][j] + bias + res;
            }
        }
    }
}

// ---- kB4: LN2 + MLP MFMA, M=64 tokens/block, chunked fc1->fc2 (4x weight reuse) ----
// kB3 was latency-bound: MFMA:weight-load = 1:1, MfmaUtil 5.7%. kB4 holds B-frags in
// regs and reuses each across 4 M-tiles (4:1); fc2 accumulates across 4 K-chunks in
// persistent registers (statically indexed).
__global__ __launch_bounds__(256) void kB4(
    const float* __restrict__ xt2,
    const float* __restrict__ n2g, const float* __restrict__ n2b,
    const unsigned short* __restrict__ fc1wb, const float* __restrict__ fc1b,
    const unsigned short* __restrict__ fc2wb, const float* __restrict__ fc2b,
    float* __restrict__ out)
{
    __shared__ __align__(16) unsigned short s_xb[64][SXBP];  // LN'd input, bf16
    __shared__ __align__(16) unsigned short s_ac[64][SXBP];  // gelu chunk (192 ch), bf16

    const int tid = threadIdx.x;
    const int t0 = blockIdx.x * 64;
    const int b  = t0 >> 16;
    const int l0 = t0 & (LL - 1);
    const float* xrow = xt2 + ((size_t)b * LL + l0) * CC;

    // ---- LN2: 4 lanes/token, each reads contiguous 48 floats; shuffle reduce ----
    {
        const int n  = tid >> 2;
        const int s4 = tid & 3;
        const float* p = xrow + (size_t)n * CC + s4 * 48;
        float4 vals[12];
        float sum = 0.f, sq = 0.f;
        #pragma unroll
        for (int j = 0; j < 12; j++) {
            float4 v = *(const float4*)(p + j * 4);
            vals[j] = v;
            sum += v.x + v.y + v.z + v.w;
            sq  += v.x*v.x + v.y*v.y + v.z*v.z + v.w*v.w;
        }
        sum += __shfl_xor(sum, 1); sq += __shfl_xor(sq, 1);
        sum += __shfl_xor(sum, 2); sq += __shfl_xor(sq, 2);
        float mu = sum * (1.f / CC);
        float rs = rsqrtf(sq * (1.f / CC) - mu * mu + 1e-5f);
        #pragma unroll
        for (int j = 0; j < 12; j++) {
            int c = s4 * 48 + j * 4;
            ushort4 o;
            o.x = f2us((vals[j].x - mu) * rs * n2g[c+0] + n2b[c+0]);
            o.y = f2us((vals[j].y - mu) * rs * n2g[c+1] + n2b[c+1]);
            o.z = f2us((vals[j].z - mu) * rs * n2g[c+2] + n2b[c+2]);
            o.w = f2us((vals[j].w - mu) * rs * n2g[c+3] + n2b[c+3]);
            *(ushort4*)&s_xb[n][c] = o;
        }
    }
    __syncthreads();

    const int lane = tid & 63;
    const int w    = tid >> 6;       // wave 0..3
    const int m16  = lane & 15;
    const int g    = lane >> 4;

    // persistent fc2 accumulators: [nIdx][M-tile], statically indexed everywhere
    f32x4 acc2[3][4];
    #pragma unroll
    for (int i = 0; i < 3; i++)
        #pragma unroll
        for (int m = 0; m < 4; m++) acc2[i][m] = (f32x4){0.f, 0.f, 0.f, 0.f};

    for (int cc = 0; cc < 4; cc++) {
        // ---- fc1 chunk cc: N channels cc*192 + wave-range [w*48, w*48+47] ----
        {
            bf16x8 bfr[3][6];
            #pragma unroll
            for (int i = 0; i < 3; i++) {
                const int ch = cc * 192 + (w * 3 + i) * 16 + m16;
                const unsigned short* wr = fc1wb + (size_t)ch * CC + g * 8;
                #pragma unroll
                for (int k = 0; k < 6; k++) bfr[i][k] = *(const bf16x8*)(wr + k * 32);
            }
            #pragma unroll
            for (int mt = 0; mt < 4; mt++) {
                bf16x8 a[6];
                #pragma unroll
                for (int k = 0; k < 6; k++)
                    a[k] = *(const bf16x8*)&s_xb[mt * 16 + m16][k * 32 + g * 8];
                #pragma unroll
                for (int i = 0; i < 3; i++) {
                    f32x4 acc = {0.f, 0.f, 0.f, 0.f};
                    #pragma unroll
                    for (int k = 0; k < 6; k++)
                        acc = __builtin_amdgcn_mfma_f32_16x16x32_bf16(a[k], bfr[i][k], acc, 0, 0, 0);
                    const int chL = (w * 3 + i) * 16 + m16;
                    const float bias = fc1b[cc * 192 + chL];
                    #pragma unroll
                    for (int t = 0; t < 4; t++)
                        s_ac[mt * 16 + g * 4 + t][chL] = f2us(gelu_exact(acc[t] + bias));
                }
            }
        }
        __syncthreads();

        // ---- fc2 partial: K-range cc*192 .. cc*192+191 into persistent acc2 ----
        {
            bf16x8 bfr[3][6];
            #pragma unroll
            for (int i = 0; i < 3; i++) {
                const int c = (w * 3 + i) * 16 + m16;
                const unsigned short* wr = fc2wb + (size_t)c * HID + cc * 192 + g * 8;
                #pragma unroll
                for (int k = 0; k < 6; k++) bfr[i][k] = *(const bf16x8*)(wr + k * 32);
            }
            #pragma unroll
            for (int mt = 0; mt < 4; mt++) {
                bf16x8 a[6];
                #pragma unroll
                for (int k = 0; k < 6; k++)
                    a[k] = *(const bf16x8*)&s_ac[mt * 16 + m16][k * 32 + g * 8];
                #pragma unroll
                for (int i = 0; i < 3; i++) {
                    #pragma unroll
                    for (int k = 0; k < 6; k++)
                        acc2[i][mt] = __builtin_amdgcn_mfma_f32_16x16x32_bf16(a[k], bfr[i][k], acc2[i][mt], 0, 0, 0);
                }
            }
        }
        __syncthreads();   // protect s_ac before next chunk overwrites
    }

    // ---- epilogue: bias + exact residual re-read (L1/L2-hot) + (B,C,L) store ----
    {
        float* outb = out + (size_t)b * CC * LL + l0;
        #pragma unroll
        for (int i = 0; i < 3; i++) {
            const int c = (w * 3 + i) * 16 + m16;
            const float bias = fc2b[c];
            #pragma unroll
            for (int mt = 0; mt < 4; mt++) {
                const int tok0 = mt * 16 + g * 4;
                float4 ov;
                ov.x = acc2[i][mt][0] + bias + xrow[(size_t)(tok0 + 0) * CC + c];
                ov.y = acc2[i][mt][1] + bias + xrow[(size_t)(tok0 + 1) * CC + c];
                ov.z = acc2[i][mt][2] + bias + xrow[(size_t)(tok0 + 2) * CC + c];
                ov.w = acc2[i][mt][3] + bias + xrow[(size_t)(tok0 + 3) * CC + c];
                *(float4*)(outb + (size_t)c * LL + tok0) = ov;
            }
        }
    }
}

// ---- kB3 (T1-tier fallback): LN2 + MLP MFMA, M=16/block (round-4 verified) ----
__global__ __launch_bounds__(256) void kB3(
    const float* __restrict__ xt2,
    const float* __restrict__ n2g, const float* __restrict__ n2b,
    const unsigned short* __restrict__ fc1wb, const float* __restrict__ fc1b,
    const unsigned short* __restrict__ fc2wb, const float* __restrict__ fc2b,
    float* __restrict__ out)
{
    __shared__ __align__(16) char smem[16 * SABP * 2];
    __shared__ __align__(16) unsigned short s_xb[16][SXBP];
    float (*s_x)[SXP] = (float(*)[SXP])smem;
    unsigned short (*s_a)[SABP] = (unsigned short(*)[SABP])smem;

    const int tid = threadIdx.x;
    const int t0 = blockIdx.x * 16;
    const int b  = t0 >> 16;
    const int l0 = t0 & (LL - 1);
    const float* xrow = xt2 + ((size_t)b * LL + l0) * CC;

    #pragma unroll
    for (int p = 0; p < 3; p++) {
        int idx = tid + p * 256;
        int n = idx / 48, c4 = idx % 48;
        float4 v = *(const float4*)(xrow + (size_t)n * CC + c4 * 4);
        *(float4*)&s_x[n][c4 * 4] = v;
    }
    __syncthreads();

    {
        const int t = tid >> 4, s = tid & 15;
        float vals[12];
        float sum = 0.f, sq = 0.f;
        #pragma unroll
        for (int k = 0; k < 12; k++) {
            float v = s_x[t][s + 16 * k];
            vals[k] = v; sum += v; sq += v * v;
        }
        #pragma unroll
        for (int m = 1; m < 16; m <<= 1) {
            sum += __shfl_xor(sum, m);
            sq  += __shfl_xor(sq, m);
        }
        float mu = sum * (1.f / CC);
        float rs = rsqrtf(sq * (1.f / CC) - mu * mu + 1e-5f);
        #pragma unroll
        for (int k = 0; k < 12; k++) {
            int c = s + 16 * k;
            s_xb[t][c] = f2us((vals[k] - mu) * rs * n2g[c] + n2b[c]);
        }
    }
    __syncthreads();

    const int lane = tid & 63;
    const int w    = tid >> 6;
    const int m16  = lane & 15;
    const int g    = lane >> 4;

    bf16x8 afrag[6];
    #pragma unroll
    for (int k = 0; k < 6; k++)
        afrag[k] = *(const bf16x8*)&s_xb[m16][k * 32 + g * 8];

    #pragma unroll
    for (int pp = 0; pp < 6; pp++) {
        const int nt0 = w * 12 + pp * 2;
        f32x4 acc0 = {0.f, 0.f, 0.f, 0.f};
        f32x4 acc1 = {0.f, 0.f, 0.f, 0.f};
        const unsigned short* wr0 = fc1wb + (size_t)(nt0 * 16 + m16) * CC + g * 8;
        const unsigned short* wr1 = wr0 + 16 * CC;
        #pragma unroll
        for (int k = 0; k < 6; k++) {
            bf16x8 b0 = *(const bf16x8*)(wr0 + k * 32);
            bf16x8 b1 = *(const bf16x8*)(wr1 + k * 32);
            acc0 = __builtin_amdgcn_mfma_f32_16x16x32_bf16(afrag[k], b0, acc0, 0, 0, 0);
            acc1 = __builtin_amdgcn_mfma_f32_16x16x32_bf16(afrag[k], b1, acc1, 0, 0, 0);
        }
        float bias0 = fc1b[nt0 * 16 + m16];
        float bias1 = fc1b[(nt0 + 1) * 16 + m16];
        #pragma unroll
        for (int t = 0; t < 4; t++) {
            s_a[g * 4 + t][nt0 * 16 + m16]       = f2us(gelu_exact(acc0[t] + bias0));
            s_a[g * 4 + t][(nt0 + 1) * 16 + m16] = f2us(gelu_exact(acc1[t] + bias1));
        }
    }
    __syncthreads();

    {
        const int nt0 = w * 3;
        f32x4 acc0 = {0.f, 0.f, 0.f, 0.f};
        f32x4 acc1 = {0.f, 0.f, 0.f, 0.f};
        f32x4 acc2 = {0.f, 0.f, 0.f, 0.f};
        const unsigned short* wr0 = fc2wb + (size_t)(nt0 * 16 + m16) * HID + g * 8;
        const unsigned short* wr1 = wr0 + 16 * HID;
        const unsigned short* wr2 = wr1 + 16 * HID;
        #pragma unroll 8
        for (int k = 0; k < 24; k++) {
            bf16x8 a  = *(const bf16x8*)&s_a[m16][k * 32 + g * 8];
            bf16x8 b0 = *(const bf16x8*)(wr0 + k * 32);
            bf16x8 b1 = *(const bf16x8*)(wr1 + k * 32);
            bf16x8 b2 = *(const bf16x8*)(wr2 + k * 32);
            acc0 = __builtin_amdgcn_mfma_f32_16x16x32_bf16(a, b0, acc0, 0, 0, 0);
            acc1 = __builtin_amdgcn_mfma_f32_16x16x32_bf16(a, b1, acc1, 0, 0, 0);
            acc2 = __builtin_amdgcn_mfma_f32_16x16x32_bf16(a, b2, acc2, 0, 0, 0);
        }
        float* outb = out + (size_t)b * CC * LL + l0;
        const int n0 = g * 4;
        #pragma unroll
        for (int i = 0; i < 3; i++) {
            const int c = (nt0 + i) * 16 + m16;
            const float bias = fc2b[c];
            const f32x4 av = (i == 0) ? acc0 : (i == 1) ? acc1 : acc2;
            float4 ov;
            ov.x = av[0] + bias + xrow[(size_t)(n0 + 0) * CC + c];
            ov.y = av[1] + bias + xrow[(size_t)(n0 + 1) * CC + c];
            ov.z = av[2] + bias + xrow[(size_t)(n0 + 2) * CC + c];
            ov.w = av[3] + bias + xrow[(size_t)(n0 + 3) * CC + c];
            *(float4*)(outb + (size_t)c * LL + n0) = ov;
        }
    }
}

// ---- kB2 (round-3 tier): LN2 + MLP f32 ----
__global__ __launch_bounds__(256, 2) void kB2(
    const float* __restrict__ xt2,
    const float* __restrict__ n2g, const float* __restrict__ n2b,
    const float* __restrict__ fc1w, const float* __restrict__ fc1b,
    const float* __restrict__ fc2w, const float* __restrict__ fc2b,
    float* __restrict__ out)
{
    __shared__ float s_x[16][SXP];
    __shared__ float s_a[16][SAP];

    const int tid = threadIdx.x;
    const int t0 = blockIdx.x * 16;
    const int b  = t0 >> 16;
    const int l0 = t0 & (LL - 1);
    const float* xrow = xt2 + ((size_t)b * LL + l0) * CC;

    #pragma unroll
    for (int p = 0; p < 3; p++) {
        int idx = tid + p * 256;
        int n = idx / 48, c4 = idx % 48;
        float4 v = *(const float4*)(xrow + (size_t)n * CC + c4 * 4);
        *(float4*)&s_x[n][c4 * 4] = v;
    }
    __syncthreads();

    {
        const int t = tid >> 4, s = tid & 15;
        float sum = 0.f, sq = 0.f;
        #pragma unroll
        for (int k = 0; k < 12; k++) {
            float v = s_x[t][s + 16 * k];
            sum += v; sq += v * v;
        }
        #pragma unroll
        for (int m = 1; m < 16; m <<= 1) {
            sum += __shfl_xor(sum, m);
            sq  += __shfl_xor(sq, m);
        }
        float mu = sum * (1.f / CC);
        float rs = rsqrtf(sq * (1.f / CC) - mu * mu + 1e-5f);
        #pragma unroll
        for (int k = 0; k < 12; k++) {
            int c = s + 16 * k;
            s_x[t][c] = (s_x[t][c] - mu) * rs * n2g[c] + n2b[c];
        }
    }
    __syncthreads();

    const int tg = tid & 3;
    const int n0 = tg * 4;
    for (int it = 0; it < 3; it++) {
        const int og  = (it * 256 + tid) >> 2;
        const int oc0 = og * 4;
        const float* w0 = fc1w + (size_t)(oc0 + 0) * CC;
        const float* w1 = fc1w + (size_t)(oc0 + 1) * CC;
        const float* w2 = fc1w + (size_t)(oc0 + 2) * CC;
        const float* w3 = fc1w + (size_t)(oc0 + 3) * CC;
        float acc[4][4];
        #pragma unroll
        for (int o = 0; o < 4; o++)
            #pragma unroll
            for (int j = 0; j < 4; j++) acc[o][j] = 0.f;

        for (int k8 = 0; k8 < CC / 8; k8++) {
            const int kb = k8 * 8;
            float4 w0a = *(const float4*)(w0 + kb), w0b = *(const float4*)(w0 + kb + 4);
            float4 w1a = *(const float4*)(w1 + kb), w1b = *(const float4*)(w1 + kb + 4);
            float4 w2a = *(const float4*)(w2 + kb), w2b = *(const float4*)(w2 + kb + 4);
            float4 w3a = *(const float4*)(w3 + kb), w3b = *(const float4*)(w3 + kb + 4);
            float4 x0a = *(const float4*)(&s_x[n0 + 0][kb]), x0b = *(const float4*)(&s_x[n0 + 0][kb + 4]);
            float4 x1a = *(const float4*)(&s_x[n0 + 1][kb]), x1b = *(const float4*)(&s_x[n0 + 1][kb + 4]);
            float4 x2a = *(const float4*)(&s_x[n0 + 2][kb]), x2b = *(const float4*)(&s_x[n0 + 2][kb + 4]);
            float4 x3a = *(const float4*)(&s_x[n0 + 3][kb]), x3b = *(const float4*)(&s_x[n0 + 3][kb + 4]);
            acc[0][0] += dot8(x0a, x0b, w0a, w0b); acc[0][1] += dot8(x1a, x1b, w0a, w0b);
            acc[0][2] += dot8(x2a, x2b, w0a, w0b); acc[0][3] += dot8(x3a, x3b, w0a, w0b);
            acc[1][0] += dot8(x0a, x0b, w1a, w1b); acc[1][1] += dot8(x1a, x1b, w1a, w1b);
            acc[1][2] += dot8(x2a, x2b, w1a, w1b); acc[1][3] += dot8(x3a, x3b, w1a, w1b);
            acc[2][0] += dot8(x0a, x0b, w2a, w2b); acc[2][1] += dot8(x1a, x1b, w2a, w2b);
            acc[2][2] += dot8(x2a, x2b, w2a, w2b); acc[2][3] += dot8(x3a, x3b, w2a, w2b);
            acc[3][0] += dot8(x0a, x0b, w3a, w3b); acc[3][1] += dot8(x1a, x1b, w3a, w3b);
            acc[3][2] += dot8(x2a, x2b, w3a, w3b); acc[3][3] += dot8(x3a, x3b, w3a, w3b);
        }
        #pragma unroll
        for (int o = 0; o < 4; o++) {
            float bias = fc1b[oc0 + o];
            #pragma unroll
            for (int j = 0; j < 4; j++)
                s_a[n0 + j][oc0 + o] = gelu_exact(acc[o][j] + bias);
        }
    }
    __syncthreads();

    {
        const int og  = tid >> 2;
        const int oc0 = og * 3;
        const float* w0 = fc2w + (size_t)(oc0 + 0) * HID;
        const float* w1 = fc2w + (size_t)(oc0 + 1) * HID;
        const float* w2 = fc2w + (size_t)(oc0 + 2) * HID;
        float acc[3][4];
        #pragma unroll
        for (int o = 0; o < 3; o++)
            #pragma unroll
            for (int j = 0; j < 4; j++) acc[o][j] = 0.f;

        for (int k8 = 0; k8 < HID / 8; k8++) {
            const int kb = k8 * 8;
            float4 w0a = *(const float4*)(w0 + kb), w0b = *(const float4*)(w0 + kb + 4);
            float4 w1a = *(const float4*)(w1 + kb), w1b = *(const float4*)(w1 + kb + 4);
            float4 w2a = *(const float4*)(w2 + kb), w2b = *(const float4*)(w2 + kb + 4);
            float4 a0a = *(const float4*)(&s_a[n0 + 0][kb]), a0b = *(const float4*)(&s_a[n0 + 0][kb + 4]);
            float4 a1a = *(const float4*)(&s_a[n0 + 1][kb]), a1b = *(const float4*)(&s_a[n0 + 1][kb + 4]);
            float4 a2a = *(const float4*)(&s_a[n0 + 2][kb]), a2b = *(const float4*)(&s_a[n0 + 2][kb + 4]);
            float4 a3a = *(const float4*)(&s_a[n0 + 3][kb]), a3b = *(const float4*)(&s_a[n0 + 3][kb + 4]);
            acc[0][0] += dot8(a0a, a0b, w0a, w0b); acc[0][1] += dot8(a1a, a1b, w0a, w0b);
            acc[0][2] += dot8(a2a, a2b, w0a, w0b); acc[0][3] += dot8(a3a, a3b, w0a, w0b);
            acc[1][0] += dot8(a0a, a0b, w1a, w1b); acc[1][1] += dot8(a1a, a1b, w1a, w1b);
            acc[1][2] += dot8(a2a, a2b, w1a, w1b); acc[1][3] += dot8(a3a, a3b, w1a, w1b);
            acc[2][0] += dot8(a0a, a0b, w2a, w2b); acc[2][1] += dot8(a1a, a1b, w2a, w2b);
            acc[2][2] += dot8(a2a, a2b, w2a, w2b); acc[2][3] += dot8(a3a, a3b, w2a, w2b);
        }
        #pragma unroll
        for (int o = 0; o < 3; o++) {
            const int c = oc0 + o;
            float bias = fc2b[c];
            float4 outv;
            float r0 = xrow[(size_t)(n0 + 0) * CC + c];
            float r1 = xrow[(size_t)(n0 + 1) * CC + c];
            float r2 = xrow[(size_t)(n0 + 2) * CC + c];
            float r3 = xrow[(size_t)(n0 + 3) * CC + c];
            outv.x = acc[o][0] + bias + r0;
            outv.y = acc[o][1] + bias + r1;
            outv.z = acc[o][2] + bias + r2;
            outv.w = acc[o][3] + bias + r3;
            *(float4*)(out + ((size_t)b * CC + c) * LL + l0 + n0) = outv;
        }
    }
}

// =================== NO-WORKSPACE FALLBACK (round-2 kernels) ===================

__global__ __launch_bounds__(256) void kA(
    const float* __restrict__ x, const int* __restrict__ perm,
    const float* __restrict__ n1g, const float* __restrict__ n1b,
    const float* __restrict__ qkvw, const float* __restrict__ qkvb,
    const float* __restrict__ projw, const float* __restrict__ projb,
    float* __restrict__ xt2)
{
    __shared__ float s_h[16][CC];
    __shared__ float s_qkv[16][3*CC];
    __shared__ float s_attn[96][16];
    __shared__ unsigned short s_stash[16][CC];
    __shared__ float s_mu[16], s_rs[16];
    __shared__ int s_tok[16];

    const int tid = threadIdx.x;
    const int wid = blockIdx.x;
    const int b  = wid >> 12;
    const int hb = (wid >> 6) & 63;
    const int wb = wid & 63;

    if (tid < 16) {
        int si = tid >> 2, sj = tid & 3;
        s_tok[tid] = perm[(hb * 4 + si) * WWW + wb * 4 + sj];
    }
    __syncthreads();

    for (int idx = tid; idx < 16 * CC; idx += 256) {
        int n = idx / CC, c = idx - n * CC;
        float v = x[((size_t)b * CC + c) * LL + s_tok[n]];
        s_h[n][c] = v;
        s_stash[n][c] = f2us(v);
    }
    __syncthreads();

    if (tid < 16) {
        float s = 0.f, q = 0.f;
        for (int c = 0; c < CC; c++) { float v = s_h[tid][c]; s += v; q += v * v; }
        float mu = s * (1.f / CC);
        float var = q * (1.f / CC) - mu * mu;
        s_mu[tid] = mu;
        s_rs[tid] = rsqrtf(var + 1e-5f);
    }
    __syncthreads();

    for (int idx = tid; idx < 16 * CC; idx += 256) {
        int n = idx / CC, c = idx - n * CC;
        s_h[n][c] = (s_h[n][c] - s_mu[n]) * s_rs[n] * n1g[c] + n1b[c];
    }
    __syncthreads();

    for (int oc = tid; oc < 3 * CC; oc += 256) {
        float acc[16];
        for (int i = 0; i < 16; i++) acc[i] = 0.f;
        const float4* wr = (const float4*)(qkvw + (size_t)oc * CC);
        for (int k8 = 0; k8 < CC / 8; ++k8) {
            float4 wa = wr[k8 * 2], wb2 = wr[k8 * 2 + 1];
            for (int n = 0; n < 16; n++) {
                const float4* hp = (const float4*)(&s_h[n][k8 * 8]);
                acc[n] += dot8(hp[0], hp[1], wa, wb2);
            }
        }
        float bias = qkvb[oc];
        for (int n = 0; n < 16; n++) s_qkv[n][oc] = acc[n] + bias;
    }
    __syncthreads();

    for (int idx = tid; idx < 1536; idx += 256) {
        int head = idx >> 8, r = (idx >> 4) & 15, col = idx & 15;
        float s = 0.f;
        for (int d = 0; d < 32; d++)
            s += s_qkv[r][head * 32 + d] * s_qkv[col][CC + head * 32 + d];
        s_attn[head * 16 + r][col] = s * 4.0f;
    }
    __syncthreads();

    if (tid < 96) {
        float mx = -1e30f;
        for (int i = 0; i < 16; i++) mx = fmaxf(mx, s_attn[tid][i]);
        float ss = 0.f;
        for (int i = 0; i < 16; i++) { float e = __expf(s_attn[tid][i] - mx); ss += e; s_attn[tid][i] = e; }
        float inv = 1.f / ss;
        for (int i = 0; i < 16; i++) s_attn[tid][i] *= inv;
    }
    __syncthreads();

    for (int idx = tid; idx < 16 * CC; idx += 256) {
        int n = idx / CC, c = idx - n * CC;
        int head = c >> 5;
        float s = 0.f;
        for (int m = 0; m < 16; m++) s += s_attn[head * 16 + n][m] * s_qkv[m][2 * CC + c];
        s_h[n][c] = s;
    }
    __syncthreads();

    if (tid < CC) {
        const int c = tid;
        float acc[16];
        for (int i = 0; i < 16; i++) acc[i] = 0.f;
        const float4* wr = (const float4*)(projw + (size_t)c * CC);
        for (int k8 = 0; k8 < CC / 8; ++k8) {
            float4 wa = wr[k8 * 2], wb2 = wr[k8 * 2 + 1];
            for (int n = 0; n < 16; n++) {
                const float4* hp = (const float4*)(&s_h[n][k8 * 8]);
                acc[n] += dot8(hp[0], hp[1], wa, wb2);
            }
        }
        float bias = projb[c];
        for (int n = 0; n < 16; n++) {
            float res = us2f(s_stash[n][c]);
            xt2[((size_t)b * CC + c) * LL + s_tok[n]] = acc[n] + bias + res;
        }
    }
}

__global__ __launch_bounds__(256, 2) void kB(
    float* __restrict__ xt2,
    const float* __restrict__ n2g, const float* __restrict__ n2b,
    const float* __restrict__ fc1w, const float* __restrict__ fc1b,
    const float* __restrict__ fc2w, const float* __restrict__ fc2b)
{
    __shared__ float s_x[16][SXP];
    __shared__ float s_a[16][SAP];

    const int tid = threadIdx.x;
    const int t0 = blockIdx.x * 16;
    const int b  = t0 >> 16;
    const int l0 = t0 & (LL - 1);
    float* xbase = xt2 + (size_t)b * CC * LL + l0;

    for (int idx = tid; idx < 4 * CC; idx += 256) {
        int c = idx >> 2, n4 = idx & 3;
        float4 v = *(const float4*)(xbase + (size_t)c * LL + n4 * 4);
        s_x[n4 * 4 + 0][c] = v.x;
        s_x[n4 * 4 + 1][c] = v.y;
        s_x[n4 * 4 + 2][c] = v.z;
        s_x[n4 * 4 + 3][c] = v.w;
    }
    __syncthreads();

    {
        const int t = tid >> 4, s = tid & 15;
        float sum = 0.f, sq = 0.f;
        #pragma unroll
        for (int k = 0; k < 12; k++) {
            float v = s_x[t][s + 16 * k];
            sum += v; sq += v * v;
        }
        #pragma unroll
        for (int m = 1; m < 16; m <<= 1) {
            sum += __shfl_xor(sum, m);
            sq  += __shfl_xor(sq, m);
        }
        float mu = sum * (1.f / CC);
        float rs = rsqrtf(sq * (1.f / CC) - mu * mu + 1e-5f);
        #pragma unroll
        for (int k = 0; k < 12; k++) {
            int c = s + 16 * k;
            s_x[t][c] = (s_x[t][c] - mu) * rs * n2g[c] + n2b[c];
        }
    }
    __syncthreads();

    const int tg = tid & 3;
    const int n0 = tg * 4;
    for (int it = 0; it < 3; it++) {
        const int og  = (it * 256 + tid) >> 2;
        const int oc0 = og * 4;
        const float* w0 = fc1w + (size_t)(oc0 + 0) * CC;
        const float* w1 = fc1w + (size_t)(oc0 + 1) * CC;
        const float* w2 = fc1w + (size_t)(oc0 + 2) * CC;
        const float* w3 = fc1w + (size_t)(oc0 + 3) * CC;
        float acc[4][4];
        #pragma unroll
        for (int o = 0; o < 4; o++)
            #pragma unroll
            for (int j = 0; j < 4; j++) acc[o][j] = 0.f;

        for (int k8 = 0; k8 < CC / 8; k8++) {
            const int kb = k8 * 8;
            float4 w0a = *(const float4*)(w0 + kb), w0b = *(const float4*)(w0 + kb + 4);
            float4 w1a = *(const float4*)(w1 + kb), w1b = *(const float4*)(w1 + kb + 4);
            float4 w2a = *(const float4*)(w2 + kb), w2b = *(const float4*)(w2 + kb + 4);
            float4 w3a = *(const float4*)(w3 + kb), w3b = *(const float4*)(w3 + kb + 4);
            float4 x0a = *(const float4*)(&s_x[n0 + 0][kb]), x0b = *(const float4*)(&s_x[n0 + 0][kb + 4]);
            float4 x1a = *(const float4*)(&s_x[n0 + 1][kb]), x1b = *(const float4*)(&s_x[n0 + 1][kb + 4]);
            float4 x2a = *(const float4*)(&s_x[n0 + 2][kb]), x2b = *(const float4*)(&s_x[n0 + 2][kb + 4]);
            float4 x3a = *(const float4*)(&s_x[n0 + 3][kb]), x3b = *(const float4*)(&s_x[n0 + 3][kb + 4]);
            acc[0][0] += dot8(x0a, x0b, w0a, w0b); acc[0][1] += dot8(x1a, x1b, w0a, w0b);
            acc[0][2] += dot8(x2a, x2b, w0a, w0b); acc[0][3] += dot8(x3a, x3b, w0a, w0b);
            acc[1][0] += dot8(x0a, x0b, w1a, w1b); acc[1][1] += dot8(x1a, x1b, w1a, w1b);
            acc[1][2] += dot8(x2a, x2b, w1a, w1b); acc[1][3] += dot8(x3a, x3b, w1a, w1b);
            acc[2][0] += dot8(x0a, x0b, w2a, w2b); acc[2][1] += dot8(x1a, x1b, w2a, w2b);
            acc[2][2] += dot8(x2a, x2b, w2a, w2b); acc[2][3] += dot8(x3a, x3b, w2a, w2b);
            acc[3][0] += dot8(x0a, x0b, w3a, w3b); acc[3][1] += dot8(x1a, x1b, w3a, w3b);
            acc[3][2] += dot8(x2a, x2b, w3a, w3b); acc[3][3] += dot8(x3a, x3b, w3a, w3b);
        }
        #pragma unroll
        for (int o = 0; o < 4; o++) {
            float bias = fc1b[oc0 + o];
            #pragma unroll
            for (int j = 0; j < 4; j++)
                s_a[n0 + j][oc0 + o] = gelu_exact(acc[o][j] + bias);
        }
    }
    __syncthreads();

    {
        const int og  = tid >> 2;
        const int oc0 = og * 3;
        const float* w0 = fc2w + (size_t)(oc0 + 0) * HID;
        const float* w1 = fc2w + (size_t)(oc0 + 1) * HID;
        const float* w2 = fc2w + (size_t)(oc0 + 2) * HID;
        float acc[3][4];
        #pragma unroll
        for (int o = 0; o < 3; o++)
            #pragma unroll
            for (int j = 0; j < 4; j++) acc[o][j] = 0.f;

        for (int k8 = 0; k8 < HID / 8; k8++) {
            const int kb = k8 * 8;
            float4 w0a = *(const float4*)(w0 + kb), w0b = *(const float4*)(w0 + kb + 4);
            float4 w1a = *(const float4*)(w1 + kb), w1b = *(const float4*)(w1 + kb + 4);
            float4 w2a = *(const float4*)(w2 + kb), w2b = *(const float4*)(w2 + kb + 4);
            float4 a0a = *(const float4*)(&s_a[n0 + 0][kb]), a0b = *(const float4*)(&s_a[n0 + 0][kb + 4]);
            float4 a1a = *(const float4*)(&s_a[n0 + 1][kb]), a1b = *(const float4*)(&s_a[n0 + 1][kb + 4]);
            float4 a2a = *(const float4*)(&s_a[n0 + 2][kb]), a2b = *(const float4*)(&s_a[n0 + 2][kb + 4]);
            float4 a3a = *(const float4*)(&s_a[n0 + 3][kb]), a3b = *(const float4*)(&s_a[n0 + 3][kb + 4]);
            acc[0][0] += dot8(a0a, a0b, w0a, w0b); acc[0][1] += dot8(a1a, a1b, w0a, w0b);
            acc[0][2] += dot8(a2a, a2b, w0a, w0b); acc[0][3] += dot8(a3a, a3b, w0a, w0b);
            acc[1][0] += dot8(a0a, a0b, w1a, w1b); acc[1][1] += dot8(a1a, a1b, w1a, w1b);
            acc[1][2] += dot8(a2a, a2b, w1a, w1b); acc[1][3] += dot8(a3a, a3b, w1a, w1b);
            acc[2][0] += dot8(a0a, a0b, w2a, w2b); acc[2][1] += dot8(a1a, a1b, w2a, w2b);
            acc[2][2] += dot8(a2a, a2b, w2a, w2b); acc[2][3] += dot8(a3a, a3b, w2a, w2b);
        }
        #pragma unroll
        for (int o = 0; o < 3; o++) {
            const int c = oc0 + o;
            float bias = fc2b[c];
            float* p = xbase + (size_t)c * LL + n0;
            float4 r = *(const float4*)p;
            float4 outv;
            outv.x = acc[o][0] + bias + r.x;
            outv.y = acc[o][1] + bias + r.y;
            outv.z = acc[o][2] + bias + r.z;
            outv.w = acc[o][3] + bias + r.w;
            *(float4*)p = outv;
        }
    }
}

extern "C" void kernel_launch(void* const* d_in, const int* in_sizes, int n_in,
                              void* d_out, int out_size, void* d_ws, size_t ws_size,
                              hipStream_t stream) {
    const float* x     = (const float*)d_in[0];
    const int*   perm  = (const int*)d_in[1];
    const float* n1g   = (const float*)d_in[2];
    const float* n1b   = (const float*)d_in[3];
    const float* qkvw  = (const float*)d_in[4];
    const float* qkvb  = (const float*)d_in[5];
    const float* projw = (const float*)d_in[6];
    const float* projb = (const float*)d_in[7];
    const float* n2g   = (const float*)d_in[8];
    const float* n2b   = (const float*)d_in[9];
    const float* fc1w  = (const float*)d_in[10];
    const float* fc1b  = (const float*)d_in[11];
    const float* fc2w  = (const float*)d_in[12];
    const float* fc2b  = (const float*)d_in[13];

    const size_t NTOK  = (size_t)BB * LL * CC;
    const size_t WS_MID  = 2 * NTOK * sizeof(float);                               // xT + xt2
    const size_t WS_T1   = WS_MID + 2 * (size_t)HID * CC * sizeof(unsigned short); // + fc bf16
    const size_t WS_T2   = WS_T1 + (size_t)(3*CC*CC + CC*CC) * sizeof(unsigned short); // + qkv/proj bf16

    if (d_ws != nullptr && ws_size >= WS_T2) {
        float* xT   = (float*)d_ws;
        float* xt2w = xT + NTOK;
        unsigned short* fc1wb  = (unsigned short*)(xt2w + NTOK);
        unsigned short* fc2wb  = fc1wb + (size_t)HID * CC;
        unsigned short* qkvwb  = fc2wb + (size_t)HID * CC;
        unsigned short* projwb = qkvwb + (size_t)3 * CC * CC;
        kW2<<<(HID * CC + 255) / 256, 256, 0, stream>>>(fc1w, fc2w, qkvw, projw, fc1wb, fc2wb, qkvwb, projwb);
        kT <<<BB * (LL / TLL), 256, 0, stream>>>(x, xT);
        kA3<<<16384, 256, 0, stream>>>(xT, perm, n1g, n1b, qkvwb, qkvb, projwb, projb, xt2w);
        kB4<<<BB * (LL / 64), 256, 0, stream>>>(xt2w, n2g, n2b, fc1wb, fc1b, fc2wb, fc2b, (float*)d_out);
    } else if (d_ws != nullptr && ws_size >= WS_T1) {
        float* xT   = (float*)d_ws;
        float* xt2w = xT + NTOK;
        unsigned short* fc1wb = (unsigned short*)(xt2w + NTOK);
        unsigned short* fc2wb = fc1wb + (size_t)HID * CC;
        kW <<<(HID * CC + 255) / 256, 256, 0, stream>>>(fc1w, fc2w, fc1wb, fc2wb);
        kT <<<BB * (LL / TLL), 256, 0, stream>>>(x, xT);
        kA2<<<16384, 256, 0, stream>>>(xT, perm, n1g, n1b, qkvw, qkvb, projw, projb, xt2w);
        kB3<<<16384, 256, 0, stream>>>(xt2w, n2g, n2b, fc1wb, fc1b, fc2wb, fc2b, (float*)d_out);
    } else if (d_ws != nullptr && ws_size >= WS_MID) {
        float* xT   = (float*)d_ws;
        float* xt2w = xT + NTOK;
        kT <<<BB * (LL / TLL), 256, 0, stream>>>(x, xT);
        kA2<<<16384, 256, 0, stream>>>(xT, perm, n1g, n1b, qkvw, qkvb, projw, projb, xt2w);
        kB2<<<16384, 256, 0, stream>>>(xt2w, n2g, n2b, fc1w, fc1b, fc2w, fc2b, (float*)d_out);
    } else {
        float* out = (float*)d_out;
        kA<<<16384, 256, 0, stream>>>(x, perm, n1g, n1b, qkvw, qkvb, projw, projb, out);
        kB<<<16384, 256, 0, stream>>>(out, n2g, n2b, fc1w, fc1b, fc2w, fc2b);
    }
    (void)in_sizes; (void)n_in; (void)out_size;
}